// Round 7
// baseline (287.770 us; speedup 1.0000x reference)
//
#include <hip/hip_runtime.h>
#include <hip/hip_bf16.h>

// Mamba layer: LN -> in_proj(bf16 MFMA) -> conv+silu -> x_proj(fp32 split-K, fused transpose)
//              -> dt_proj+softplus -> chunked scan+gate (XCD-swizzled, DPP reduce) -> out_proj(bf16 MFMA split-K)
#define BATCH 2
#define SEQ   1024
#define DIM   768
#define DI    1536
#define DS    16
#define DCONV 4
#define DTR   48
#define XZW   (2*DI)     // 3072
#define DBCW  (DTR+2*DS) // 80
#define MROWS (BATCH*SEQ) // 2048
#define NCHUNK 16
#define CLEN  (SEQ/NCHUNK) // 64
#define XP_KS 8          // x_proj split-K slices
#define OP_KS 4          // out_proj split-K slices
#define PIDX(t) ((t) + ((t) >> 6))   // chunk-pad: spreads the 4 chunk-groups across banks

typedef unsigned short ushort_t;
typedef __attribute__((ext_vector_type(8))) short short8;
typedef __attribute__((ext_vector_type(4))) float f32x4;

__device__ __forceinline__ float sigmoidf_(float x) {
    return 1.f / (1.f + __expf(-x));
}

__device__ __forceinline__ ushort_t f2bf(float x) {
    union { float f; unsigned u; } c{x};
    unsigned r = c.u + 0x7FFF + ((c.u >> 16) & 1);   // RNE
    return (ushort_t)(r >> 16);
}

__device__ __forceinline__ void gload16(const void* g, void* lds) {
    __builtin_amdgcn_global_load_lds(
        (const __attribute__((address_space(1))) void*)g,
        (__attribute__((address_space(3))) void*)lds,
        16, 0, 0);
}

// sum across the 16 lanes of a DPP row via rotate-add (full-rate VALU, no LDS pipe)
__device__ __forceinline__ float row_sum16(float p) {
    int x;
    x = __builtin_amdgcn_update_dpp(0, __float_as_int(p), 0x128, 0xf, 0xf, true); // row_ror:8
    p += __int_as_float(x);
    x = __builtin_amdgcn_update_dpp(0, __float_as_int(p), 0x124, 0xf, 0xf, true); // row_ror:4
    p += __int_as_float(x);
    x = __builtin_amdgcn_update_dpp(0, __float_as_int(p), 0x122, 0xf, 0xf, true); // row_ror:2
    p += __int_as_float(x);
    x = __builtin_amdgcn_update_dpp(0, __float_as_int(p), 0x121, 0xf, 0xf, true); // row_ror:1
    p += __int_as_float(x);
    return p;
}

// ---------------- fp32 -> bf16 conversion (8 elems/thread) ----------------
__global__ __launch_bounds__(256) void cvt_bf16(const float* __restrict__ in,
                                                ushort_t* __restrict__ out, int n)
{
    int i = (blockIdx.x * 256 + threadIdx.x) * 8;
    if (i >= n) return;
    float4 a = *(const float4*)(in + i);
    float4 b = *(const float4*)(in + i + 4);
    ushort_t o[8] = { f2bf(a.x), f2bf(a.y), f2bf(a.z), f2bf(a.w),
                      f2bf(b.x), f2bf(b.y), f2bf(b.z), f2bf(b.w) };
    *(ushort4*)(out + i)     = *(ushort4*)o;
    *(ushort4*)(out + i + 4) = *(ushort4*)(o + 4);
}

// ---------------- split-K partial reduce: out[i] = sum_z part[z][i] (float4) -------
__global__ __launch_bounds__(256) void reduce_sk4(const float4* __restrict__ part,
                                                  float4* __restrict__ out,
                                                  int count4, int nslices)
{
    int i = blockIdx.x * 256 + threadIdx.x;
    if (i >= count4) return;
    float4 s = part[i];
    for (int z = 1; z < nslices; ++z) {
        float4 p = part[(size_t)z * count4 + i];
        s.x += p.x; s.y += p.y; s.z += p.z; s.w += p.w;
    }
    out[i] = s;
}

// ---- x_proj split-K reduce + scatter: dbc[t][c] plus transposed BT/CT [b][n][t] ----
__global__ __launch_bounds__(256) void reduce_dbc(const float* __restrict__ part,
                                                  float* __restrict__ dbc,
                                                  float* __restrict__ BT,
                                                  float* __restrict__ CT)
{
    int i = blockIdx.x * 256 + threadIdx.x;    // over MROWS*DBCW
    if (i >= MROWS * DBCW) return;
    float s = 0.f;
    #pragma unroll
    for (int z = 0; z < XP_KS; ++z)
        s += part[(size_t)z * MROWS * DBCW + i];
    dbc[i] = s;
    int t = i / DBCW;
    int c = i % DBCW;
    if (c >= DTR) {
        int b = t / SEQ, tt = t % SEQ;
        int n = c - DTR;
        if (n < DS) BT[((size_t)b * DS + n) * SEQ + tt] = s;
        else        CT[((size_t)b * DS + (n - DS)) * SEQ + tt] = s;
    }
}

// ---------------- LayerNorm (fp32 in, bf16 out), shfl-based ----------------
__global__ __launch_bounds__(256) void ln_kernel(const float* __restrict__ x,
                                                 const float* __restrict__ w,
                                                 const float* __restrict__ b,
                                                 ushort_t* __restrict__ xn)
{
    __shared__ float part[8];
    int row = blockIdx.x;               // 0..2047
    const float* xr = x + (size_t)row * DIM;
    ushort_t* o = xn + (size_t)row * DIM;
    int tid = threadIdx.x;
    int lane = tid & 63, wid = tid >> 6;

    float v0 = xr[tid], v1 = xr[tid + 256], v2 = xr[tid + 512];
    float s = v0 + v1 + v2;
    #pragma unroll
    for (int off = 32; off > 0; off >>= 1) s += __shfl_xor(s, off);
    if (lane == 0) part[wid] = s;
    __syncthreads();
    float mu = (part[0] + part[1] + part[2] + part[3]) * (1.f / DIM);

    float d0 = v0 - mu, d1 = v1 - mu, d2 = v2 - mu;
    float q = d0 * d0 + d1 * d1 + d2 * d2;
    #pragma unroll
    for (int off = 32; off > 0; off >>= 1) q += __shfl_xor(q, off);
    if (lane == 0) part[4 + wid] = q;
    __syncthreads();
    float rstd = rsqrtf((part[4] + part[5] + part[6] + part[7]) * (1.f / DIM) + 1e-5f);

    o[tid]       = f2bf(d0 * rstd * w[tid]       + b[tid]);
    o[tid + 256] = f2bf(d1 * rstd * w[tid + 256] + b[tid + 256]);
    o[tid + 512] = f2bf(d2 * rstd * w[tid + 512] + b[tid + 512]);
}

// ---------------- bf16 MFMA GEMM: C(MxN fp32) = A(MxK bf16) @ W(NxK bf16)^T ----------
__global__ __launch_bounds__(256) void gemm_bf16(const ushort_t* __restrict__ A,
                                                 const ushort_t* __restrict__ W,
                                                 float* __restrict__ C,
                                                 int N, int K)
{
    __shared__ __align__(16) ushort_t As[128 * 32];
    __shared__ __align__(16) ushort_t Bs[128 * 32];

    int tid = threadIdx.x;
    int wave = tid >> 6, lane = tid & 63;
    int wr = wave >> 1, wc = wave & 1;
    int l15 = lane & 15, kb = lane >> 4;
    int m0 = blockIdx.y * 128, n0 = blockIdx.x * 128;

    f32x4 acc[4][4] = {};

    for (int k0 = 0; k0 < K; k0 += 32) {
        #pragma unroll
        for (int i = 0; i < 2; ++i) {
            int cbase = i * 256 + wave * 64;
            int c = cbase + lane;
            int row = c >> 2;
            int col = (c & 3) * 8;
            gload16(A + (size_t)(m0 + row) * K + k0 + col, (char*)As + (size_t)cbase * 16);
            gload16(W + (size_t)(n0 + row) * K + k0 + col, (char*)Bs + (size_t)cbase * 16);
        }
        __syncthreads();

        short8 af[4], bfr[4];
        #pragma unroll
        for (int m = 0; m < 4; ++m)
            af[m] = *(const short8*)&As[(wr * 64 + m * 16 + l15) * 32 + kb * 8];
        #pragma unroll
        for (int n = 0; n < 4; ++n)
            bfr[n] = *(const short8*)&Bs[(wc * 64 + n * 16 + l15) * 32 + kb * 8];

        #pragma unroll
        for (int m = 0; m < 4; ++m)
            #pragma unroll
            for (int n = 0; n < 4; ++n)
                acc[m][n] = __builtin_amdgcn_mfma_f32_16x16x32_bf16(af[m], bfr[n], acc[m][n], 0, 0, 0);

        __syncthreads();
    }

    int r0 = m0 + wr * 64 + kb * 4;
    int c0 = n0 + wc * 64 + l15;
    #pragma unroll
    for (int m = 0; m < 4; ++m)
        #pragma unroll
        for (int n = 0; n < 4; ++n) {
            int rr = r0 + m * 16;
            int cc = c0 + n * 16;
            #pragma unroll
            for (int r = 0; r < 4; ++r)
                C[(size_t)(rr + r) * N + cc] = acc[m][n][r];
        }
}

// ---- split-K bf16 MFMA GEMM: Cpart[z] = A @ W^T over K-slice z (z = blockIdx.z) ----
__global__ __launch_bounds__(256) void gemm_bf16_sk(const ushort_t* __restrict__ A,
                                                    const ushort_t* __restrict__ W,
                                                    float* __restrict__ Cpart,
                                                    int N, int Ktot, int Kslice, int M)
{
    __shared__ __align__(16) ushort_t As[128 * 32];
    __shared__ __align__(16) ushort_t Bs[128 * 32];

    int tid = threadIdx.x;
    int wave = tid >> 6, lane = tid & 63;
    int wr = wave >> 1, wc = wave & 1;
    int l15 = lane & 15, kb = lane >> 4;
    int m0 = blockIdx.y * 128, n0 = blockIdx.x * 128;
    int kbase = blockIdx.z * Kslice;
    float* C = Cpart + (size_t)blockIdx.z * M * N;

    f32x4 acc[4][4] = {};

    for (int k0 = kbase; k0 < kbase + Kslice; k0 += 32) {
        #pragma unroll
        for (int i = 0; i < 2; ++i) {
            int cbase = i * 256 + wave * 64;
            int c = cbase + lane;
            int row = c >> 2;
            int col = (c & 3) * 8;
            gload16(A + (size_t)(m0 + row) * Ktot + k0 + col, (char*)As + (size_t)cbase * 16);
            gload16(W + (size_t)(n0 + row) * Ktot + k0 + col, (char*)Bs + (size_t)cbase * 16);
        }
        __syncthreads();

        short8 af[4], bfr[4];
        #pragma unroll
        for (int m = 0; m < 4; ++m)
            af[m] = *(const short8*)&As[(wr * 64 + m * 16 + l15) * 32 + kb * 8];
        #pragma unroll
        for (int n = 0; n < 4; ++n)
            bfr[n] = *(const short8*)&Bs[(wc * 64 + n * 16 + l15) * 32 + kb * 8];

        #pragma unroll
        for (int m = 0; m < 4; ++m)
            #pragma unroll
            for (int n = 0; n < 4; ++n)
                acc[m][n] = __builtin_amdgcn_mfma_f32_16x16x32_bf16(af[m], bfr[n], acc[m][n], 0, 0, 0);

        __syncthreads();
    }

    int r0 = m0 + wr * 64 + kb * 4;
    int c0 = n0 + wc * 64 + l15;
    #pragma unroll
    for (int m = 0; m < 4; ++m)
        #pragma unroll
        for (int n = 0; n < 4; ++n) {
            int rr = r0 + m * 16;
            int cc = c0 + n * 16;
            #pragma unroll
            for (int r = 0; r < 4; ++r)
                C[(size_t)(rr + r) * N + cc] = acc[m][n][r];
        }
}

// ---------------- Generic tiled fp32 GEMM: C = act(A @ W^T + bias) ----------------
__global__ __launch_bounds__(256) void gemm_nt(const float* __restrict__ A, int lda,
                                               const float* __restrict__ W, int ldw,
                                               float* __restrict__ C, int ldc,
                                               int N, int K,
                                               const float* __restrict__ bias, int act)
{
    __shared__ float As[64][17];
    __shared__ float Ws[64][17];
    int tid = threadIdx.x;
    int tx = tid & 15;
    int ty = tid >> 4;
    int m0 = blockIdx.y * 64;
    int n0 = blockIdx.x * 64;

    float acc[4][4] = {};

    for (int k0 = 0; k0 < K; k0 += 16) {
        #pragma unroll
        for (int i = 0; i < 4; ++i) {
            int idx = tid + i * 256;
            int r = idx >> 4, c = idx & 15;
            As[r][c] = A[(size_t)(m0 + r) * lda + k0 + c];
            int nr = n0 + r;
            Ws[r][c] = (nr < N) ? W[(size_t)nr * ldw + k0 + c] : 0.f;
        }
        __syncthreads();
        #pragma unroll
        for (int kk = 0; kk < 16; ++kk) {
            float av[4], wv[4];
            #pragma unroll
            for (int i = 0; i < 4; ++i) av[i] = As[ty * 4 + i][kk];
            #pragma unroll
            for (int j = 0; j < 4; ++j) wv[j] = Ws[tx * 4 + j][kk];
            #pragma unroll
            for (int i = 0; i < 4; ++i)
                #pragma unroll
                for (int j = 0; j < 4; ++j)
                    acc[i][j] += av[i] * wv[j];
        }
        __syncthreads();
    }

    #pragma unroll
    for (int i = 0; i < 4; ++i) {
        int m = m0 + ty * 4 + i;
        #pragma unroll
        for (int j = 0; j < 4; ++j) {
            int n = n0 + tx * 4 + j;
            if (n < N) {
                float v = acc[i][j];
                if (bias) v += bias[n];
                if (act == 1) v = (v > 20.f) ? v : log1pf(__expf(v));
                C[(size_t)m * ldc + n] = v;
            }
        }
    }
}

// ---- split-K fp32 GEMM: Cpart[z] = A @ W^T over K-slice z (no bias/act) ----
__global__ __launch_bounds__(256) void gemm_nt_sk(const float* __restrict__ A, int lda,
                                                  const float* __restrict__ W, int ldw,
                                                  float* __restrict__ Cpart, int ldc,
                                                  int N, int Kslice, int M)
{
    __shared__ float As[64][17];
    __shared__ float Ws[64][17];
    int tid = threadIdx.x;
    int tx = tid & 15;
    int ty = tid >> 4;
    int m0 = blockIdx.y * 64;
    int n0 = blockIdx.x * 64;
    int kbase = blockIdx.z * Kslice;
    float* C = Cpart + (size_t)blockIdx.z * M * ldc;

    float acc[4][4] = {};

    for (int k0 = kbase; k0 < kbase + Kslice; k0 += 16) {
        #pragma unroll
        for (int i = 0; i < 4; ++i) {
            int idx = tid + i * 256;
            int r = idx >> 4, c = idx & 15;
            As[r][c] = A[(size_t)(m0 + r) * lda + k0 + c];
            int nr = n0 + r;
            Ws[r][c] = (nr < N) ? W[(size_t)nr * ldw + k0 + c] : 0.f;
        }
        __syncthreads();
        #pragma unroll
        for (int kk = 0; kk < 16; ++kk) {
            float av[4], wv[4];
            #pragma unroll
            for (int i = 0; i < 4; ++i) av[i] = As[ty * 4 + i][kk];
            #pragma unroll
            for (int j = 0; j < 4; ++j) wv[j] = Ws[tx * 4 + j][kk];
            #pragma unroll
            for (int i = 0; i < 4; ++i)
                #pragma unroll
                for (int j = 0; j < 4; ++j)
                    acc[i][j] += av[i] * wv[j];
        }
        __syncthreads();
    }

    #pragma unroll
    for (int i = 0; i < 4; ++i) {
        int m = m0 + ty * 4 + i;
        #pragma unroll
        for (int j = 0; j < 4; ++j) {
            int n = n0 + tx * 4 + j;
            if (n < N)
                C[(size_t)m * ldc + n] = acc[i][j];
        }
    }
}

// ---------------- causal depthwise conv + SiLU (float4 over d) ----------------
__global__ __launch_bounds__(256) void conv_silu_kernel(const float* __restrict__ xz,
                                                        const float* __restrict__ cw,
                                                        const float* __restrict__ cb,
                                                        float* __restrict__ u)
{
    int idx = blockIdx.x * 256 + threadIdx.x;   // over MROWS * DI/4
    int d4 = idx % (DI / 4);
    int bt = idx / (DI / 4);
    int t = bt % SEQ;
    int b = bt / SEQ;
    int d = d4 * 4;

    float4 w0 = *(const float4*)(cw + (d + 0) * 4);
    float4 w1 = *(const float4*)(cw + (d + 1) * 4);
    float4 w2 = *(const float4*)(cw + (d + 2) * 4);
    float4 w3 = *(const float4*)(cw + (d + 3) * 4);
    const float* wp[4] = { (const float*)&w0, (const float*)&w1,
                           (const float*)&w2, (const float*)&w3 };

    float4 acc = *(const float4*)(cb + d);
    #pragma unroll
    for (int k = 0; k < DCONV; ++k) {
        int tt = t - (DCONV - 1) + k;
        if (tt >= 0) {
            float4 xv = *(const float4*)(xz + (size_t)(b * SEQ + tt) * XZW + d);
            acc.x += xv.x * wp[0][k];
            acc.y += xv.y * wp[1][k];
            acc.z += xv.z * wp[2][k];
            acc.w += xv.w * wp[3][k];
        }
    }
    acc.x *= sigmoidf_(acc.x);
    acc.y *= sigmoidf_(acc.y);
    acc.z *= sigmoidf_(acc.z);
    acc.w *= sigmoidf_(acc.w);
    *(float4*)(u + (size_t)(b * SEQ + t) * DI + d) = acc;
}

// ---------------- chunked parallel selective scan + gate (bf16 y out) -------------
// One block per (b,d), XCD-swizzled. Threads = (chunk 0..15) x (n 0..15).
// B/C read from transposed BT/CT as float4; n-reduction via DPP row rotate-add.
__global__ __launch_bounds__(256) void scan_kernel(const float* __restrict__ delta,
                                                   const float* __restrict__ u,
                                                   const float* __restrict__ BT,
                                                   const float* __restrict__ CT,
                                                   const float* __restrict__ xz,
                                                   const float* __restrict__ A_log,
                                                   const float* __restrict__ Dp,
                                                   ushort_t* __restrict__ y)
{
    __shared__ float2 du_s[SEQ + NCHUNK];      // packed (delta, u), padded
    __shared__ float  g_s[SEQ + NCHUNK];       // silu(z) gate, padded
    __shared__ float Ps[DS][NCHUNK + 1];
    __shared__ float Ss[DS][NCHUNK + 1];
    __shared__ float Hin[DS][NCHUNK + 1];

    int tid = threadIdx.x;
    int n = tid & 15;
    int chunk = tid >> 4;
    int p_ = blockIdx.x;
    int g = (p_ & 7) * (BATCH * DI / 8) + (p_ >> 3);   // XCD-contiguous mapping
    int b = g / DI;
    int d = g % DI;

    const float* drow = delta + (size_t)b * SEQ * DI + d;
    const float* urow = u     + (size_t)b * SEQ * DI + d;
    const float* zrow = xz    + (size_t)b * SEQ * XZW + DI + d;

    // stage: (delta,u) pairs + precomputed gates, each global elem read once
    #pragma unroll
    for (int i = 0; i < SEQ / 256; ++i) {
        int t = tid + i * 256;
        du_s[PIDX(t)] = make_float2(drow[(size_t)t * DI], urow[(size_t)t * DI]);
        float z = zrow[(size_t)t * XZW];
        g_s[PIDX(t)] = z * sigmoidf_(z);
    }

    // fold log2(e) into a so dA = exp2(dlt * a) is a single v_exp_f32
    float a = -__expf(A_log[d * DS + n]) * 1.44269504f;
    int t0 = chunk * CLEN;
    const float* Bp = BT + ((size_t)b * DS + n) * SEQ + t0;
    const float* Cp = CT + ((size_t)b * DS + n) * SEQ + t0;
    __syncthreads();

    // Phase 1: chunk-local (P,S), h_in = 0 — B via contiguous float4
    float P = 1.f, S = 0.f;
    #pragma unroll 4
    for (int i4 = 0; i4 < CLEN / 4; ++i4) {
        float4 Bv = *(const float4*)(Bp + i4 * 4);
        const float* bv = (const float*)&Bv;
        #pragma unroll
        for (int j = 0; j < 4; ++j) {
            float2 du = du_s[PIDX(t0 + i4 * 4 + j)];
            float dA = exp2f(du.x * a);
            P *= dA;
            S = dA * S + (du.x * du.y) * bv[j];
        }
    }
    Ps[n][chunk] = P;
    Ss[n][chunk] = S;
    __syncthreads();

    // Phase 2: serial chunk combine (16 threads x 16 steps)
    if (tid < DS) {
        float h = 0.f;
        #pragma unroll
        for (int c = 0; c < NCHUNK; ++c) {
            Hin[tid][c] = h;
            h = Ps[tid][c] * h + Ss[tid][c];
        }
    }
    __syncthreads();

    // Phase 3: replay with correct h_in, contract C, DPP-reduce over n, gate, write
    float h = Hin[n][chunk];
    float Dd = Dp[d];
    ushort_t* yp = y + (size_t)b * SEQ * DI + (size_t)t0 * DI + d;
    #pragma unroll 4
    for (int i4 = 0; i4 < CLEN / 4; ++i4) {
        float4 Bv = *(const float4*)(Bp + i4 * 4);
        float4 Cv = *(const float4*)(Cp + i4 * 4);
        const float* bv = (const float*)&Bv;
        const float* cv = (const float*)&Cv;
        #pragma unroll
        for (int j = 0; j < 4; ++j) {
            int t = t0 + i4 * 4 + j;
            float2 du = du_s[PIDX(t)];
            float dA = exp2f(du.x * a);
            h = dA * h + (du.x * du.y) * bv[j];
            float p = row_sum16(h * cv[j]);
            if (n == 0)
                yp[(size_t)(i4 * 4 + j) * DI] = f2bf((p + du.y * Dd) * g_s[PIDX(t)]);
        }
    }
}

extern "C" void kernel_launch(void* const* d_in, const int* in_sizes, int n_in,
                              void* d_out, int out_size, void* d_ws, size_t ws_size,
                              hipStream_t stream) {
    const float* x         = (const float*)d_in[0];
    const float* ln_w      = (const float*)d_in[1];
    const float* ln_b      = (const float*)d_in[2];
    const float* in_proj_w = (const float*)d_in[3];   // (3072, 768)
    const float* conv_w    = (const float*)d_in[4];   // (1536, 4)
    const float* conv_b    = (const float*)d_in[5];   // (1536)
    const float* x_proj_w  = (const float*)d_in[6];   // (80, 1536)
    const float* dt_proj_w = (const float*)d_in[7];   // (1536, 48)
    const float* dt_proj_b = (const float*)d_in[8];   // (1536)
    const float* A_log     = (const float*)d_in[9];   // (1536, 16)
    const float* D_param   = (const float*)d_in[10];  // (1536)
    const float* out_proj_w= (const float*)d_in[11];  // (768, 1536)
    float* out = (float*)d_out;

    char* ws = (char*)d_ws;
    size_t off = 0;
    auto alloc = [&](size_t bytes) { void* p = ws + off; off += (bytes + 255) & ~255ull; return p; };

    ushort_t* xn_bf   = (ushort_t*)alloc((size_t)MROWS * DIM * 2);
    ushort_t* w_in_bf = (ushort_t*)alloc((size_t)XZW * DIM * 2);
    ushort_t* w_out_bf= (ushort_t*)alloc((size_t)DIM * DI * 2);
    ushort_t* y_bf    = (ushort_t*)alloc((size_t)MROWS * DI * 2);
    float* xz    = (float*)alloc((size_t)MROWS * XZW * 4);
    float* u     = (float*)alloc((size_t)MROWS * DI * 4);
    float* dbc   = (float*)alloc((size_t)MROWS * DBCW * 4);
    float* delta = (float*)alloc((size_t)MROWS * DI * 4);
    float* BT    = (float*)alloc((size_t)BATCH * DS * SEQ * 4);
    float* CT    = (float*)alloc((size_t)BATCH * DS * SEQ * 4);
    float* xpart = (float*)alloc((size_t)XP_KS * MROWS * DBCW * 4);
    float* opart = (float*)alloc((size_t)OP_KS * MROWS * DIM * 4);

    // 0. weight conversions
    hipLaunchKernelGGL(cvt_bf16, dim3((XZW * DIM) / 2048), dim3(256), 0, stream,
                       in_proj_w, w_in_bf, XZW * DIM);
    hipLaunchKernelGGL(cvt_bf16, dim3((DIM * DI) / 2048), dim3(256), 0, stream,
                       out_proj_w, w_out_bf, DIM * DI);

    // 1. LayerNorm -> bf16
    hipLaunchKernelGGL(ln_kernel, dim3(MROWS), dim3(256), 0, stream, x, ln_w, ln_b, xn_bf);

    // 2. in_proj (bf16 MFMA): xz(2048x3072) = xn @ in_proj_w^T
    hipLaunchKernelGGL(gemm_bf16, dim3(XZW / 128, MROWS / 128), dim3(256), 0, stream,
                       xn_bf, w_in_bf, xz, XZW, DIM);

    // 3. conv + silu -> u (fp32, float4)
    hipLaunchKernelGGL(conv_silu_kernel, dim3((MROWS * DI / 4) / 256), dim3(256), 0, stream,
                       xz, conv_w, conv_b, u);

    // 4. x_proj (fp32 split-K): dbc(2048x80) = u @ x_proj_w^T, + transposed BT/CT
    hipLaunchKernelGGL(gemm_nt_sk, dim3((DBCW + 63) / 64, MROWS / 64, XP_KS), dim3(256), 0, stream,
                       u, DI, x_proj_w, DI, xpart, DBCW, DBCW, DI / XP_KS, MROWS);
    hipLaunchKernelGGL(reduce_dbc, dim3((MROWS * DBCW + 255) / 256), dim3(256), 0, stream,
                       xpart, dbc, BT, CT);

    // 5. dt_proj + softplus (fp32): delta = softplus(dbc[:, :48] @ dt_proj_w^T + b)
    hipLaunchKernelGGL(gemm_nt, dim3(DI / 64, MROWS / 64), dim3(256), 0, stream,
                       dbc, DBCW, dt_proj_w, DTR, delta, DI, DI, DTR, dt_proj_b, 1);

    // 6. chunked scan + gate -> y (bf16), XCD-swizzled, DPP reduce
    hipLaunchKernelGGL(scan_kernel, dim3(BATCH * DI), dim3(256), 0, stream,
                       delta, u, BT, CT, xz, A_log, D_param, y_bf);

    // 7. out_proj (bf16 MFMA split-K): out(2048x768) = y @ out_proj_w^T
    hipLaunchKernelGGL(gemm_bf16_sk, dim3(DIM / 128, MROWS / 128, OP_KS), dim3(256), 0, stream,
                       y_bf, w_out_bf, opart, DIM, DI, DI / OP_KS, MROWS);
    hipLaunchKernelGGL(reduce_sk4, dim3((MROWS * DIM / 4 + 255) / 256), dim3(256), 0, stream,
                       (const float4*)opart, (float4*)out, MROWS * DIM / 4, OP_KS);
}

// Round 8
// 253.592 us; speedup vs baseline: 1.1348x; 1.1348x over previous
//
#include <hip/hip_runtime.h>
#include <hip/hip_bf16.h>

// Mamba layer: LN -> in_proj(bf16 MFMA) -> conv+silu -> x_proj(fp32 split-K)
//              -> dt_proj+softplus -> scan (n-in-registers, wave-scan combine) -> out_proj(bf16 MFMA split-K)
#define BATCH 2
#define SEQ   1024
#define DIM   768
#define DI    1536
#define DS    16
#define DCONV 4
#define DTR   48
#define XZW   (2*DI)     // 3072
#define DBCW  (DTR+2*DS) // 80
#define MROWS (BATCH*SEQ) // 2048
#define CL2   4          // timesteps per thread in scan (256 threads * 4 = SEQ)
#define XP_KS 8          // x_proj split-K slices
#define OP_KS 4          // out_proj split-K slices
#define PIDX2(t) ((t) + ((t) >> 2))   // pad every 4 t: de-conflicts lane-stride-4 float2 reads

typedef unsigned short ushort_t;
typedef __attribute__((ext_vector_type(8))) short short8;
typedef __attribute__((ext_vector_type(4))) float f32x4;

__device__ __forceinline__ float sigmoidf_(float x) {
    return 1.f / (1.f + __expf(-x));
}

__device__ __forceinline__ ushort_t f2bf(float x) {
    union { float f; unsigned u; } c{x};
    unsigned r = c.u + 0x7FFF + ((c.u >> 16) & 1);   // RNE
    return (ushort_t)(r >> 16);
}

__device__ __forceinline__ void gload16(const void* g, void* lds) {
    __builtin_amdgcn_global_load_lds(
        (const __attribute__((address_space(1))) void*)g,
        (__attribute__((address_space(3))) void*)lds,
        16, 0, 0);
}

// ---------------- fp32 -> bf16 conversion (8 elems/thread) ----------------
__global__ __launch_bounds__(256) void cvt_bf16(const float* __restrict__ in,
                                                ushort_t* __restrict__ out, int n)
{
    int i = (blockIdx.x * 256 + threadIdx.x) * 8;
    if (i >= n) return;
    float4 a = *(const float4*)(in + i);
    float4 b = *(const float4*)(in + i + 4);
    ushort_t o[8] = { f2bf(a.x), f2bf(a.y), f2bf(a.z), f2bf(a.w),
                      f2bf(b.x), f2bf(b.y), f2bf(b.z), f2bf(b.w) };
    *(ushort4*)(out + i)     = *(ushort4*)o;
    *(ushort4*)(out + i + 4) = *(ushort4*)(o + 4);
}

// ---------------- split-K partial reduce: out[i] = sum_z part[z][i] (float4) -------
__global__ __launch_bounds__(256) void reduce_sk4(const float4* __restrict__ part,
                                                  float4* __restrict__ out,
                                                  int count4, int nslices)
{
    int i = blockIdx.x * 256 + threadIdx.x;
    if (i >= count4) return;
    float4 s = part[i];
    for (int z = 1; z < nslices; ++z) {
        float4 p = part[(size_t)z * count4 + i];
        s.x += p.x; s.y += p.y; s.z += p.z; s.w += p.w;
    }
    out[i] = s;
}

// ---------------- LayerNorm (fp32 in, bf16 out), shfl-based ----------------
__global__ __launch_bounds__(256) void ln_kernel(const float* __restrict__ x,
                                                 const float* __restrict__ w,
                                                 const float* __restrict__ b,
                                                 ushort_t* __restrict__ xn)
{
    __shared__ float part[8];
    int row = blockIdx.x;               // 0..2047
    const float* xr = x + (size_t)row * DIM;
    ushort_t* o = xn + (size_t)row * DIM;
    int tid = threadIdx.x;
    int lane = tid & 63, wid = tid >> 6;

    float v0 = xr[tid], v1 = xr[tid + 256], v2 = xr[tid + 512];
    float s = v0 + v1 + v2;
    #pragma unroll
    for (int off = 32; off > 0; off >>= 1) s += __shfl_xor(s, off);
    if (lane == 0) part[wid] = s;
    __syncthreads();
    float mu = (part[0] + part[1] + part[2] + part[3]) * (1.f / DIM);

    float d0 = v0 - mu, d1 = v1 - mu, d2 = v2 - mu;
    float q = d0 * d0 + d1 * d1 + d2 * d2;
    #pragma unroll
    for (int off = 32; off > 0; off >>= 1) q += __shfl_xor(q, off);
    if (lane == 0) part[4 + wid] = q;
    __syncthreads();
    float rstd = rsqrtf((part[4] + part[5] + part[6] + part[7]) * (1.f / DIM) + 1e-5f);

    o[tid]       = f2bf(d0 * rstd * w[tid]       + b[tid]);
    o[tid + 256] = f2bf(d1 * rstd * w[tid + 256] + b[tid + 256]);
    o[tid + 512] = f2bf(d2 * rstd * w[tid + 512] + b[tid + 512]);
}

// ---------------- bf16 MFMA GEMM: C(MxN fp32) = A(MxK bf16) @ W(NxK bf16)^T ----------
__global__ __launch_bounds__(256) void gemm_bf16(const ushort_t* __restrict__ A,
                                                 const ushort_t* __restrict__ W,
                                                 float* __restrict__ C,
                                                 int N, int K)
{
    __shared__ __align__(16) ushort_t As[128 * 32];
    __shared__ __align__(16) ushort_t Bs[128 * 32];

    int tid = threadIdx.x;
    int wave = tid >> 6, lane = tid & 63;
    int wr = wave >> 1, wc = wave & 1;
    int l15 = lane & 15, kb = lane >> 4;
    int m0 = blockIdx.y * 128, n0 = blockIdx.x * 128;

    f32x4 acc[4][4] = {};

    for (int k0 = 0; k0 < K; k0 += 32) {
        #pragma unroll
        for (int i = 0; i < 2; ++i) {
            int cbase = i * 256 + wave * 64;
            int c = cbase + lane;
            int row = c >> 2;
            int col = (c & 3) * 8;
            gload16(A + (size_t)(m0 + row) * K + k0 + col, (char*)As + (size_t)cbase * 16);
            gload16(W + (size_t)(n0 + row) * K + k0 + col, (char*)Bs + (size_t)cbase * 16);
        }
        __syncthreads();

        short8 af[4], bfr[4];
        #pragma unroll
        for (int m = 0; m < 4; ++m)
            af[m] = *(const short8*)&As[(wr * 64 + m * 16 + l15) * 32 + kb * 8];
        #pragma unroll
        for (int n = 0; n < 4; ++n)
            bfr[n] = *(const short8*)&Bs[(wc * 64 + n * 16 + l15) * 32 + kb * 8];

        #pragma unroll
        for (int m = 0; m < 4; ++m)
            #pragma unroll
            for (int n = 0; n < 4; ++n)
                acc[m][n] = __builtin_amdgcn_mfma_f32_16x16x32_bf16(af[m], bfr[n], acc[m][n], 0, 0, 0);

        __syncthreads();
    }

    int r0 = m0 + wr * 64 + kb * 4;
    int c0 = n0 + wc * 64 + l15;
    #pragma unroll
    for (int m = 0; m < 4; ++m)
        #pragma unroll
        for (int n = 0; n < 4; ++n) {
            int rr = r0 + m * 16;
            int cc = c0 + n * 16;
            #pragma unroll
            for (int r = 0; r < 4; ++r)
                C[(size_t)(rr + r) * N + cc] = acc[m][n][r];
        }
}

// ---- split-K bf16 MFMA GEMM: Cpart[z] = A @ W^T over K-slice z (z = blockIdx.z) ----
__global__ __launch_bounds__(256) void gemm_bf16_sk(const ushort_t* __restrict__ A,
                                                    const ushort_t* __restrict__ W,
                                                    float* __restrict__ Cpart,
                                                    int N, int Ktot, int Kslice, int M)
{
    __shared__ __align__(16) ushort_t As[128 * 32];
    __shared__ __align__(16) ushort_t Bs[128 * 32];

    int tid = threadIdx.x;
    int wave = tid >> 6, lane = tid & 63;
    int wr = wave >> 1, wc = wave & 1;
    int l15 = lane & 15, kb = lane >> 4;
    int m0 = blockIdx.y * 128, n0 = blockIdx.x * 128;
    int kbase = blockIdx.z * Kslice;
    float* C = Cpart + (size_t)blockIdx.z * M * N;

    f32x4 acc[4][4] = {};

    for (int k0 = kbase; k0 < kbase + Kslice; k0 += 32) {
        #pragma unroll
        for (int i = 0; i < 2; ++i) {
            int cbase = i * 256 + wave * 64;
            int c = cbase + lane;
            int row = c >> 2;
            int col = (c & 3) * 8;
            gload16(A + (size_t)(m0 + row) * Ktot + k0 + col, (char*)As + (size_t)cbase * 16);
            gload16(W + (size_t)(n0 + row) * Ktot + k0 + col, (char*)Bs + (size_t)cbase * 16);
        }
        __syncthreads();

        short8 af[4], bfr[4];
        #pragma unroll
        for (int m = 0; m < 4; ++m)
            af[m] = *(const short8*)&As[(wr * 64 + m * 16 + l15) * 32 + kb * 8];
        #pragma unroll
        for (int n = 0; n < 4; ++n)
            bfr[n] = *(const short8*)&Bs[(wc * 64 + n * 16 + l15) * 32 + kb * 8];

        #pragma unroll
        for (int m = 0; m < 4; ++m)
            #pragma unroll
            for (int n = 0; n < 4; ++n)
                acc[m][n] = __builtin_amdgcn_mfma_f32_16x16x32_bf16(af[m], bfr[n], acc[m][n], 0, 0, 0);

        __syncthreads();
    }

    int r0 = m0 + wr * 64 + kb * 4;
    int c0 = n0 + wc * 64 + l15;
    #pragma unroll
    for (int m = 0; m < 4; ++m)
        #pragma unroll
        for (int n = 0; n < 4; ++n) {
            int rr = r0 + m * 16;
            int cc = c0 + n * 16;
            #pragma unroll
            for (int r = 0; r < 4; ++r)
                C[(size_t)(rr + r) * N + cc] = acc[m][n][r];
        }
}

// ---------------- Generic tiled fp32 GEMM: C = act(A @ W^T + bias) ----------------
__global__ __launch_bounds__(256) void gemm_nt(const float* __restrict__ A, int lda,
                                               const float* __restrict__ W, int ldw,
                                               float* __restrict__ C, int ldc,
                                               int N, int K,
                                               const float* __restrict__ bias, int act)
{
    __shared__ float As[64][17];
    __shared__ float Ws[64][17];
    int tid = threadIdx.x;
    int tx = tid & 15;
    int ty = tid >> 4;
    int m0 = blockIdx.y * 64;
    int n0 = blockIdx.x * 64;

    float acc[4][4] = {};

    for (int k0 = 0; k0 < K; k0 += 16) {
        #pragma unroll
        for (int i = 0; i < 4; ++i) {
            int idx = tid + i * 256;
            int r = idx >> 4, c = idx & 15;
            As[r][c] = A[(size_t)(m0 + r) * lda + k0 + c];
            int nr = n0 + r;
            Ws[r][c] = (nr < N) ? W[(size_t)nr * ldw + k0 + c] : 0.f;
        }
        __syncthreads();
        #pragma unroll
        for (int kk = 0; kk < 16; ++kk) {
            float av[4], wv[4];
            #pragma unroll
            for (int i = 0; i < 4; ++i) av[i] = As[ty * 4 + i][kk];
            #pragma unroll
            for (int j = 0; j < 4; ++j) wv[j] = Ws[tx * 4 + j][kk];
            #pragma unroll
            for (int i = 0; i < 4; ++i)
                #pragma unroll
                for (int j = 0; j < 4; ++j)
                    acc[i][j] += av[i] * wv[j];
        }
        __syncthreads();
    }

    #pragma unroll
    for (int i = 0; i < 4; ++i) {
        int m = m0 + ty * 4 + i;
        #pragma unroll
        for (int j = 0; j < 4; ++j) {
            int n = n0 + tx * 4 + j;
            if (n < N) {
                float v = acc[i][j];
                if (bias) v += bias[n];
                if (act == 1) v = (v > 20.f) ? v : log1pf(__expf(v));
                C[(size_t)m * ldc + n] = v;
            }
        }
    }
}

// ---- split-K fp32 GEMM: Cpart[z] = A @ W^T over K-slice z (no bias/act) ----
__global__ __launch_bounds__(256) void gemm_nt_sk(const float* __restrict__ A, int lda,
                                                  const float* __restrict__ W, int ldw,
                                                  float* __restrict__ Cpart, int ldc,
                                                  int N, int Kslice, int M)
{
    __shared__ float As[64][17];
    __shared__ float Ws[64][17];
    int tid = threadIdx.x;
    int tx = tid & 15;
    int ty = tid >> 4;
    int m0 = blockIdx.y * 64;
    int n0 = blockIdx.x * 64;
    int kbase = blockIdx.z * Kslice;
    float* C = Cpart + (size_t)blockIdx.z * M * ldc;

    float acc[4][4] = {};

    for (int k0 = kbase; k0 < kbase + Kslice; k0 += 16) {
        #pragma unroll
        for (int i = 0; i < 4; ++i) {
            int idx = tid + i * 256;
            int r = idx >> 4, c = idx & 15;
            As[r][c] = A[(size_t)(m0 + r) * lda + k0 + c];
            int nr = n0 + r;
            Ws[r][c] = (nr < N) ? W[(size_t)nr * ldw + k0 + c] : 0.f;
        }
        __syncthreads();
        #pragma unroll
        for (int kk = 0; kk < 16; ++kk) {
            float av[4], wv[4];
            #pragma unroll
            for (int i = 0; i < 4; ++i) av[i] = As[ty * 4 + i][kk];
            #pragma unroll
            for (int j = 0; j < 4; ++j) wv[j] = Ws[tx * 4 + j][kk];
            #pragma unroll
            for (int i = 0; i < 4; ++i)
                #pragma unroll
                for (int j = 0; j < 4; ++j)
                    acc[i][j] += av[i] * wv[j];
        }
        __syncthreads();
    }

    #pragma unroll
    for (int i = 0; i < 4; ++i) {
        int m = m0 + ty * 4 + i;
        #pragma unroll
        for (int j = 0; j < 4; ++j) {
            int n = n0 + tx * 4 + j;
            if (n < N)
                C[(size_t)m * ldc + n] = acc[i][j];
        }
    }
}

// ---------------- causal depthwise conv + SiLU (float4 over d) ----------------
__global__ __launch_bounds__(256) void conv_silu_kernel(const float* __restrict__ xz,
                                                        const float* __restrict__ cw,
                                                        const float* __restrict__ cb,
                                                        float* __restrict__ u)
{
    int idx = blockIdx.x * 256 + threadIdx.x;   // over MROWS * DI/4
    int d4 = idx % (DI / 4);
    int bt = idx / (DI / 4);
    int t = bt % SEQ;
    int b = bt / SEQ;
    int d = d4 * 4;

    float4 w0 = *(const float4*)(cw + (d + 0) * 4);
    float4 w1 = *(const float4*)(cw + (d + 1) * 4);
    float4 w2 = *(const float4*)(cw + (d + 2) * 4);
    float4 w3 = *(const float4*)(cw + (d + 3) * 4);
    const float* wp[4] = { (const float*)&w0, (const float*)&w1,
                           (const float*)&w2, (const float*)&w3 };

    float4 acc = *(const float4*)(cb + d);
    #pragma unroll
    for (int k = 0; k < DCONV; ++k) {
        int tt = t - (DCONV - 1) + k;
        if (tt >= 0) {
            float4 xv = *(const float4*)(xz + (size_t)(b * SEQ + tt) * XZW + d);
            acc.x += xv.x * wp[0][k];
            acc.y += xv.y * wp[1][k];
            acc.z += xv.z * wp[2][k];
            acc.w += xv.w * wp[3][k];
        }
    }
    acc.x *= sigmoidf_(acc.x);
    acc.y *= sigmoidf_(acc.y);
    acc.z *= sigmoidf_(acc.z);
    acc.w *= sigmoidf_(acc.w);
    *(float4*)(u + (size_t)(b * SEQ + t) * DI + d) = acc;
}

// ---------------- selective scan: n-in-registers + Kogge-Stone wave scan ----------
// One block per (b,d), XCD-swizzled. Each thread owns CL2=4 timesteps and ALL 16
// states in registers: no cross-lane ops per t. Chunk combine: inclusive wave scan
// over 64 lanes (composition op) + cross-wave prefix via tiny LDS.
__global__ __launch_bounds__(256) void scan_kernel(const float* __restrict__ delta,
                                                   const float* __restrict__ u,
                                                   const float* __restrict__ dbc,
                                                   const float* __restrict__ xz,
                                                   const float* __restrict__ A_log,
                                                   const float* __restrict__ Dp,
                                                   ushort_t* __restrict__ y)
{
    __shared__ float2 du_s[SEQ + SEQ / 4];     // (delta,u) padded every 4 t
    __shared__ float waggP[4][DS], waggS[4][DS];
    __shared__ float wpP[4][DS], wpS[4][DS];

    int tid = threadIdx.x;
    int lane = tid & 63, w = tid >> 6;
    int p_ = blockIdx.x;
    int g = (p_ & 7) * (BATCH * DI / 8) + (p_ >> 3);   // XCD-contiguous mapping
    int b = g / DI;
    int d = g % DI;

    const float* drow = delta + (size_t)b * SEQ * DI + d;
    const float* urow = u     + (size_t)b * SEQ * DI + d;
    const float* zrow = xz    + (size_t)b * SEQ * XZW + DI + d;
    const float* bbase = dbc  + (size_t)b * SEQ * DBCW + DTR;

    // stage (delta, u) column
    #pragma unroll
    for (int i = 0; i < SEQ / 256; ++i) {
        int t = tid + i * 256;
        du_s[PIDX2(t)] = make_float2(drow[(size_t)t * DI], urow[(size_t)t * DI]);
    }

    // per-state decay constants (log2-folded)
    float a[DS];
    {
        const float4* Ar = (const float4*)(A_log + d * DS);
        float4 a0 = Ar[0], a1 = Ar[1], a2 = Ar[2], a3 = Ar[3];
        float al[DS] = { a0.x, a0.y, a0.z, a0.w, a1.x, a1.y, a1.z, a1.w,
                         a2.x, a2.y, a2.z, a2.w, a3.x, a3.y, a3.z, a3.w };
        #pragma unroll
        for (int n = 0; n < DS; ++n) a[n] = -__expf(al[n]) * 1.44269504f;
    }

    int t0 = tid * CL2;
    __syncthreads();

    // Phase 1: chunk-local (P,S) per state, h_in = 0
    float P[DS], S[DS];
    #pragma unroll
    for (int n = 0; n < DS; ++n) { P[n] = 1.f; S[n] = 0.f; }
    #pragma unroll
    for (int j = 0; j < CL2; ++j) {
        int t = t0 + j;
        float2 du = du_s[PIDX2(t)];
        float dltu = du.x * du.y;
        const float4* Bt = (const float4*)(bbase + (size_t)t * DBCW);
        float Bf[DS];
        *(float4*)(&Bf[0])  = Bt[0];
        *(float4*)(&Bf[4])  = Bt[1];
        *(float4*)(&Bf[8])  = Bt[2];
        *(float4*)(&Bf[12]) = Bt[3];
        #pragma unroll
        for (int n = 0; n < DS; ++n) {
            float dA = exp2f(du.x * a[n]);
            P[n] *= dA;
            S[n] = dA * S[n] + dltu * Bf[n];
        }
    }

    // Kogge-Stone inclusive scan over 64 lanes (chunks in lane order)
    // compose earlier(up) then current: S = P_cur*S_up + S_cur; P = P_up*P_cur
    #pragma unroll
    for (int off = 1; off < 64; off <<= 1) {
        float Pu[DS], Su[DS];
        #pragma unroll
        for (int n = 0; n < DS; ++n) {
            Pu[n] = __shfl_up(P[n], off);
            Su[n] = __shfl_up(S[n], off);
        }
        if (lane >= off) {
            #pragma unroll
            for (int n = 0; n < DS; ++n) {
                S[n] = P[n] * Su[n] + S[n];
                P[n] = Pu[n] * P[n];
            }
        }
    }

    // cross-wave prefix
    if (lane == 63) {
        #pragma unroll
        for (int n = 0; n < DS; ++n) { waggP[w][n] = P[n]; waggS[w][n] = S[n]; }
    }
    __syncthreads();
    if (tid < DS) {
        int n = tid;
        float Pa = 1.f, Sa = 0.f;
        #pragma unroll
        for (int wv = 0; wv < 4; ++wv) {
            wpP[wv][n] = Pa;
            wpS[wv][n] = Sa;
            Sa = waggP[wv][n] * Sa + waggS[wv][n];
            Pa = Pa * waggP[wv][n];
        }
    }
    __syncthreads();

    // h_in = (wave_prefix ∘ lane_exclusive) applied to 0
    float h[DS];
    #pragma unroll
    for (int n = 0; n < DS; ++n) {
        float Pex = __shfl_up(P[n], 1);
        float Sex = __shfl_up(S[n], 1);
        if (lane == 0) { Pex = 1.f; Sex = 0.f; }
        h[n] = Pex * wpS[w][n] + Sex;
    }

    // Phase 3: replay chunk with correct h_in, dot with C in-register, gate, write
    float Dd = Dp[d];
    ushort_t* yrow = y + (size_t)b * SEQ * DI + d;
    #pragma unroll
    for (int j = 0; j < CL2; ++j) {
        int t = t0 + j;
        float2 du = du_s[PIDX2(t)];
        float dltu = du.x * du.y;
        const float4* Bt = (const float4*)(bbase + (size_t)t * DBCW);
        const float4* Ct = (const float4*)(bbase + DS + (size_t)t * DBCW);
        float Bf[DS], Cf[DS];
        *(float4*)(&Bf[0])  = Bt[0];
        *(float4*)(&Bf[4])  = Bt[1];
        *(float4*)(&Bf[8])  = Bt[2];
        *(float4*)(&Bf[12]) = Bt[3];
        *(float4*)(&Cf[0])  = Ct[0];
        *(float4*)(&Cf[4])  = Ct[1];
        *(float4*)(&Cf[8])  = Ct[2];
        *(float4*)(&Cf[12]) = Ct[3];
        #pragma unroll
        for (int n = 0; n < DS; ++n) {
            float dA = exp2f(du.x * a[n]);
            h[n] = dA * h[n] + dltu * Bf[n];
        }
        float p0 = 0.f, p1 = 0.f, p2 = 0.f, p3 = 0.f;
        #pragma unroll
        for (int n = 0; n < DS; n += 4) {
            p0 += h[n] * Cf[n];
            p1 += h[n + 1] * Cf[n + 1];
            p2 += h[n + 2] * Cf[n + 2];
            p3 += h[n + 3] * Cf[n + 3];
        }
        float p = (p0 + p1) + (p2 + p3);
        float z = zrow[(size_t)t * XZW];
        float yv = (p + du.y * Dd) * (z * sigmoidf_(z));
        yrow[(size_t)t * DI] = f2bf(yv);
    }
}

extern "C" void kernel_launch(void* const* d_in, const int* in_sizes, int n_in,
                              void* d_out, int out_size, void* d_ws, size_t ws_size,
                              hipStream_t stream) {
    const float* x         = (const float*)d_in[0];
    const float* ln_w      = (const float*)d_in[1];
    const float* ln_b      = (const float*)d_in[2];
    const float* in_proj_w = (const float*)d_in[3];   // (3072, 768)
    const float* conv_w    = (const float*)d_in[4];   // (1536, 4)
    const float* conv_b    = (const float*)d_in[5];   // (1536)
    const float* x_proj_w  = (const float*)d_in[6];   // (80, 1536)
    const float* dt_proj_w = (const float*)d_in[7];   // (1536, 48)
    const float* dt_proj_b = (const float*)d_in[8];   // (1536)
    const float* A_log     = (const float*)d_in[9];   // (1536, 16)
    const float* D_param   = (const float*)d_in[10];  // (1536)
    const float* out_proj_w= (const float*)d_in[11];  // (768, 1536)
    float* out = (float*)d_out;

    char* ws = (char*)d_ws;
    size_t off = 0;
    auto alloc = [&](size_t bytes) { void* p = ws + off; off += (bytes + 255) & ~255ull; return p; };

    ushort_t* xn_bf   = (ushort_t*)alloc((size_t)MROWS * DIM * 2);
    ushort_t* w_in_bf = (ushort_t*)alloc((size_t)XZW * DIM * 2);
    ushort_t* w_out_bf= (ushort_t*)alloc((size_t)DIM * DI * 2);
    ushort_t* y_bf    = (ushort_t*)alloc((size_t)MROWS * DI * 2);
    float* xz    = (float*)alloc((size_t)MROWS * XZW * 4);
    float* u     = (float*)alloc((size_t)MROWS * DI * 4);
    float* dbc   = (float*)alloc((size_t)MROWS * DBCW * 4);
    float* delta = (float*)alloc((size_t)MROWS * DI * 4);
    float* xpart = (float*)alloc((size_t)XP_KS * MROWS * DBCW * 4);
    float* opart = (float*)alloc((size_t)OP_KS * MROWS * DIM * 4);

    // 0. weight conversions
    hipLaunchKernelGGL(cvt_bf16, dim3((XZW * DIM) / 2048), dim3(256), 0, stream,
                       in_proj_w, w_in_bf, XZW * DIM);
    hipLaunchKernelGGL(cvt_bf16, dim3((DIM * DI) / 2048), dim3(256), 0, stream,
                       out_proj_w, w_out_bf, DIM * DI);

    // 1. LayerNorm -> bf16
    hipLaunchKernelGGL(ln_kernel, dim3(MROWS), dim3(256), 0, stream, x, ln_w, ln_b, xn_bf);

    // 2. in_proj (bf16 MFMA): xz(2048x3072) = xn @ in_proj_w^T
    hipLaunchKernelGGL(gemm_bf16, dim3(XZW / 128, MROWS / 128), dim3(256), 0, stream,
                       xn_bf, w_in_bf, xz, XZW, DIM);

    // 3. conv + silu -> u (fp32, float4)
    hipLaunchKernelGGL(conv_silu_kernel, dim3((MROWS * DI / 4) / 256), dim3(256), 0, stream,
                       xz, conv_w, conv_b, u);

    // 4. x_proj (fp32 split-K): dbc(2048x80) = u @ x_proj_w^T
    hipLaunchKernelGGL(gemm_nt_sk, dim3((DBCW + 63) / 64, MROWS / 64, XP_KS), dim3(256), 0, stream,
                       u, DI, x_proj_w, DI, xpart, DBCW, DBCW, DI / XP_KS, MROWS);
    hipLaunchKernelGGL(reduce_sk4, dim3((MROWS * DBCW / 4 + 255) / 256), dim3(256), 0, stream,
                       (const float4*)xpart, (float4*)dbc, MROWS * DBCW / 4, XP_KS);

    // 5. dt_proj + softplus (fp32): delta = softplus(dbc[:, :48] @ dt_proj_w^T + b)
    hipLaunchKernelGGL(gemm_nt, dim3(DI / 64, MROWS / 64), dim3(256), 0, stream,
                       dbc, DBCW, dt_proj_w, DTR, delta, DI, DI, DTR, dt_proj_b, 1);

    // 6. scan + gate -> y (bf16), XCD-swizzled, n-in-registers
    hipLaunchKernelGGL(scan_kernel, dim3(BATCH * DI), dim3(256), 0, stream,
                       delta, u, dbc, xz, A_log, D_param, y_bf);

    // 7. out_proj (bf16 MFMA split-K): out(2048x768) = y @ out_proj_w^T
    hipLaunchKernelGGL(gemm_bf16_sk, dim3(DIM / 128, MROWS / 128, OP_KS), dim3(256), 0, stream,
                       y_bf, w_out_bf, opart, DIM, DI, DI / OP_KS, MROWS);
    hipLaunchKernelGGL(reduce_sk4, dim3((MROWS * DIM / 4 + 255) / 256), dim3(256), 0, stream,
                       (const float4*)opart, (float4*)out, MROWS * DIM / 4, OP_KS);
}

// Round 9
// 205.685 us; speedup vs baseline: 1.3991x; 1.2329x over previous
//
#include <hip/hip_runtime.h>
#include <hip/hip_bf16.h>

// Mamba layer: LN -> in_proj(bf16 MFMA) -> conv+silu -> x_proj(fp32 split-K)
//              -> dt_proj+softplus -> scan (lane=channel, 3-kernel chunked) -> out_proj(bf16 MFMA split-K)
#define BATCH 2
#define SEQ   1024
#define DIM   768
#define DI    1536
#define DS    16
#define DCONV 4
#define DTR   48
#define XZW   (2*DI)     // 3072
#define DBCW  (DTR+2*DS) // 80
#define MROWS (BATCH*SEQ) // 2048
#define NCHUNK 32
#define CLEN  (SEQ/NCHUNK) // 32
#define XP_KS 8          // x_proj split-K slices
#define OP_KS 4          // out_proj split-K slices

typedef unsigned short ushort_t;
typedef __attribute__((ext_vector_type(8))) short short8;
typedef __attribute__((ext_vector_type(4))) float f32x4;

__device__ __forceinline__ float sigmoidf_(float x) {
    return 1.f / (1.f + __expf(-x));
}

__device__ __forceinline__ ushort_t f2bf(float x) {
    union { float f; unsigned u; } c{x};
    unsigned r = c.u + 0x7FFF + ((c.u >> 16) & 1);   // RNE
    return (ushort_t)(r >> 16);
}

__device__ __forceinline__ void gload16(const void* g, void* lds) {
    __builtin_amdgcn_global_load_lds(
        (const __attribute__((address_space(1))) void*)g,
        (__attribute__((address_space(3))) void*)lds,
        16, 0, 0);
}

// ---------------- fp32 -> bf16 conversion (8 elems/thread) ----------------
__global__ __launch_bounds__(256) void cvt_bf16(const float* __restrict__ in,
                                                ushort_t* __restrict__ out, int n)
{
    int i = (blockIdx.x * 256 + threadIdx.x) * 8;
    if (i >= n) return;
    float4 a = *(const float4*)(in + i);
    float4 b = *(const float4*)(in + i + 4);
    ushort_t o[8] = { f2bf(a.x), f2bf(a.y), f2bf(a.z), f2bf(a.w),
                      f2bf(b.x), f2bf(b.y), f2bf(b.z), f2bf(b.w) };
    *(ushort4*)(out + i)     = *(ushort4*)o;
    *(ushort4*)(out + i + 4) = *(ushort4*)(o + 4);
}

// ---------------- A_log transpose: aT[n][d] = -exp(A_log[d][n]) * log2(e) ----------
__global__ __launch_bounds__(256) void at_kernel(const float* __restrict__ A_log,
                                                 float* __restrict__ aT)
{
    int i = blockIdx.x * 256 + threadIdx.x;   // i = n*DI + d
    if (i >= DS * DI) return;
    int n = i / DI, d = i % DI;
    aT[i] = -__expf(A_log[d * DS + n]) * 1.44269504f;
}

// ---------------- split-K partial reduce: out[i] = sum_z part[z][i] (float4) -------
__global__ __launch_bounds__(256) void reduce_sk4(const float4* __restrict__ part,
                                                  float4* __restrict__ out,
                                                  int count4, int nslices)
{
    int i = blockIdx.x * 256 + threadIdx.x;
    if (i >= count4) return;
    float4 s = part[i];
    for (int z = 1; z < nslices; ++z) {
        float4 p = part[(size_t)z * count4 + i];
        s.x += p.x; s.y += p.y; s.z += p.z; s.w += p.w;
    }
    out[i] = s;
}

// ---------------- LayerNorm (fp32 in, bf16 out), shfl-based ----------------
__global__ __launch_bounds__(256) void ln_kernel(const float* __restrict__ x,
                                                 const float* __restrict__ w,
                                                 const float* __restrict__ b,
                                                 ushort_t* __restrict__ xn)
{
    __shared__ float part[8];
    int row = blockIdx.x;               // 0..2047
    const float* xr = x + (size_t)row * DIM;
    ushort_t* o = xn + (size_t)row * DIM;
    int tid = threadIdx.x;
    int lane = tid & 63, wid = tid >> 6;

    float v0 = xr[tid], v1 = xr[tid + 256], v2 = xr[tid + 512];
    float s = v0 + v1 + v2;
    #pragma unroll
    for (int off = 32; off > 0; off >>= 1) s += __shfl_xor(s, off);
    if (lane == 0) part[wid] = s;
    __syncthreads();
    float mu = (part[0] + part[1] + part[2] + part[3]) * (1.f / DIM);

    float d0 = v0 - mu, d1 = v1 - mu, d2 = v2 - mu;
    float q = d0 * d0 + d1 * d1 + d2 * d2;
    #pragma unroll
    for (int off = 32; off > 0; off >>= 1) q += __shfl_xor(q, off);
    if (lane == 0) part[4 + wid] = q;
    __syncthreads();
    float rstd = rsqrtf((part[4] + part[5] + part[6] + part[7]) * (1.f / DIM) + 1e-5f);

    o[tid]       = f2bf(d0 * rstd * w[tid]       + b[tid]);
    o[tid + 256] = f2bf(d1 * rstd * w[tid + 256] + b[tid + 256]);
    o[tid + 512] = f2bf(d2 * rstd * w[tid + 512] + b[tid + 512]);
}

// ---------------- bf16 MFMA GEMM: C(MxN fp32) = A(MxK bf16) @ W(NxK bf16)^T ----------
__global__ __launch_bounds__(256) void gemm_bf16(const ushort_t* __restrict__ A,
                                                 const ushort_t* __restrict__ W,
                                                 float* __restrict__ C,
                                                 int N, int K)
{
    __shared__ __align__(16) ushort_t As[128 * 32];
    __shared__ __align__(16) ushort_t Bs[128 * 32];

    int tid = threadIdx.x;
    int wave = tid >> 6, lane = tid & 63;
    int wr = wave >> 1, wc = wave & 1;
    int l15 = lane & 15, kb = lane >> 4;
    int m0 = blockIdx.y * 128, n0 = blockIdx.x * 128;

    f32x4 acc[4][4] = {};

    for (int k0 = 0; k0 < K; k0 += 32) {
        #pragma unroll
        for (int i = 0; i < 2; ++i) {
            int cbase = i * 256 + wave * 64;
            int c = cbase + lane;
            int row = c >> 2;
            int col = (c & 3) * 8;
            gload16(A + (size_t)(m0 + row) * K + k0 + col, (char*)As + (size_t)cbase * 16);
            gload16(W + (size_t)(n0 + row) * K + k0 + col, (char*)Bs + (size_t)cbase * 16);
        }
        __syncthreads();

        short8 af[4], bfr[4];
        #pragma unroll
        for (int m = 0; m < 4; ++m)
            af[m] = *(const short8*)&As[(wr * 64 + m * 16 + l15) * 32 + kb * 8];
        #pragma unroll
        for (int n = 0; n < 4; ++n)
            bfr[n] = *(const short8*)&Bs[(wc * 64 + n * 16 + l15) * 32 + kb * 8];

        #pragma unroll
        for (int m = 0; m < 4; ++m)
            #pragma unroll
            for (int n = 0; n < 4; ++n)
                acc[m][n] = __builtin_amdgcn_mfma_f32_16x16x32_bf16(af[m], bfr[n], acc[m][n], 0, 0, 0);

        __syncthreads();
    }

    int r0 = m0 + wr * 64 + kb * 4;
    int c0 = n0 + wc * 64 + l15;
    #pragma unroll
    for (int m = 0; m < 4; ++m)
        #pragma unroll
        for (int n = 0; n < 4; ++n) {
            int rr = r0 + m * 16;
            int cc = c0 + n * 16;
            #pragma unroll
            for (int r = 0; r < 4; ++r)
                C[(size_t)(rr + r) * N + cc] = acc[m][n][r];
        }
}

// ---- split-K bf16 MFMA GEMM: Cpart[z] = A @ W^T over K-slice z (z = blockIdx.z) ----
__global__ __launch_bounds__(256) void gemm_bf16_sk(const ushort_t* __restrict__ A,
                                                    const ushort_t* __restrict__ W,
                                                    float* __restrict__ Cpart,
                                                    int N, int Ktot, int Kslice, int M)
{
    __shared__ __align__(16) ushort_t As[128 * 32];
    __shared__ __align__(16) ushort_t Bs[128 * 32];

    int tid = threadIdx.x;
    int wave = tid >> 6, lane = tid & 63;
    int wr = wave >> 1, wc = wave & 1;
    int l15 = lane & 15, kb = lane >> 4;
    int m0 = blockIdx.y * 128, n0 = blockIdx.x * 128;
    int kbase = blockIdx.z * Kslice;
    float* C = Cpart + (size_t)blockIdx.z * M * N;

    f32x4 acc[4][4] = {};

    for (int k0 = kbase; k0 < kbase + Kslice; k0 += 32) {
        #pragma unroll
        for (int i = 0; i < 2; ++i) {
            int cbase = i * 256 + wave * 64;
            int c = cbase + lane;
            int row = c >> 2;
            int col = (c & 3) * 8;
            gload16(A + (size_t)(m0 + row) * Ktot + k0 + col, (char*)As + (size_t)cbase * 16);
            gload16(W + (size_t)(n0 + row) * Ktot + k0 + col, (char*)Bs + (size_t)cbase * 16);
        }
        __syncthreads();

        short8 af[4], bfr[4];
        #pragma unroll
        for (int m = 0; m < 4; ++m)
            af[m] = *(const short8*)&As[(wr * 64 + m * 16 + l15) * 32 + kb * 8];
        #pragma unroll
        for (int n = 0; n < 4; ++n)
            bfr[n] = *(const short8*)&Bs[(wc * 64 + n * 16 + l15) * 32 + kb * 8];

        #pragma unroll
        for (int m = 0; m < 4; ++m)
            #pragma unroll
            for (int n = 0; n < 4; ++n)
                acc[m][n] = __builtin_amdgcn_mfma_f32_16x16x32_bf16(af[m], bfr[n], acc[m][n], 0, 0, 0);

        __syncthreads();
    }

    int r0 = m0 + wr * 64 + kb * 4;
    int c0 = n0 + wc * 64 + l15;
    #pragma unroll
    for (int m = 0; m < 4; ++m)
        #pragma unroll
        for (int n = 0; n < 4; ++n) {
            int rr = r0 + m * 16;
            int cc = c0 + n * 16;
            #pragma unroll
            for (int r = 0; r < 4; ++r)
                C[(size_t)(rr + r) * N + cc] = acc[m][n][r];
        }
}

// ---------------- Generic tiled fp32 GEMM: C = act(A @ W^T + bias) ----------------
__global__ __launch_bounds__(256) void gemm_nt(const float* __restrict__ A, int lda,
                                               const float* __restrict__ W, int ldw,
                                               float* __restrict__ C, int ldc,
                                               int N, int K,
                                               const float* __restrict__ bias, int act)
{
    __shared__ float As[64][17];
    __shared__ float Ws[64][17];
    int tid = threadIdx.x;
    int tx = tid & 15;
    int ty = tid >> 4;
    int m0 = blockIdx.y * 64;
    int n0 = blockIdx.x * 64;

    float acc[4][4] = {};

    for (int k0 = 0; k0 < K; k0 += 16) {
        #pragma unroll
        for (int i = 0; i < 4; ++i) {
            int idx = tid + i * 256;
            int r = idx >> 4, c = idx & 15;
            As[r][c] = A[(size_t)(m0 + r) * lda + k0 + c];
            int nr = n0 + r;
            Ws[r][c] = (nr < N) ? W[(size_t)nr * ldw + k0 + c] : 0.f;
        }
        __syncthreads();
        #pragma unroll
        for (int kk = 0; kk < 16; ++kk) {
            float av[4], wv[4];
            #pragma unroll
            for (int i = 0; i < 4; ++i) av[i] = As[ty * 4 + i][kk];
            #pragma unroll
            for (int j = 0; j < 4; ++j) wv[j] = Ws[tx * 4 + j][kk];
            #pragma unroll
            for (int i = 0; i < 4; ++i)
                #pragma unroll
                for (int j = 0; j < 4; ++j)
                    acc[i][j] += av[i] * wv[j];
        }
        __syncthreads();
    }

    #pragma unroll
    for (int i = 0; i < 4; ++i) {
        int m = m0 + ty * 4 + i;
        #pragma unroll
        for (int j = 0; j < 4; ++j) {
            int n = n0 + tx * 4 + j;
            if (n < N) {
                float v = acc[i][j];
                if (bias) v += bias[n];
                if (act == 1) v = (v > 20.f) ? v : log1pf(__expf(v));
                C[(size_t)m * ldc + n] = v;
            }
        }
    }
}

// ---- split-K fp32 GEMM: Cpart[z] = A @ W^T over K-slice z (no bias/act) ----
__global__ __launch_bounds__(256) void gemm_nt_sk(const float* __restrict__ A, int lda,
                                                  const float* __restrict__ W, int ldw,
                                                  float* __restrict__ Cpart, int ldc,
                                                  int N, int Kslice, int M)
{
    __shared__ float As[64][17];
    __shared__ float Ws[64][17];
    int tid = threadIdx.x;
    int tx = tid & 15;
    int ty = tid >> 4;
    int m0 = blockIdx.y * 64;
    int n0 = blockIdx.x * 64;
    int kbase = blockIdx.z * Kslice;
    float* C = Cpart + (size_t)blockIdx.z * M * ldc;

    float acc[4][4] = {};

    for (int k0 = kbase; k0 < kbase + Kslice; k0 += 16) {
        #pragma unroll
        for (int i = 0; i < 4; ++i) {
            int idx = tid + i * 256;
            int r = idx >> 4, c = idx & 15;
            As[r][c] = A[(size_t)(m0 + r) * lda + k0 + c];
            int nr = n0 + r;
            Ws[r][c] = (nr < N) ? W[(size_t)nr * ldw + k0 + c] : 0.f;
        }
        __syncthreads();
        #pragma unroll
        for (int kk = 0; kk < 16; ++kk) {
            float av[4], wv[4];
            #pragma unroll
            for (int i = 0; i < 4; ++i) av[i] = As[ty * 4 + i][kk];
            #pragma unroll
            for (int j = 0; j < 4; ++j) wv[j] = Ws[tx * 4 + j][kk];
            #pragma unroll
            for (int i = 0; i < 4; ++i)
                #pragma unroll
                for (int j = 0; j < 4; ++j)
                    acc[i][j] += av[i] * wv[j];
        }
        __syncthreads();
    }

    #pragma unroll
    for (int i = 0; i < 4; ++i) {
        int m = m0 + ty * 4 + i;
        #pragma unroll
        for (int j = 0; j < 4; ++j) {
            int n = n0 + tx * 4 + j;
            if (n < N)
                C[(size_t)m * ldc + n] = acc[i][j];
        }
    }
}

// ---------------- causal depthwise conv + SiLU (float4 over d) ----------------
__global__ __launch_bounds__(256) void conv_silu_kernel(const float* __restrict__ xz,
                                                        const float* __restrict__ cw,
                                                        const float* __restrict__ cb,
                                                        float* __restrict__ u)
{
    int idx = blockIdx.x * 256 + threadIdx.x;   // over MROWS * DI/4
    int d4 = idx % (DI / 4);
    int bt = idx / (DI / 4);
    int t = bt % SEQ;
    int b = bt / SEQ;
    int d = d4 * 4;

    float4 w0 = *(const float4*)(cw + (d + 0) * 4);
    float4 w1 = *(const float4*)(cw + (d + 1) * 4);
    float4 w2 = *(const float4*)(cw + (d + 2) * 4);
    float4 w3 = *(const float4*)(cw + (d + 3) * 4);
    const float* wp[4] = { (const float*)&w0, (const float*)&w1,
                           (const float*)&w2, (const float*)&w3 };

    float4 acc = *(const float4*)(cb + d);
    #pragma unroll
    for (int k = 0; k < DCONV; ++k) {
        int tt = t - (DCONV - 1) + k;
        if (tt >= 0) {
            float4 xv = *(const float4*)(xz + (size_t)(b * SEQ + tt) * XZW + d);
            acc.x += xv.x * wp[0][k];
            acc.y += xv.y * wp[1][k];
            acc.z += xv.z * wp[2][k];
            acc.w += xv.w * wp[3][k];
        }
    }
    acc.x *= sigmoidf_(acc.x);
    acc.y *= sigmoidf_(acc.y);
    acc.z *= sigmoidf_(acc.z);
    acc.w *= sigmoidf_(acc.w);
    *(float4*)(u + (size_t)(b * SEQ + t) * DI + d) = acc;
}

// ======================= 3-kernel chunked scan, lane = channel =====================
// grid (DI/64, NCHUNK/4, BATCH), block 256 = 4 waves; wave w owns chunk blockIdx.y*4+w
// for 64 channels d = blockIdx.x*64 + lane. All 16 states per thread in registers.
// B[t][n] (wave-uniform t) staged into LDS -> broadcast reads, conflict-free.

// K1: chunk-local (P,S) with h_in = 0
__global__ __launch_bounds__(256) void scan_p1(const float* __restrict__ delta,
                                               const float* __restrict__ u,
                                               const float* __restrict__ dbc,
                                               const float* __restrict__ aT,
                                               float* __restrict__ Pw,
                                               float* __restrict__ Sw)
{
    __shared__ float Bs[4][CLEN][DS];          // 4 waves x 32 t x 16 n = 8 KB
    int tid = threadIdx.x;
    int lane = tid & 63, w = tid >> 6;
    int d = blockIdx.x * 64 + lane;
    int chunk = blockIdx.y * 4 + w;
    int b = blockIdx.z;
    int t0 = chunk * CLEN;

    // stage B: 32t x 16 floats = 512 floats/wave -> 2 float4/lane
    #pragma unroll
    for (int i = 0; i < 2; ++i) {
        int idx = i * 64 + lane;               // [t(32)][c(4 float4 slots)]
        int tl = idx >> 2, c = idx & 3;
        *(float4*)&Bs[w][tl][c * 4] =
            *(const float4*)(dbc + (size_t)(b * SEQ + t0 + tl) * DBCW + DTR + c * 4);
    }

    float a[DS];
    #pragma unroll
    for (int n = 0; n < DS; ++n) a[n] = aT[n * DI + d];

    __syncthreads();

    float P[DS], S[DS];
    #pragma unroll
    for (int n = 0; n < DS; ++n) { P[n] = 1.f; S[n] = 0.f; }

    const float* dp = delta + ((size_t)b * SEQ + t0) * DI + d;
    const float* up = u     + ((size_t)b * SEQ + t0) * DI + d;
    #pragma unroll 4
    for (int j = 0; j < CLEN; ++j) {
        float dlt = dp[(size_t)j * DI];
        float uu  = up[(size_t)j * DI];
        float dltu = dlt * uu;
        #pragma unroll
        for (int n = 0; n < DS; ++n) {
            float dA = exp2f(dlt * a[n]);
            P[n] *= dA;
            S[n] = dA * S[n] + dltu * Bs[w][j][n];
        }
    }

    size_t base = (((size_t)b * NCHUNK + chunk) * DS) * DI + d;
    #pragma unroll
    for (int n = 0; n < DS; ++n) {
        Pw[base + (size_t)n * DI] = P[n];
        Sw[base + (size_t)n * DI] = S[n];
    }
}

// K2: serial combine across chunks -> Hin (incoming state per chunk)
__global__ __launch_bounds__(256) void scan_comb(const float* __restrict__ Pw,
                                                 const float* __restrict__ Sw,
                                                 float* __restrict__ Hin)
{
    int d = blockIdx.x * 256 + threadIdx.x;    // DI/256 = 6 blocks in x
    int n = blockIdx.y, b = blockIdx.z;
    float h = 0.f;
    for (int c = 0; c < NCHUNK; ++c) {
        size_t idx = (((size_t)b * NCHUNK + c) * DS + n) * DI + d;
        Hin[idx] = h;
        h = Pw[idx] * h + Sw[idx];
    }
}

// K3: replay with correct h_in, dot with C in-lane, gate with silu(z), write y bf16
__global__ __launch_bounds__(256) void scan_p3(const float* __restrict__ delta,
                                               const float* __restrict__ u,
                                               const float* __restrict__ dbc,
                                               const float* __restrict__ xz,
                                               const float* __restrict__ aT,
                                               const float* __restrict__ Dp,
                                               const float* __restrict__ Hin,
                                               ushort_t* __restrict__ y)
{
    __shared__ float Bs[4][CLEN][2 * DS];      // B(16)+C(16) per t = 16 KB
    int tid = threadIdx.x;
    int lane = tid & 63, w = tid >> 6;
    int d = blockIdx.x * 64 + lane;
    int chunk = blockIdx.y * 4 + w;
    int b = blockIdx.z;
    int t0 = chunk * CLEN;

    // stage B+C: 32t x 32 floats = 1024 floats/wave -> 4 float4/lane
    #pragma unroll
    for (int i = 0; i < 4; ++i) {
        int idx = i * 64 + lane;               // [t(32)][c(8 float4 slots)]
        int tl = idx >> 3, c = idx & 7;
        *(float4*)&Bs[w][tl][c * 4] =
            *(const float4*)(dbc + (size_t)(b * SEQ + t0 + tl) * DBCW + DTR + c * 4);
    }

    float a[DS], h[DS];
    #pragma unroll
    for (int n = 0; n < DS; ++n) a[n] = aT[n * DI + d];
    size_t hbase = (((size_t)b * NCHUNK + chunk) * DS) * DI + d;
    #pragma unroll
    for (int n = 0; n < DS; ++n) h[n] = Hin[hbase + (size_t)n * DI];

    float Dd = Dp[d];
    __syncthreads();

    const float* dp = delta + ((size_t)b * SEQ + t0) * DI + d;
    const float* up = u     + ((size_t)b * SEQ + t0) * DI + d;
    const float* zp = xz    + ((size_t)b * SEQ + t0) * XZW + DI + d;
    ushort_t* yp    = y     + ((size_t)b * SEQ + t0) * DI + d;

    #pragma unroll 2
    for (int j = 0; j < CLEN; ++j) {
        float dlt = dp[(size_t)j * DI];
        float uu  = up[(size_t)j * DI];
        float dltu = dlt * uu;
        #pragma unroll
        for (int n = 0; n < DS; ++n) {
            float dA = exp2f(dlt * a[n]);
            h[n] = dA * h[n] + dltu * Bs[w][j][n];
        }
        float p0 = 0.f, p1 = 0.f, p2 = 0.f, p3 = 0.f;
        #pragma unroll
        for (int n = 0; n < DS; n += 4) {
            p0 += h[n]     * Bs[w][j][DS + n];
            p1 += h[n + 1] * Bs[w][j][DS + n + 1];
            p2 += h[n + 2] * Bs[w][j][DS + n + 2];
            p3 += h[n + 3] * Bs[w][j][DS + n + 3];
        }
        float p = (p0 + p1) + (p2 + p3);
        float z = zp[(size_t)j * XZW];
        float yv = (p + uu * Dd) * (z * sigmoidf_(z));
        yp[(size_t)j * DI] = f2bf(yv);
    }
}

extern "C" void kernel_launch(void* const* d_in, const int* in_sizes, int n_in,
                              void* d_out, int out_size, void* d_ws, size_t ws_size,
                              hipStream_t stream) {
    const float* x         = (const float*)d_in[0];
    const float* ln_w      = (const float*)d_in[1];
    const float* ln_b      = (const float*)d_in[2];
    const float* in_proj_w = (const float*)d_in[3];   // (3072, 768)
    const float* conv_w    = (const float*)d_in[4];   // (1536, 4)
    const float* conv_b    = (const float*)d_in[5];   // (1536)
    const float* x_proj_w  = (const float*)d_in[6];   // (80, 1536)
    const float* dt_proj_w = (const float*)d_in[7];   // (1536, 48)
    const float* dt_proj_b = (const float*)d_in[8];   // (1536)
    const float* A_log     = (const float*)d_in[9];   // (1536, 16)
    const float* D_param   = (const float*)d_in[10];  // (1536)
    const float* out_proj_w= (const float*)d_in[11];  // (768, 1536)
    float* out = (float*)d_out;

    char* ws = (char*)d_ws;
    size_t off = 0;
    auto alloc = [&](size_t bytes) { void* p = ws + off; off += (bytes + 255) & ~255ull; return p; };

    ushort_t* xn_bf   = (ushort_t*)alloc((size_t)MROWS * DIM * 2);
    ushort_t* w_in_bf = (ushort_t*)alloc((size_t)XZW * DIM * 2);
    ushort_t* w_out_bf= (ushort_t*)alloc((size_t)DIM * DI * 2);
    ushort_t* y_bf    = (ushort_t*)alloc((size_t)MROWS * DI * 2);
    float* xz    = (float*)alloc((size_t)MROWS * XZW * 4);
    float* u     = (float*)alloc((size_t)MROWS * DI * 4);
    float* dbc   = (float*)alloc((size_t)MROWS * DBCW * 4);
    float* delta = (float*)alloc((size_t)MROWS * DI * 4);
    float* aT    = (float*)alloc((size_t)DS * DI * 4);
    float* xpart = (float*)alloc((size_t)XP_KS * MROWS * DBCW * 4);
    float* opart = (float*)alloc((size_t)OP_KS * MROWS * DIM * 4);

    // scan scratch aliases opart (used only after the scan completes):
    // P/S/Hin = 3 * B*NCHUNK*DS*DI floats = 18.9 MB <= 25.2 MB
    size_t cvol = (size_t)BATCH * NCHUNK * DS * DI;
    float* Pw  = opart;
    float* Sw  = opart + cvol;
    float* Hin = opart + 2 * cvol;

    // 0. weight conversions + A transpose
    hipLaunchKernelGGL(cvt_bf16, dim3((XZW * DIM) / 2048), dim3(256), 0, stream,
                       in_proj_w, w_in_bf, XZW * DIM);
    hipLaunchKernelGGL(cvt_bf16, dim3((DIM * DI) / 2048), dim3(256), 0, stream,
                       out_proj_w, w_out_bf, DIM * DI);
    hipLaunchKernelGGL(at_kernel, dim3((DS * DI + 255) / 256), dim3(256), 0, stream,
                       A_log, aT);

    // 1. LayerNorm -> bf16
    hipLaunchKernelGGL(ln_kernel, dim3(MROWS), dim3(256), 0, stream, x, ln_w, ln_b, xn_bf);

    // 2. in_proj (bf16 MFMA): xz(2048x3072) = xn @ in_proj_w^T
    hipLaunchKernelGGL(gemm_bf16, dim3(XZW / 128, MROWS / 128), dim3(256), 0, stream,
                       xn_bf, w_in_bf, xz, XZW, DIM);

    // 3. conv + silu -> u (fp32, float4)
    hipLaunchKernelGGL(conv_silu_kernel, dim3((MROWS * DI / 4) / 256), dim3(256), 0, stream,
                       xz, conv_w, conv_b, u);

    // 4. x_proj (fp32 split-K): dbc(2048x80) = u @ x_proj_w^T
    hipLaunchKernelGGL(gemm_nt_sk, dim3((DBCW + 63) / 64, MROWS / 64, XP_KS), dim3(256), 0, stream,
                       u, DI, x_proj_w, DI, xpart, DBCW, DBCW, DI / XP_KS, MROWS);
    hipLaunchKernelGGL(reduce_sk4, dim3((MROWS * DBCW / 4 + 255) / 256), dim3(256), 0, stream,
                       (const float4*)xpart, (float4*)dbc, MROWS * DBCW / 4, XP_KS);

    // 5. dt_proj + softplus (fp32): delta = softplus(dbc[:, :48] @ dt_proj_w^T + b)
    hipLaunchKernelGGL(gemm_nt, dim3(DI / 64, MROWS / 64), dim3(256), 0, stream,
                       dbc, DBCW, dt_proj_w, DTR, delta, DI, DI, DTR, dt_proj_b, 1);

    // 6. chunked scan: K1 (P,S) -> K2 combine -> K3 replay+gate
    hipLaunchKernelGGL(scan_p1, dim3(DI / 64, NCHUNK / 4, BATCH), dim3(256), 0, stream,
                       delta, u, dbc, aT, Pw, Sw);
    hipLaunchKernelGGL(scan_comb, dim3(DI / 256, DS, BATCH), dim3(256), 0, stream,
                       Pw, Sw, Hin);
    hipLaunchKernelGGL(scan_p3, dim3(DI / 64, NCHUNK / 4, BATCH), dim3(256), 0, stream,
                       delta, u, dbc, xz, aT, D_param, Hin, y_bf);

    // 7. out_proj (bf16 MFMA split-K): out(2048x768) = y @ out_proj_w^T
    hipLaunchKernelGGL(gemm_bf16_sk, dim3(DIM / 128, MROWS / 128, OP_KS), dim3(256), 0, stream,
                       y_bf, w_out_bf, opart, DIM, DI, DI / OP_KS, MROWS);
    hipLaunchKernelGGL(reduce_sk4, dim3((MROWS * DIM / 4 + 255) / 256), dim3(256), 0, stream,
                       (const float4*)opart, (float4*)out, MROWS * DIM / 4, OP_KS);
}

// Round 10
// 184.690 us; speedup vs baseline: 1.5581x; 1.1137x over previous
//
#include <hip/hip_runtime.h>
#include <hip/hip_bf16.h>

// Mamba layer: LN -> in_proj(bf16 MFMA) -> conv+silu -> x_proj(bf16 MFMA split-K)
//              -> dt_proj(bf16 MFMA K=64, softplus) -> scan (lane=channel, 3-kernel chunked)
//              -> out_proj(bf16 MFMA split-K)
#define BATCH 2
#define SEQ   1024
#define DIM   768
#define DI    1536
#define DS    16
#define DCONV 4
#define DTR   48
#define XZW   (2*DI)     // 3072
#define DBCW  (DTR+2*DS) // 80
#define MROWS (BATCH*SEQ) // 2048
#define NCHUNK 32
#define CLEN  (SEQ/NCHUNK) // 32
#define XP_KS 8          // x_proj split-K slices
#define OP_KS 4          // out_proj split-K slices
#define XPN   128        // padded x_proj output width

typedef unsigned short ushort_t;
typedef __attribute__((ext_vector_type(8))) short short8;
typedef __attribute__((ext_vector_type(4))) float f32x4;

__device__ __forceinline__ float sigmoidf_(float x) {
    return 1.f / (1.f + __expf(-x));
}

__device__ __forceinline__ ushort_t f2bf(float x) {
    union { float f; unsigned u; } c{x};
    unsigned r = c.u + 0x7FFF + ((c.u >> 16) & 1);   // RNE
    return (ushort_t)(r >> 16);
}

__device__ __forceinline__ void gload16(const void* g, void* lds) {
    __builtin_amdgcn_global_load_lds(
        (const __attribute__((address_space(1))) void*)g,
        (__attribute__((address_space(3))) void*)lds,
        16, 0, 0);
}

// ---------------- fp32 -> bf16 conversion (8 elems/thread) ----------------
__global__ __launch_bounds__(256) void cvt_bf16(const float* __restrict__ in,
                                                ushort_t* __restrict__ out, int n)
{
    int i = (blockIdx.x * 256 + threadIdx.x) * 8;
    if (i >= n) return;
    float4 a = *(const float4*)(in + i);
    float4 b = *(const float4*)(in + i + 4);
    ushort_t o[8] = { f2bf(a.x), f2bf(a.y), f2bf(a.z), f2bf(a.w),
                      f2bf(b.x), f2bf(b.y), f2bf(b.z), f2bf(b.w) };
    *(ushort4*)(out + i)     = *(ushort4*)o;
    *(ushort4*)(out + i + 4) = *(ushort4*)(o + 4);
}

// ---- small prep: aT[n][d] = -exp(A_log[d][n])*log2e; xpw_pad(128x1536 bf16);
//      dtw_bf(1536x64 bf16, cols 48.. zero) ----
__global__ __launch_bounds__(256) void prep_small(const float* __restrict__ A_log,
                                                  const float* __restrict__ x_proj_w,
                                                  const float* __restrict__ dt_proj_w,
                                                  float* __restrict__ aT,
                                                  ushort_t* __restrict__ xpw_pad,
                                                  ushort_t* __restrict__ dtw_bf)
{
    int i = blockIdx.x * 256 + threadIdx.x;
    const int NA = DS * DI;               // 24576
    const int NX = XPN * DI;              // 196608
    const int NDT = DI * 64;              // 98304
    if (i < NA) {
        int n = i / DI, d = i % DI;
        aT[i] = -__expf(A_log[d * DS + n]) * 1.44269504f;
    } else if (i < NA + NX) {
        int j = i - NA;
        int r = j / DI, c = j % DI;
        xpw_pad[j] = (r < DBCW) ? f2bf(x_proj_w[r * DI + c]) : (ushort_t)0;
    } else if (i < NA + NX + NDT) {
        int j = i - NA - NX;
        int r = j / 64, c = j % 64;
        dtw_bf[j] = (c < DTR) ? f2bf(dt_proj_w[r * DTR + c]) : (ushort_t)0;
    }
}

// ---------------- split-K partial reduce: out[i] = sum_z part[z][i] (float4) -------
__global__ __launch_bounds__(256) void reduce_sk4(const float4* __restrict__ part,
                                                  float4* __restrict__ out,
                                                  int count4, int nslices)
{
    int i = blockIdx.x * 256 + threadIdx.x;
    if (i >= count4) return;
    float4 s = part[i];
    for (int z = 1; z < nslices; ++z) {
        float4 p = part[(size_t)z * count4 + i];
        s.x += p.x; s.y += p.y; s.z += p.z; s.w += p.w;
    }
    out[i] = s;
}

// ---- x_proj split-K reduce: part 8x[2048][128] -> dbc[2048][80] fp32 + dtb[2048][64] bf16
__global__ __launch_bounds__(256) void reduce_dbc(const float* __restrict__ part,
                                                  float* __restrict__ dbc,
                                                  ushort_t* __restrict__ dtb)
{
    int i = blockIdx.x * 256 + threadIdx.x;    // over 2048*128
    if (i >= MROWS * XPN) return;
    float s = 0.f;
    #pragma unroll
    for (int z = 0; z < XP_KS; ++z)
        s += part[(size_t)z * MROWS * XPN + i];
    int r = i / XPN, c = i % XPN;
    if (c < DBCW) dbc[(size_t)r * DBCW + c] = s;
    if (c < 64)   dtb[(size_t)r * 64 + c] = (c < DTR) ? f2bf(s) : (ushort_t)0;
}

// ---------------- LayerNorm (fp32 in, bf16 out), shfl-based ----------------
__global__ __launch_bounds__(256) void ln_kernel(const float* __restrict__ x,
                                                 const float* __restrict__ w,
                                                 const float* __restrict__ b,
                                                 ushort_t* __restrict__ xn)
{
    __shared__ float part[8];
    int row = blockIdx.x;               // 0..2047
    const float* xr = x + (size_t)row * DIM;
    ushort_t* o = xn + (size_t)row * DIM;
    int tid = threadIdx.x;
    int lane = tid & 63, wid = tid >> 6;

    float v0 = xr[tid], v1 = xr[tid + 256], v2 = xr[tid + 512];
    float s = v0 + v1 + v2;
    #pragma unroll
    for (int off = 32; off > 0; off >>= 1) s += __shfl_xor(s, off);
    if (lane == 0) part[wid] = s;
    __syncthreads();
    float mu = (part[0] + part[1] + part[2] + part[3]) * (1.f / DIM);

    float d0 = v0 - mu, d1 = v1 - mu, d2 = v2 - mu;
    float q = d0 * d0 + d1 * d1 + d2 * d2;
    #pragma unroll
    for (int off = 32; off > 0; off >>= 1) q += __shfl_xor(q, off);
    if (lane == 0) part[4 + wid] = q;
    __syncthreads();
    float rstd = rsqrtf((part[4] + part[5] + part[6] + part[7]) * (1.f / DIM) + 1e-5f);

    o[tid]       = f2bf(d0 * rstd * w[tid]       + b[tid]);
    o[tid + 256] = f2bf(d1 * rstd * w[tid + 256] + b[tid + 256]);
    o[tid + 512] = f2bf(d2 * rstd * w[tid + 512] + b[tid + 512]);
}

// ---------------- bf16 MFMA GEMM: C(MxN fp32) = A(MxK bf16) @ W(NxK bf16)^T ----------
__global__ __launch_bounds__(256) void gemm_bf16(const ushort_t* __restrict__ A,
                                                 const ushort_t* __restrict__ W,
                                                 float* __restrict__ C,
                                                 int N, int K)
{
    __shared__ __align__(16) ushort_t As[128 * 32];
    __shared__ __align__(16) ushort_t Bs[128 * 32];

    int tid = threadIdx.x;
    int wave = tid >> 6, lane = tid & 63;
    int wr = wave >> 1, wc = wave & 1;
    int l15 = lane & 15, kb = lane >> 4;
    int m0 = blockIdx.y * 128, n0 = blockIdx.x * 128;

    f32x4 acc[4][4] = {};

    for (int k0 = 0; k0 < K; k0 += 32) {
        #pragma unroll
        for (int i = 0; i < 2; ++i) {
            int cbase = i * 256 + wave * 64;
            int c = cbase + lane;
            int row = c >> 2;
            int col = (c & 3) * 8;
            gload16(A + (size_t)(m0 + row) * K + k0 + col, (char*)As + (size_t)cbase * 16);
            gload16(W + (size_t)(n0 + row) * K + k0 + col, (char*)Bs + (size_t)cbase * 16);
        }
        __syncthreads();

        short8 af[4], bfr[4];
        #pragma unroll
        for (int m = 0; m < 4; ++m)
            af[m] = *(const short8*)&As[(wr * 64 + m * 16 + l15) * 32 + kb * 8];
        #pragma unroll
        for (int n = 0; n < 4; ++n)
            bfr[n] = *(const short8*)&Bs[(wc * 64 + n * 16 + l15) * 32 + kb * 8];

        #pragma unroll
        for (int m = 0; m < 4; ++m)
            #pragma unroll
            for (int n = 0; n < 4; ++n)
                acc[m][n] = __builtin_amdgcn_mfma_f32_16x16x32_bf16(af[m], bfr[n], acc[m][n], 0, 0, 0);

        __syncthreads();
    }

    int r0 = m0 + wr * 64 + kb * 4;
    int c0 = n0 + wc * 64 + l15;
    #pragma unroll
    for (int m = 0; m < 4; ++m)
        #pragma unroll
        for (int n = 0; n < 4; ++n) {
            int rr = r0 + m * 16;
            int cc = c0 + n * 16;
            #pragma unroll
            for (int r = 0; r < 4; ++r)
                C[(size_t)(rr + r) * N + cc] = acc[m][n][r];
        }
}

// ---- split-K bf16 MFMA GEMM: Cpart[z] = A @ W^T over K-slice z (z = blockIdx.z) ----
__global__ __launch_bounds__(256) void gemm_bf16_sk(const ushort_t* __restrict__ A,
                                                    const ushort_t* __restrict__ W,
                                                    float* __restrict__ Cpart,
                                                    int N, int Ktot, int Kslice, int M)
{
    __shared__ __align__(16) ushort_t As[128 * 32];
    __shared__ __align__(16) ushort_t Bs[128 * 32];

    int tid = threadIdx.x;
    int wave = tid >> 6, lane = tid & 63;
    int wr = wave >> 1, wc = wave & 1;
    int l15 = lane & 15, kb = lane >> 4;
    int m0 = blockIdx.y * 128, n0 = blockIdx.x * 128;
    int kbase = blockIdx.z * Kslice;
    float* C = Cpart + (size_t)blockIdx.z * M * N;

    f32x4 acc[4][4] = {};

    for (int k0 = kbase; k0 < kbase + Kslice; k0 += 32) {
        #pragma unroll
        for (int i = 0; i < 2; ++i) {
            int cbase = i * 256 + wave * 64;
            int c = cbase + lane;
            int row = c >> 2;
            int col = (c & 3) * 8;
            gload16(A + (size_t)(m0 + row) * Ktot + k0 + col, (char*)As + (size_t)cbase * 16);
            gload16(W + (size_t)(n0 + row) * Ktot + k0 + col, (char*)Bs + (size_t)cbase * 16);
        }
        __syncthreads();

        short8 af[4], bfr[4];
        #pragma unroll
        for (int m = 0; m < 4; ++m)
            af[m] = *(const short8*)&As[(wr * 64 + m * 16 + l15) * 32 + kb * 8];
        #pragma unroll
        for (int n = 0; n < 4; ++n)
            bfr[n] = *(const short8*)&Bs[(wc * 64 + n * 16 + l15) * 32 + kb * 8];

        #pragma unroll
        for (int m = 0; m < 4; ++m)
            #pragma unroll
            for (int n = 0; n < 4; ++n)
                acc[m][n] = __builtin_amdgcn_mfma_f32_16x16x32_bf16(af[m], bfr[n], acc[m][n], 0, 0, 0);

        __syncthreads();
    }

    int r0 = m0 + wr * 64 + kb * 4;
    int c0 = n0 + wc * 64 + l15;
    #pragma unroll
    for (int m = 0; m < 4; ++m)
        #pragma unroll
        for (int n = 0; n < 4; ++n) {
            int rr = r0 + m * 16;
            int cc = c0 + n * 16;
            #pragma unroll
            for (int r = 0; r < 4; ++r)
                C[(size_t)(rr + r) * N + cc] = acc[m][n][r];
        }
}

// ---- dt_proj bf16 MFMA, K=64 fixed, fused bias+softplus: delta = sp(A@W^T + b) ----
__global__ __launch_bounds__(256) void gemm_dt(const ushort_t* __restrict__ A,
                                               const ushort_t* __restrict__ W,
                                               const float* __restrict__ bias,
                                               float* __restrict__ C)
{
    __shared__ __align__(16) ushort_t As[128 * 32];
    __shared__ __align__(16) ushort_t Bs[128 * 32];

    int tid = threadIdx.x;
    int wave = tid >> 6, lane = tid & 63;
    int wr = wave >> 1, wc = wave & 1;
    int l15 = lane & 15, kb = lane >> 4;
    int m0 = blockIdx.y * 128, n0 = blockIdx.x * 128;

    f32x4 acc[4][4] = {};

    #pragma unroll
    for (int k0 = 0; k0 < 64; k0 += 32) {
        #pragma unroll
        for (int i = 0; i < 2; ++i) {
            int cbase = i * 256 + wave * 64;
            int c = cbase + lane;
            int row = c >> 2;
            int col = (c & 3) * 8;
            gload16(A + (size_t)(m0 + row) * 64 + k0 + col, (char*)As + (size_t)cbase * 16);
            gload16(W + (size_t)(n0 + row) * 64 + k0 + col, (char*)Bs + (size_t)cbase * 16);
        }
        __syncthreads();

        short8 af[4], bfr[4];
        #pragma unroll
        for (int m = 0; m < 4; ++m)
            af[m] = *(const short8*)&As[(wr * 64 + m * 16 + l15) * 32 + kb * 8];
        #pragma unroll
        for (int n = 0; n < 4; ++n)
            bfr[n] = *(const short8*)&Bs[(wc * 64 + n * 16 + l15) * 32 + kb * 8];

        #pragma unroll
        for (int m = 0; m < 4; ++m)
            #pragma unroll
            for (int n = 0; n < 4; ++n)
                acc[m][n] = __builtin_amdgcn_mfma_f32_16x16x32_bf16(af[m], bfr[n], acc[m][n], 0, 0, 0);

        __syncthreads();
    }

    int r0 = m0 + wr * 64 + kb * 4;
    int c0 = n0 + wc * 64 + l15;
    #pragma unroll
    for (int m = 0; m < 4; ++m)
        #pragma unroll
        for (int n = 0; n < 4; ++n) {
            int rr = r0 + m * 16;
            int cc = c0 + n * 16;
            float bv = bias[cc];
            #pragma unroll
            for (int r = 0; r < 4; ++r) {
                float v = acc[m][n][r] + bv;
                v = (v > 20.f) ? v : log1pf(__expf(v));
                C[(size_t)(rr + r) * DI + cc] = v;
            }
        }
}

// ---------------- causal depthwise conv + SiLU (float4 over d), u fp32 + bf16 ------
__global__ __launch_bounds__(256) void conv_silu_kernel(const float* __restrict__ xz,
                                                        const float* __restrict__ cw,
                                                        const float* __restrict__ cb,
                                                        float* __restrict__ u,
                                                        ushort_t* __restrict__ u_bf)
{
    int idx = blockIdx.x * 256 + threadIdx.x;   // over MROWS * DI/4
    int d4 = idx % (DI / 4);
    int bt = idx / (DI / 4);
    int t = bt % SEQ;
    int b = bt / SEQ;
    int d = d4 * 4;

    float4 w0 = *(const float4*)(cw + (d + 0) * 4);
    float4 w1 = *(const float4*)(cw + (d + 1) * 4);
    float4 w2 = *(const float4*)(cw + (d + 2) * 4);
    float4 w3 = *(const float4*)(cw + (d + 3) * 4);
    const float* wp[4] = { (const float*)&w0, (const float*)&w1,
                           (const float*)&w2, (const float*)&w3 };

    float4 acc = *(const float4*)(cb + d);
    #pragma unroll
    for (int k = 0; k < DCONV; ++k) {
        int tt = t - (DCONV - 1) + k;
        if (tt >= 0) {
            float4 xv = *(const float4*)(xz + (size_t)(b * SEQ + tt) * XZW + d);
            acc.x += xv.x * wp[0][k];
            acc.y += xv.y * wp[1][k];
            acc.z += xv.z * wp[2][k];
            acc.w += xv.w * wp[3][k];
        }
    }
    acc.x *= sigmoidf_(acc.x);
    acc.y *= sigmoidf_(acc.y);
    acc.z *= sigmoidf_(acc.z);
    acc.w *= sigmoidf_(acc.w);
    size_t o = (size_t)(b * SEQ + t) * DI + d;
    *(float4*)(u + o) = acc;
    ushort4 ob = { f2bf(acc.x), f2bf(acc.y), f2bf(acc.z), f2bf(acc.w) };
    *(ushort4*)(u_bf + o) = ob;
}

// ======================= 3-kernel chunked scan, lane = channel =====================
// K1: chunk-local (P,S) with h_in = 0
__global__ __launch_bounds__(256) void scan_p1(const float* __restrict__ delta,
                                               const float* __restrict__ u,
                                               const float* __restrict__ dbc,
                                               const float* __restrict__ aT,
                                               float* __restrict__ Pw,
                                               float* __restrict__ Sw)
{
    __shared__ float Bs[4][CLEN][DS];          // 8 KB
    int tid = threadIdx.x;
    int lane = tid & 63, w = tid >> 6;
    int d = blockIdx.x * 64 + lane;
    int chunk = blockIdx.y * 4 + w;
    int b = blockIdx.z;
    int t0 = chunk * CLEN;

    #pragma unroll
    for (int i = 0; i < 2; ++i) {
        int idx = i * 64 + lane;
        int tl = idx >> 2, c = idx & 3;
        *(float4*)&Bs[w][tl][c * 4] =
            *(const float4*)(dbc + (size_t)(b * SEQ + t0 + tl) * DBCW + DTR + c * 4);
    }

    float a[DS];
    #pragma unroll
    for (int n = 0; n < DS; ++n) a[n] = aT[n * DI + d];

    __syncthreads();

    float P[DS], S[DS];
    #pragma unroll
    for (int n = 0; n < DS; ++n) { P[n] = 1.f; S[n] = 0.f; }

    const float* dp = delta + ((size_t)b * SEQ + t0) * DI + d;
    const float* up = u     + ((size_t)b * SEQ + t0) * DI + d;
    #pragma unroll 4
    for (int j = 0; j < CLEN; ++j) {
        float dlt = dp[(size_t)j * DI];
        float uu  = up[(size_t)j * DI];
        float dltu = dlt * uu;
        #pragma unroll
        for (int n = 0; n < DS; ++n) {
            float dA = exp2f(dlt * a[n]);
            P[n] *= dA;
            S[n] = dA * S[n] + dltu * Bs[w][j][n];
        }
    }

    size_t base = (((size_t)b * NCHUNK + chunk) * DS) * DI + d;
    #pragma unroll
    for (int n = 0; n < DS; ++n) {
        Pw[base + (size_t)n * DI] = P[n];
        Sw[base + (size_t)n * DI] = S[n];
    }
}

// K2: serial combine across chunks -> Hin
__global__ __launch_bounds__(256) void scan_comb(const float* __restrict__ Pw,
                                                 const float* __restrict__ Sw,
                                                 float* __restrict__ Hin)
{
    int d = blockIdx.x * 256 + threadIdx.x;
    int n = blockIdx.y, b = blockIdx.z;
    float h = 0.f;
    for (int c = 0; c < NCHUNK; ++c) {
        size_t idx = (((size_t)b * NCHUNK + c) * DS + n) * DI + d;
        Hin[idx] = h;
        h = Pw[idx] * h + Sw[idx];
    }
}

// K3: replay with h_in, dot with C in-lane, gate with silu(z), write y bf16
__global__ __launch_bounds__(256) void scan_p3(const float* __restrict__ delta,
                                               const float* __restrict__ u,
                                               const float* __restrict__ dbc,
                                               const float* __restrict__ xz,
                                               const float* __restrict__ aT,
                                               const float* __restrict__ Dp,
                                               const float* __restrict__ Hin,
                                               ushort_t* __restrict__ y)
{
    __shared__ float Bs[4][CLEN][2 * DS];      // 16 KB
    int tid = threadIdx.x;
    int lane = tid & 63, w = tid >> 6;
    int d = blockIdx.x * 64 + lane;
    int chunk = blockIdx.y * 4 + w;
    int b = blockIdx.z;
    int t0 = chunk * CLEN;

    #pragma unroll
    for (int i = 0; i < 4; ++i) {
        int idx = i * 64 + lane;
        int tl = idx >> 3, c = idx & 7;
        *(float4*)&Bs[w][tl][c * 4] =
            *(const float4*)(dbc + (size_t)(b * SEQ + t0 + tl) * DBCW + DTR + c * 4);
    }

    float a[DS], h[DS];
    #pragma unroll
    for (int n = 0; n < DS; ++n) a[n] = aT[n * DI + d];
    size_t hbase = (((size_t)b * NCHUNK + chunk) * DS) * DI + d;
    #pragma unroll
    for (int n = 0; n < DS; ++n) h[n] = Hin[hbase + (size_t)n * DI];

    float Dd = Dp[d];
    __syncthreads();

    const float* dp = delta + ((size_t)b * SEQ + t0) * DI + d;
    const float* up = u     + ((size_t)b * SEQ + t0) * DI + d;
    const float* zp = xz    + ((size_t)b * SEQ + t0) * XZW + DI + d;
    ushort_t* yp    = y     + ((size_t)b * SEQ + t0) * DI + d;

    #pragma unroll 2
    for (int j = 0; j < CLEN; ++j) {
        float dlt = dp[(size_t)j * DI];
        float uu  = up[(size_t)j * DI];
        float dltu = dlt * uu;
        #pragma unroll
        for (int n = 0; n < DS; ++n) {
            float dA = exp2f(dlt * a[n]);
            h[n] = dA * h[n] + dltu * Bs[w][j][n];
        }
        float p0 = 0.f, p1 = 0.f, p2 = 0.f, p3 = 0.f;
        #pragma unroll
        for (int n = 0; n < DS; n += 4) {
            p0 += h[n]     * Bs[w][j][DS + n];
            p1 += h[n + 1] * Bs[w][j][DS + n + 1];
            p2 += h[n + 2] * Bs[w][j][DS + n + 2];
            p3 += h[n + 3] * Bs[w][j][DS + n + 3];
        }
        float p = (p0 + p1) + (p2 + p3);
        float z = zp[(size_t)j * XZW];
        float yv = (p + uu * Dd) * (z * sigmoidf_(z));
        yp[(size_t)j * DI] = f2bf(yv);
    }
}

extern "C" void kernel_launch(void* const* d_in, const int* in_sizes, int n_in,
                              void* d_out, int out_size, void* d_ws, size_t ws_size,
                              hipStream_t stream) {
    const float* x         = (const float*)d_in[0];
    const float* ln_w      = (const float*)d_in[1];
    const float* ln_b      = (const float*)d_in[2];
    const float* in_proj_w = (const float*)d_in[3];   // (3072, 768)
    const float* conv_w    = (const float*)d_in[4];   // (1536, 4)
    const float* conv_b    = (const float*)d_in[5];   // (1536)
    const float* x_proj_w  = (const float*)d_in[6];   // (80, 1536)
    const float* dt_proj_w = (const float*)d_in[7];   // (1536, 48)
    const float* dt_proj_b = (const float*)d_in[8];   // (1536)
    const float* A_log     = (const float*)d_in[9];   // (1536, 16)
    const float* D_param   = (const float*)d_in[10];  // (1536)
    const float* out_proj_w= (const float*)d_in[11];  // (768, 1536)
    float* out = (float*)d_out;

    char* ws = (char*)d_ws;
    size_t off = 0;
    auto alloc = [&](size_t bytes) { void* p = ws + off; off += (bytes + 255) & ~255ull; return p; };

    ushort_t* xn_bf   = (ushort_t*)alloc((size_t)MROWS * DIM * 2);
    ushort_t* w_in_bf = (ushort_t*)alloc((size_t)XZW * DIM * 2);
    ushort_t* w_out_bf= (ushort_t*)alloc((size_t)DIM * DI * 2);
    ushort_t* y_bf    = (ushort_t*)alloc((size_t)MROWS * DI * 2);
    ushort_t* u_bf    = (ushort_t*)alloc((size_t)MROWS * DI * 2);
    ushort_t* xpw_pad = (ushort_t*)alloc((size_t)XPN * DI * 2);
    ushort_t* dtw_bf  = (ushort_t*)alloc((size_t)DI * 64 * 2);
    ushort_t* dtb     = (ushort_t*)alloc((size_t)MROWS * 64 * 2);
    float* xz    = (float*)alloc((size_t)MROWS * XZW * 4);
    float* u     = (float*)alloc((size_t)MROWS * DI * 4);
    float* dbc   = (float*)alloc((size_t)MROWS * DBCW * 4);
    float* delta = (float*)alloc((size_t)MROWS * DI * 4);
    float* aT    = (float*)alloc((size_t)DS * DI * 4);
    float* xpart = (float*)alloc((size_t)XP_KS * MROWS * XPN * 4);
    float* opart = (float*)alloc((size_t)OP_KS * MROWS * DIM * 4);

    // scan scratch aliases opart (used only after scan): 3*B*NCHUNK*DS*DI = 18.9 MB <= 25.2 MB
    size_t cvol = (size_t)BATCH * NCHUNK * DS * DI;
    float* Pw  = opart;
    float* Sw  = opart + cvol;
    float* Hin = opart + 2 * cvol;

    // 0. weight conversions + small prep (aT, padded x_proj/dt_proj bf16 weights)
    hipLaunchKernelGGL(cvt_bf16, dim3((XZW * DIM) / 2048), dim3(256), 0, stream,
                       in_proj_w, w_in_bf, XZW * DIM);
    hipLaunchKernelGGL(cvt_bf16, dim3((DIM * DI) / 2048), dim3(256), 0, stream,
                       out_proj_w, w_out_bf, DIM * DI);
    hipLaunchKernelGGL(prep_small,
                       dim3((DS * DI + XPN * DI + DI * 64 + 255) / 256), dim3(256), 0, stream,
                       A_log, x_proj_w, dt_proj_w, aT, xpw_pad, dtw_bf);

    // 1. LayerNorm -> bf16
    hipLaunchKernelGGL(ln_kernel, dim3(MROWS), dim3(256), 0, stream, x, ln_w, ln_b, xn_bf);

    // 2. in_proj (bf16 MFMA): xz(2048x3072) = xn @ in_proj_w^T
    hipLaunchKernelGGL(gemm_bf16, dim3(XZW / 128, MROWS / 128), dim3(256), 0, stream,
                       xn_bf, w_in_bf, xz, XZW, DIM);

    // 3. conv + silu -> u (fp32 + bf16)
    hipLaunchKernelGGL(conv_silu_kernel, dim3((MROWS * DI / 4) / 256), dim3(256), 0, stream,
                       xz, conv_w, conv_b, u, u_bf);

    // 4. x_proj (bf16 MFMA split-K, N padded to 128): xpart[z] = u_bf @ xpw_pad^T
    hipLaunchKernelGGL(gemm_bf16_sk, dim3(XPN / 128, MROWS / 128, XP_KS), dim3(256), 0, stream,
                       u_bf, xpw_pad, xpart, XPN, DI, DI / XP_KS, MROWS);
    hipLaunchKernelGGL(reduce_dbc, dim3((MROWS * XPN + 255) / 256), dim3(256), 0, stream,
                       xpart, dbc, dtb);

    // 5. dt_proj (bf16 MFMA K=64) + bias + softplus -> delta
    hipLaunchKernelGGL(gemm_dt, dim3(DI / 128, MROWS / 128), dim3(256), 0, stream,
                       dtb, dtw_bf, dt_proj_b, delta);

    // 6. chunked scan: K1 (P,S) -> K2 combine -> K3 replay+gate
    hipLaunchKernelGGL(scan_p1, dim3(DI / 64, NCHUNK / 4, BATCH), dim3(256), 0, stream,
                       delta, u, dbc, aT, Pw, Sw);
    hipLaunchKernelGGL(scan_comb, dim3(DI / 256, DS, BATCH), dim3(256), 0, stream,
                       Pw, Sw, Hin);
    hipLaunchKernelGGL(scan_p3, dim3(DI / 64, NCHUNK / 4, BATCH), dim3(256), 0, stream,
                       delta, u, dbc, xz, aT, D_param, Hin, y_bf);

    // 7. out_proj (bf16 MFMA split-K): out(2048x768) = y @ out_proj_w^T
    hipLaunchKernelGGL(gemm_bf16_sk, dim3(DIM / 128, MROWS / 128, OP_KS), dim3(256), 0, stream,
                       y_bf, w_out_bf, opart, DIM, DI, DI / OP_KS, MROWS);
    hipLaunchKernelGGL(reduce_sk4, dim3((MROWS * DIM / 4 + 255) / 256), dim3(256), 0, stream,
                       (const float4*)opart, (float4*)out, MROWS * DIM / 4, OP_KS);
}

// Round 11
// 178.941 us; speedup vs baseline: 1.6082x; 1.0321x over previous
//
#include <hip/hip_runtime.h>
#include <hip/hip_bf16.h>

// Mamba layer: LN -> in_proj(bf16 MFMA, bf16 out) -> conv+silu(bf16) -> x_proj(bf16 MFMA split-K)
//              -> dt_proj(bf16 MFMA K=64, softplus) -> scan (lane=channel, 3-kernel chunked)
//              -> out_proj(bf16 MFMA split-K)
#define BATCH 2
#define SEQ   1024
#define DIM   768
#define DI    1536
#define DS    16
#define DCONV 4
#define DTR   48
#define XZW   (2*DI)     // 3072
#define DBCW  (DTR+2*DS) // 80
#define MROWS (BATCH*SEQ) // 2048
#define NCHUNK 32
#define CLEN  (SEQ/NCHUNK) // 32
#define XP_KS 8          // x_proj split-K slices
#define OP_KS 4          // out_proj split-K slices
#define XPN   128        // padded x_proj output width

typedef unsigned short ushort_t;
typedef __attribute__((ext_vector_type(8))) short short8;
typedef __attribute__((ext_vector_type(4))) float f32x4;

__device__ __forceinline__ float sigmoidf_(float x) {
    return 1.f / (1.f + __expf(-x));
}

__device__ __forceinline__ ushort_t f2bf(float x) {
    union { float f; unsigned u; } c{x};
    unsigned r = c.u + 0x7FFF + ((c.u >> 16) & 1);   // RNE
    return (ushort_t)(r >> 16);
}

__device__ __forceinline__ float bf2f(ushort_t v) {
    union { unsigned u; float f; } c{(unsigned)v << 16};
    return c.f;
}

__device__ __forceinline__ void gload16(const void* g, void* lds) {
    __builtin_amdgcn_global_load_lds(
        (const __attribute__((address_space(1))) void*)g,
        (__attribute__((address_space(3))) void*)lds,
        16, 0, 0);
}

// ---- fused prep: in_proj/out_proj weight cvt (8/thread), aT, xpw_pad, dtw_bf ------
#define PREP_W1 ((XZW*DIM)/8)            // 294912
#define PREP_W2 ((DIM*DI)/8)             // 147456
#define PREP_A  (DS*DI)                  // 24576
#define PREP_X  (XPN*DI)                 // 196608
#define PREP_DT (DI*64)                  // 98304
__global__ __launch_bounds__(256) void prep_all(const float* __restrict__ in_proj_w,
                                                const float* __restrict__ out_proj_w,
                                                const float* __restrict__ A_log,
                                                const float* __restrict__ x_proj_w,
                                                const float* __restrict__ dt_proj_w,
                                                ushort_t* __restrict__ w_in_bf,
                                                ushort_t* __restrict__ w_out_bf,
                                                float* __restrict__ aT,
                                                ushort_t* __restrict__ xpw_pad,
                                                ushort_t* __restrict__ dtw_bf)
{
    int i = blockIdx.x * 256 + threadIdx.x;
    if (i < PREP_W1) {
        int j = i * 8;
        float4 a = *(const float4*)(in_proj_w + j);
        float4 b = *(const float4*)(in_proj_w + j + 4);
        ushort_t o[8] = { f2bf(a.x), f2bf(a.y), f2bf(a.z), f2bf(a.w),
                          f2bf(b.x), f2bf(b.y), f2bf(b.z), f2bf(b.w) };
        *(ushort4*)(w_in_bf + j)     = *(ushort4*)o;
        *(ushort4*)(w_in_bf + j + 4) = *(ushort4*)(o + 4);
        return;
    }
    i -= PREP_W1;
    if (i < PREP_W2) {
        int j = i * 8;
        float4 a = *(const float4*)(out_proj_w + j);
        float4 b = *(const float4*)(out_proj_w + j + 4);
        ushort_t o[8] = { f2bf(a.x), f2bf(a.y), f2bf(a.z), f2bf(a.w),
                          f2bf(b.x), f2bf(b.y), f2bf(b.z), f2bf(b.w) };
        *(ushort4*)(w_out_bf + j)     = *(ushort4*)o;
        *(ushort4*)(w_out_bf + j + 4) = *(ushort4*)(o + 4);
        return;
    }
    i -= PREP_W2;
    if (i < PREP_A) {
        int n = i / DI, d = i % DI;
        aT[i] = -__expf(A_log[d * DS + n]) * 1.44269504f;
        return;
    }
    i -= PREP_A;
    if (i < PREP_X) {
        int r = i / DI, c = i % DI;
        xpw_pad[i] = (r < DBCW) ? f2bf(x_proj_w[r * DI + c]) : (ushort_t)0;
        return;
    }
    i -= PREP_X;
    if (i < PREP_DT) {
        int r = i / 64, c = i % 64;
        dtw_bf[i] = (c < DTR) ? f2bf(dt_proj_w[r * DTR + c]) : (ushort_t)0;
    }
}

// ---------------- split-K partial reduce: out[i] = sum_z part[z][i] (float4) -------
__global__ __launch_bounds__(256) void reduce_sk4(const float4* __restrict__ part,
                                                  float4* __restrict__ out,
                                                  int count4, int nslices)
{
    int i = blockIdx.x * 256 + threadIdx.x;
    if (i >= count4) return;
    float4 s = part[i];
    for (int z = 1; z < nslices; ++z) {
        float4 p = part[(size_t)z * count4 + i];
        s.x += p.x; s.y += p.y; s.z += p.z; s.w += p.w;
    }
    out[i] = s;
}

// ---- x_proj split-K reduce: part 8x[2048][128] -> dbc[2048][80] fp32 + dtb[2048][64] bf16
__global__ __launch_bounds__(256) void reduce_dbc(const float* __restrict__ part,
                                                  float* __restrict__ dbc,
                                                  ushort_t* __restrict__ dtb)
{
    int i = blockIdx.x * 256 + threadIdx.x;    // over 2048*128
    if (i >= MROWS * XPN) return;
    float s = 0.f;
    #pragma unroll
    for (int z = 0; z < XP_KS; ++z)
        s += part[(size_t)z * MROWS * XPN + i];
    int r = i / XPN, c = i % XPN;
    if (c < DBCW) dbc[(size_t)r * DBCW + c] = s;
    if (c < 64)   dtb[(size_t)r * 64 + c] = (c < DTR) ? f2bf(s) : (ushort_t)0;
}

// ---------------- LayerNorm (fp32 in, bf16 out), shfl-based ----------------
__global__ __launch_bounds__(256) void ln_kernel(const float* __restrict__ x,
                                                 const float* __restrict__ w,
                                                 const float* __restrict__ b,
                                                 ushort_t* __restrict__ xn)
{
    __shared__ float part[8];
    int row = blockIdx.x;               // 0..2047
    const float* xr = x + (size_t)row * DIM;
    ushort_t* o = xn + (size_t)row * DIM;
    int tid = threadIdx.x;
    int lane = tid & 63, wid = tid >> 6;

    float v0 = xr[tid], v1 = xr[tid + 256], v2 = xr[tid + 512];
    float s = v0 + v1 + v2;
    #pragma unroll
    for (int off = 32; off > 0; off >>= 1) s += __shfl_xor(s, off);
    if (lane == 0) part[wid] = s;
    __syncthreads();
    float mu = (part[0] + part[1] + part[2] + part[3]) * (1.f / DIM);

    float d0 = v0 - mu, d1 = v1 - mu, d2 = v2 - mu;
    float q = d0 * d0 + d1 * d1 + d2 * d2;
    #pragma unroll
    for (int off = 32; off > 0; off >>= 1) q += __shfl_xor(q, off);
    if (lane == 0) part[4 + wid] = q;
    __syncthreads();
    float rstd = rsqrtf((part[4] + part[5] + part[6] + part[7]) * (1.f / DIM) + 1e-5f);

    o[tid]       = f2bf(d0 * rstd * w[tid]       + b[tid]);
    o[tid + 256] = f2bf(d1 * rstd * w[tid + 256] + b[tid + 256]);
    o[tid + 512] = f2bf(d2 * rstd * w[tid + 512] + b[tid + 512]);
}

// ---- bf16 MFMA GEMM, bf16 output: C(MxN bf16) = A(MxK bf16) @ W(NxK bf16)^T -------
__global__ __launch_bounds__(256) void gemm_bf16_obf(const ushort_t* __restrict__ A,
                                                     const ushort_t* __restrict__ W,
                                                     ushort_t* __restrict__ C,
                                                     int N, int K)
{
    __shared__ __align__(16) ushort_t As[128 * 32];
    __shared__ __align__(16) ushort_t Bs[128 * 32];

    int tid = threadIdx.x;
    int wave = tid >> 6, lane = tid & 63;
    int wr = wave >> 1, wc = wave & 1;
    int l15 = lane & 15, kb = lane >> 4;
    int m0 = blockIdx.y * 128, n0 = blockIdx.x * 128;

    f32x4 acc[4][4] = {};

    for (int k0 = 0; k0 < K; k0 += 32) {
        #pragma unroll
        for (int i = 0; i < 2; ++i) {
            int cbase = i * 256 + wave * 64;
            int c = cbase + lane;
            int row = c >> 2;
            int col = (c & 3) * 8;
            gload16(A + (size_t)(m0 + row) * K + k0 + col, (char*)As + (size_t)cbase * 16);
            gload16(W + (size_t)(n0 + row) * K + k0 + col, (char*)Bs + (size_t)cbase * 16);
        }
        __syncthreads();

        short8 af[4], bfr[4];
        #pragma unroll
        for (int m = 0; m < 4; ++m)
            af[m] = *(const short8*)&As[(wr * 64 + m * 16 + l15) * 32 + kb * 8];
        #pragma unroll
        for (int n = 0; n < 4; ++n)
            bfr[n] = *(const short8*)&Bs[(wc * 64 + n * 16 + l15) * 32 + kb * 8];

        #pragma unroll
        for (int m = 0; m < 4; ++m)
            #pragma unroll
            for (int n = 0; n < 4; ++n)
                acc[m][n] = __builtin_amdgcn_mfma_f32_16x16x32_bf16(af[m], bfr[n], acc[m][n], 0, 0, 0);

        __syncthreads();
    }

    int r0 = m0 + wr * 64 + kb * 4;
    int c0 = n0 + wc * 64 + l15;
    #pragma unroll
    for (int m = 0; m < 4; ++m)
        #pragma unroll
        for (int n = 0; n < 4; ++n) {
            int rr = r0 + m * 16;
            int cc = c0 + n * 16;
            #pragma unroll
            for (int r = 0; r < 4; ++r)
                C[(size_t)(rr + r) * N + cc] = f2bf(acc[m][n][r]);
        }
}

// ---- split-K bf16 MFMA GEMM: Cpart[z] = A @ W^T over K-slice z (z = blockIdx.z) ----
__global__ __launch_bounds__(256) void gemm_bf16_sk(const ushort_t* __restrict__ A,
                                                    const ushort_t* __restrict__ W,
                                                    float* __restrict__ Cpart,
                                                    int N, int Ktot, int Kslice, int M)
{
    __shared__ __align__(16) ushort_t As[128 * 32];
    __shared__ __align__(16) ushort_t Bs[128 * 32];

    int tid = threadIdx.x;
    int wave = tid >> 6, lane = tid & 63;
    int wr = wave >> 1, wc = wave & 1;
    int l15 = lane & 15, kb = lane >> 4;
    int m0 = blockIdx.y * 128, n0 = blockIdx.x * 128;
    int kbase = blockIdx.z * Kslice;
    float* C = Cpart + (size_t)blockIdx.z * M * N;

    f32x4 acc[4][4] = {};

    for (int k0 = kbase; k0 < kbase + Kslice; k0 += 32) {
        #pragma unroll
        for (int i = 0; i < 2; ++i) {
            int cbase = i * 256 + wave * 64;
            int c = cbase + lane;
            int row = c >> 2;
            int col = (c & 3) * 8;
            gload16(A + (size_t)(m0 + row) * Ktot + k0 + col, (char*)As + (size_t)cbase * 16);
            gload16(W + (size_t)(n0 + row) * Ktot + k0 + col, (char*)Bs + (size_t)cbase * 16);
        }
        __syncthreads();

        short8 af[4], bfr[4];
        #pragma unroll
        for (int m = 0; m < 4; ++m)
            af[m] = *(const short8*)&As[(wr * 64 + m * 16 + l15) * 32 + kb * 8];
        #pragma unroll
        for (int n = 0; n < 4; ++n)
            bfr[n] = *(const short8*)&Bs[(wc * 64 + n * 16 + l15) * 32 + kb * 8];

        #pragma unroll
        for (int m = 0; m < 4; ++m)
            #pragma unroll
            for (int n = 0; n < 4; ++n)
                acc[m][n] = __builtin_amdgcn_mfma_f32_16x16x32_bf16(af[m], bfr[n], acc[m][n], 0, 0, 0);

        __syncthreads();
    }

    int r0 = m0 + wr * 64 + kb * 4;
    int c0 = n0 + wc * 64 + l15;
    #pragma unroll
    for (int m = 0; m < 4; ++m)
        #pragma unroll
        for (int n = 0; n < 4; ++n) {
            int rr = r0 + m * 16;
            int cc = c0 + n * 16;
            #pragma unroll
            for (int r = 0; r < 4; ++r)
                C[(size_t)(rr + r) * N + cc] = acc[m][n][r];
        }
}

// ---- dt_proj bf16 MFMA, K=64 fixed, fused bias+softplus: delta = sp(A@W^T + b) ----
__global__ __launch_bounds__(256) void gemm_dt(const ushort_t* __restrict__ A,
                                               const ushort_t* __restrict__ W,
                                               const float* __restrict__ bias,
                                               float* __restrict__ C)
{
    __shared__ __align__(16) ushort_t As[128 * 32];
    __shared__ __align__(16) ushort_t Bs[128 * 32];

    int tid = threadIdx.x;
    int wave = tid >> 6, lane = tid & 63;
    int wr = wave >> 1, wc = wave & 1;
    int l15 = lane & 15, kb = lane >> 4;
    int m0 = blockIdx.y * 128, n0 = blockIdx.x * 128;

    f32x4 acc[4][4] = {};

    #pragma unroll
    for (int k0 = 0; k0 < 64; k0 += 32) {
        #pragma unroll
        for (int i = 0; i < 2; ++i) {
            int cbase = i * 256 + wave * 64;
            int c = cbase + lane;
            int row = c >> 2;
            int col = (c & 3) * 8;
            gload16(A + (size_t)(m0 + row) * 64 + k0 + col, (char*)As + (size_t)cbase * 16);
            gload16(W + (size_t)(n0 + row) * 64 + k0 + col, (char*)Bs + (size_t)cbase * 16);
        }
        __syncthreads();

        short8 af[4], bfr[4];
        #pragma unroll
        for (int m = 0; m < 4; ++m)
            af[m] = *(const short8*)&As[(wr * 64 + m * 16 + l15) * 32 + kb * 8];
        #pragma unroll
        for (int n = 0; n < 4; ++n)
            bfr[n] = *(const short8*)&Bs[(wc * 64 + n * 16 + l15) * 32 + kb * 8];

        #pragma unroll
        for (int m = 0; m < 4; ++m)
            #pragma unroll
            for (int n = 0; n < 4; ++n)
                acc[m][n] = __builtin_amdgcn_mfma_f32_16x16x32_bf16(af[m], bfr[n], acc[m][n], 0, 0, 0);

        __syncthreads();
    }

    int r0 = m0 + wr * 64 + kb * 4;
    int c0 = n0 + wc * 64 + l15;
    #pragma unroll
    for (int m = 0; m < 4; ++m)
        #pragma unroll
        for (int n = 0; n < 4; ++n) {
            int rr = r0 + m * 16;
            int cc = c0 + n * 16;
            float bv = bias[cc];
            #pragma unroll
            for (int r = 0; r < 4; ++r) {
                float v = acc[m][n][r] + bv;
                v = (v > 20.f) ? v : log1pf(__expf(v));
                C[(size_t)(rr + r) * DI + cc] = v;
            }
        }
}

// ---------- causal depthwise conv + SiLU (bf16 in, bf16 out, fp32 math) ------------
__global__ __launch_bounds__(256) void conv_silu_kernel(const ushort_t* __restrict__ xzb,
                                                        const float* __restrict__ cw,
                                                        const float* __restrict__ cb,
                                                        ushort_t* __restrict__ u_bf)
{
    int idx = blockIdx.x * 256 + threadIdx.x;   // over MROWS * DI/4
    int d4 = idx % (DI / 4);
    int bt = idx / (DI / 4);
    int t = bt % SEQ;
    int b = bt / SEQ;
    int d = d4 * 4;

    float4 w0 = *(const float4*)(cw + (d + 0) * 4);
    float4 w1 = *(const float4*)(cw + (d + 1) * 4);
    float4 w2 = *(const float4*)(cw + (d + 2) * 4);
    float4 w3 = *(const float4*)(cw + (d + 3) * 4);
    const float* wp[4] = { (const float*)&w0, (const float*)&w1,
                           (const float*)&w2, (const float*)&w3 };

    float4 acc = *(const float4*)(cb + d);
    #pragma unroll
    for (int k = 0; k < DCONV; ++k) {
        int tt = t - (DCONV - 1) + k;
        if (tt >= 0) {
            ushort4 xv = *(const ushort4*)(xzb + (size_t)(b * SEQ + tt) * XZW + d);
            acc.x += bf2f(xv.x) * wp[0][k];
            acc.y += bf2f(xv.y) * wp[1][k];
            acc.z += bf2f(xv.z) * wp[2][k];
            acc.w += bf2f(xv.w) * wp[3][k];
        }
    }
    acc.x *= sigmoidf_(acc.x);
    acc.y *= sigmoidf_(acc.y);
    acc.z *= sigmoidf_(acc.z);
    acc.w *= sigmoidf_(acc.w);
    ushort4 ob = { f2bf(acc.x), f2bf(acc.y), f2bf(acc.z), f2bf(acc.w) };
    *(ushort4*)(u_bf + (size_t)(b * SEQ + t) * DI + d) = ob;
}

// ======================= 3-kernel chunked scan, lane = channel =====================
// K1: chunk-local (P,S) with h_in = 0
__global__ __launch_bounds__(256) void scan_p1(const float* __restrict__ delta,
                                               const ushort_t* __restrict__ u,
                                               const float* __restrict__ dbc,
                                               const float* __restrict__ aT,
                                               float* __restrict__ Pw,
                                               float* __restrict__ Sw)
{
    __shared__ float Bs[4][CLEN][DS];          // 8 KB
    int tid = threadIdx.x;
    int lane = tid & 63, w = tid >> 6;
    int d = blockIdx.x * 64 + lane;
    int chunk = blockIdx.y * 4 + w;
    int b = blockIdx.z;
    int t0 = chunk * CLEN;

    #pragma unroll
    for (int i = 0; i < 2; ++i) {
        int idx = i * 64 + lane;
        int tl = idx >> 2, c = idx & 3;
        *(float4*)&Bs[w][tl][c * 4] =
            *(const float4*)(dbc + (size_t)(b * SEQ + t0 + tl) * DBCW + DTR + c * 4);
    }

    float a[DS];
    #pragma unroll
    for (int n = 0; n < DS; ++n) a[n] = aT[n * DI + d];

    __syncthreads();

    float P[DS], S[DS];
    #pragma unroll
    for (int n = 0; n < DS; ++n) { P[n] = 1.f; S[n] = 0.f; }

    const float* dp    = delta + ((size_t)b * SEQ + t0) * DI + d;
    const ushort_t* up = u     + ((size_t)b * SEQ + t0) * DI + d;
    #pragma unroll 4
    for (int j = 0; j < CLEN; ++j) {
        float dlt = dp[(size_t)j * DI];
        float uu  = bf2f(up[(size_t)j * DI]);
        float dltu = dlt * uu;
        #pragma unroll
        for (int n = 0; n < DS; ++n) {
            float dA = exp2f(dlt * a[n]);
            P[n] *= dA;
            S[n] = dA * S[n] + dltu * Bs[w][j][n];
        }
    }

    size_t base = (((size_t)b * NCHUNK + chunk) * DS) * DI + d;
    #pragma unroll
    for (int n = 0; n < DS; ++n) {
        Pw[base + (size_t)n * DI] = P[n];
        Sw[base + (size_t)n * DI] = S[n];
    }
}

// K2: serial combine across chunks -> Hin
__global__ __launch_bounds__(256) void scan_comb(const float* __restrict__ Pw,
                                                 const float* __restrict__ Sw,
                                                 float* __restrict__ Hin)
{
    int d = blockIdx.x * 256 + threadIdx.x;
    int n = blockIdx.y, b = blockIdx.z;
    float h = 0.f;
    for (int c = 0; c < NCHUNK; ++c) {
        size_t idx = (((size_t)b * NCHUNK + c) * DS + n) * DI + d;
        Hin[idx] = h;
        h = Pw[idx] * h + Sw[idx];
    }
}

// K3: replay with h_in, dot with C in-lane, gate with silu(z), write y bf16
__global__ __launch_bounds__(256) void scan_p3(const float* __restrict__ delta,
                                               const ushort_t* __restrict__ u,
                                               const float* __restrict__ dbc,
                                               const ushort_t* __restrict__ xzb,
                                               const float* __restrict__ aT,
                                               const float* __restrict__ Dp,
                                               const float* __restrict__ Hin,
                                               ushort_t* __restrict__ y)
{
    __shared__ float Bs[4][CLEN][2 * DS];      // 16 KB
    int tid = threadIdx.x;
    int lane = tid & 63, w = tid >> 6;
    int d = blockIdx.x * 64 + lane;
    int chunk = blockIdx.y * 4 + w;
    int b = blockIdx.z;
    int t0 = chunk * CLEN;

    #pragma unroll
    for (int i = 0; i < 4; ++i) {
        int idx = i * 64 + lane;
        int tl = idx >> 3, c = idx & 7;
        *(float4*)&Bs[w][tl][c * 4] =
            *(const float4*)(dbc + (size_t)(b * SEQ + t0 + tl) * DBCW + DTR + c * 4);
    }

    float a[DS], h[DS];
    #pragma unroll
    for (int n = 0; n < DS; ++n) a[n] = aT[n * DI + d];
    size_t hbase = (((size_t)b * NCHUNK + chunk) * DS) * DI + d;
    #pragma unroll
    for (int n = 0; n < DS; ++n) h[n] = Hin[hbase + (size_t)n * DI];

    float Dd = Dp[d];
    __syncthreads();

    const float* dp    = delta + ((size_t)b * SEQ + t0) * DI + d;
    const ushort_t* up = u     + ((size_t)b * SEQ + t0) * DI + d;
    const ushort_t* zp = xzb   + ((size_t)b * SEQ + t0) * XZW + DI + d;
    ushort_t* yp       = y     + ((size_t)b * SEQ + t0) * DI + d;

    #pragma unroll 2
    for (int j = 0; j < CLEN; ++j) {
        float dlt = dp[(size_t)j * DI];
        float uu  = bf2f(up[(size_t)j * DI]);
        float dltu = dlt * uu;
        #pragma unroll
        for (int n = 0; n < DS; ++n) {
            float dA = exp2f(dlt * a[n]);
            h[n] = dA * h[n] + dltu * Bs[w][j][n];
        }
        float p0 = 0.f, p1 = 0.f, p2 = 0.f, p3 = 0.f;
        #pragma unroll
        for (int n = 0; n < DS; n += 4) {
            p0 += h[n]     * Bs[w][j][DS + n];
            p1 += h[n + 1] * Bs[w][j][DS + n + 1];
            p2 += h[n + 2] * Bs[w][j][DS + n + 2];
            p3 += h[n + 3] * Bs[w][j][DS + n + 3];
        }
        float p = (p0 + p1) + (p2 + p3);
        float z = bf2f(zp[(size_t)j * XZW]);
        float yv = (p + uu * Dd) * (z * sigmoidf_(z));
        yp[(size_t)j * DI] = f2bf(yv);
    }
}

extern "C" void kernel_launch(void* const* d_in, const int* in_sizes, int n_in,
                              void* d_out, int out_size, void* d_ws, size_t ws_size,
                              hipStream_t stream) {
    const float* x         = (const float*)d_in[0];
    const float* ln_w      = (const float*)d_in[1];
    const float* ln_b      = (const float*)d_in[2];
    const float* in_proj_w = (const float*)d_in[3];   // (3072, 768)
    const float* conv_w    = (const float*)d_in[4];   // (1536, 4)
    const float* conv_b    = (const float*)d_in[5];   // (1536)
    const float* x_proj_w  = (const float*)d_in[6];   // (80, 1536)
    const float* dt_proj_w = (const float*)d_in[7];   // (1536, 48)
    const float* dt_proj_b = (const float*)d_in[8];   // (1536)
    const float* A_log     = (const float*)d_in[9];   // (1536, 16)
    const float* D_param   = (const float*)d_in[10];  // (1536)
    const float* out_proj_w= (const float*)d_in[11];  // (768, 1536)
    float* out = (float*)d_out;

    char* ws = (char*)d_ws;
    size_t off = 0;
    auto alloc = [&](size_t bytes) { void* p = ws + off; off += (bytes + 255) & ~255ull; return p; };

    ushort_t* xn_bf   = (ushort_t*)alloc((size_t)MROWS * DIM * 2);
    ushort_t* w_in_bf = (ushort_t*)alloc((size_t)XZW * DIM * 2);
    ushort_t* w_out_bf= (ushort_t*)alloc((size_t)DIM * DI * 2);
    ushort_t* y_bf    = (ushort_t*)alloc((size_t)MROWS * DI * 2);
    ushort_t* u_bf    = (ushort_t*)alloc((size_t)MROWS * DI * 2);
    ushort_t* xpw_pad = (ushort_t*)alloc((size_t)XPN * DI * 2);
    ushort_t* dtw_bf  = (ushort_t*)alloc((size_t)DI * 64 * 2);
    ushort_t* dtb     = (ushort_t*)alloc((size_t)MROWS * 64 * 2);
    ushort_t* xzb     = (ushort_t*)alloc((size_t)MROWS * XZW * 2);
    float* dbc   = (float*)alloc((size_t)MROWS * DBCW * 4);
    float* delta = (float*)alloc((size_t)MROWS * DI * 4);
    float* aT    = (float*)alloc((size_t)DS * DI * 4);
    float* xpart = (float*)alloc((size_t)XP_KS * MROWS * XPN * 4);
    float* opart = (float*)alloc((size_t)OP_KS * MROWS * DIM * 4);

    // scan scratch aliases opart (used only after scan): 3*B*NCHUNK*DS*DI = 18.9 MB <= 25.2 MB
    size_t cvol = (size_t)BATCH * NCHUNK * DS * DI;
    float* Pw  = opart;
    float* Sw  = opart + cvol;
    float* Hin = opart + 2 * cvol;

    // 0. fused prep: weight conversions, aT, padded x_proj/dt_proj bf16 weights
    hipLaunchKernelGGL(prep_all,
                       dim3((PREP_W1 + PREP_W2 + PREP_A + PREP_X + PREP_DT + 255) / 256),
                       dim3(256), 0, stream,
                       in_proj_w, out_proj_w, A_log, x_proj_w, dt_proj_w,
                       w_in_bf, w_out_bf, aT, xpw_pad, dtw_bf);

    // 1. LayerNorm -> bf16
    hipLaunchKernelGGL(ln_kernel, dim3(MROWS), dim3(256), 0, stream, x, ln_w, ln_b, xn_bf);

    // 2. in_proj (bf16 MFMA, bf16 out): xzb(2048x3072) = xn @ in_proj_w^T
    hipLaunchKernelGGL(gemm_bf16_obf, dim3(XZW / 128, MROWS / 128), dim3(256), 0, stream,
                       xn_bf, w_in_bf, xzb, XZW, DIM);

    // 3. conv + silu -> u_bf
    hipLaunchKernelGGL(conv_silu_kernel, dim3((MROWS * DI / 4) / 256), dim3(256), 0, stream,
                       xzb, conv_w, conv_b, u_bf);

    // 4. x_proj (bf16 MFMA split-K, N padded to 128): xpart[z] = u_bf @ xpw_pad^T
    hipLaunchKernelGGL(gemm_bf16_sk, dim3(XPN / 128, MROWS / 128, XP_KS), dim3(256), 0, stream,
                       u_bf, xpw_pad, xpart, XPN, DI, DI / XP_KS, MROWS);
    hipLaunchKernelGGL(reduce_dbc, dim3((MROWS * XPN + 255) / 256), dim3(256), 0, stream,
                       xpart, dbc, dtb);

    // 5. dt_proj (bf16 MFMA K=64) + bias + softplus -> delta
    hipLaunchKernelGGL(gemm_dt, dim3(DI / 128, MROWS / 128), dim3(256), 0, stream,
                       dtb, dtw_bf, dt_proj_b, delta);

    // 6. chunked scan: K1 (P,S) -> K2 combine -> K3 replay+gate
    hipLaunchKernelGGL(scan_p1, dim3(DI / 64, NCHUNK / 4, BATCH), dim3(256), 0, stream,
                       delta, u_bf, dbc, aT, Pw, Sw);
    hipLaunchKernelGGL(scan_comb, dim3(DI / 256, DS, BATCH), dim3(256), 0, stream,
                       Pw, Sw, Hin);
    hipLaunchKernelGGL(scan_p3, dim3(DI / 64, NCHUNK / 4, BATCH), dim3(256), 0, stream,
                       delta, u_bf, dbc, xzb, aT, D_param, Hin, y_bf);

    // 7. out_proj (bf16 MFMA split-K): out(2048x768) = y @ out_proj_w^T
    hipLaunchKernelGGL(gemm_bf16_sk, dim3(DIM / 128, MROWS / 128, OP_KS), dim3(256), 0, stream,
                       y_bf, w_out_bf, opart, DIM, DI, DI / OP_KS, MROWS);
    hipLaunchKernelGGL(reduce_sk4, dim3((MROWS * DIM / 4 + 255) / 256), dim3(256), 0, stream,
                       (const float4*)opart, (float4*)out, MROWS * DIM / 4, OP_KS);
}

// Round 12
// 170.674 us; speedup vs baseline: 1.6861x; 1.0484x over previous
//
#include <hip/hip_runtime.h>
#include <hip/hip_bf16.h>

// Mamba layer: prep+LN(fused) -> in_proj(bf16 MFMA BK=64 swizzled, bf16 out) -> conv+silu(bf16)
//              -> x_proj(bf16 MFMA split-K) -> dt_proj(bf16 MFMA K=64, softplus, bf16 out)
//              -> scan (lane=channel, 3-kernel chunked) -> out_proj(bf16 MFMA split-K)
#define BATCH 2
#define SEQ   1024
#define DIM   768
#define DI    1536
#define DS    16
#define DCONV 4
#define DTR   48
#define XZW   (2*DI)     // 3072
#define DBCW  (DTR+2*DS) // 80
#define MROWS (BATCH*SEQ) // 2048
#define NCHUNK 32
#define CLEN  (SEQ/NCHUNK) // 32
#define XP_KS 8          // x_proj split-K slices
#define OP_KS 4          // out_proj split-K slices
#define XPN   128        // padded x_proj output width

typedef unsigned short ushort_t;
typedef __attribute__((ext_vector_type(8))) short short8;
typedef __attribute__((ext_vector_type(4))) float f32x4;

__device__ __forceinline__ float sigmoidf_(float x) {
    return 1.f / (1.f + __expf(-x));
}

__device__ __forceinline__ ushort_t f2bf(float x) {
    union { float f; unsigned u; } c{x};
    unsigned r = c.u + 0x7FFF + ((c.u >> 16) & 1);   // RNE
    return (ushort_t)(r >> 16);
}

__device__ __forceinline__ float bf2f(ushort_t v) {
    union { unsigned u; float f; } c{(unsigned)v << 16};
    return c.f;
}

__device__ __forceinline__ void gload16(const void* g, void* lds) {
    __builtin_amdgcn_global_load_lds(
        (const __attribute__((address_space(1))) void*)g,
        (__attribute__((address_space(3))) void*)lds,
        16, 0, 0);
}

// ---- fused prep + LayerNorm (block-range dispatch) ----
#define PREP_W1 ((XZW*DIM)/8)            // 294912
#define PREP_W2 ((DIM*DI)/8)             // 147456
#define PREP_A  (DS*DI)                  // 24576
#define PREP_X  (XPN*DI)                 // 196608
#define PREP_DT (DI*64)                  // 98304
#define PREP_BLOCKS ((PREP_W1+PREP_W2+PREP_A+PREP_X+PREP_DT+255)/256)  // 2976
__global__ __launch_bounds__(256) void prep_ln(const float* __restrict__ in_proj_w,
                                               const float* __restrict__ out_proj_w,
                                               const float* __restrict__ A_log,
                                               const float* __restrict__ x_proj_w,
                                               const float* __restrict__ dt_proj_w,
                                               const float* __restrict__ x,
                                               const float* __restrict__ ln_w,
                                               const float* __restrict__ ln_b,
                                               ushort_t* __restrict__ w_in_bf,
                                               ushort_t* __restrict__ w_out_bf,
                                               float* __restrict__ aT,
                                               ushort_t* __restrict__ xpw_pad,
                                               ushort_t* __restrict__ dtw_bf,
                                               ushort_t* __restrict__ xn)
{
    __shared__ float part[8];
    if (blockIdx.x >= PREP_BLOCKS) {
        // --------- LayerNorm branch: one row per block ---------
        int row = blockIdx.x - PREP_BLOCKS;
        const float* xr = x + (size_t)row * DIM;
        ushort_t* o = xn + (size_t)row * DIM;
        int tid = threadIdx.x;
        int lane = tid & 63, wid = tid >> 6;

        float v0 = xr[tid], v1 = xr[tid + 256], v2 = xr[tid + 512];
        float s = v0 + v1 + v2;
        #pragma unroll
        for (int off = 32; off > 0; off >>= 1) s += __shfl_xor(s, off);
        if (lane == 0) part[wid] = s;
        __syncthreads();
        float mu = (part[0] + part[1] + part[2] + part[3]) * (1.f / DIM);

        float d0 = v0 - mu, d1 = v1 - mu, d2 = v2 - mu;
        float q = d0 * d0 + d1 * d1 + d2 * d2;
        #pragma unroll
        for (int off = 32; off > 0; off >>= 1) q += __shfl_xor(q, off);
        if (lane == 0) part[4 + wid] = q;
        __syncthreads();
        float rstd = rsqrtf((part[4] + part[5] + part[6] + part[7]) * (1.f / DIM) + 1e-5f);

        o[tid]       = f2bf(d0 * rstd * ln_w[tid]       + ln_b[tid]);
        o[tid + 256] = f2bf(d1 * rstd * ln_w[tid + 256] + ln_b[tid + 256]);
        o[tid + 512] = f2bf(d2 * rstd * ln_w[tid + 512] + ln_b[tid + 512]);
        return;
    }
    // --------- prep branch ---------
    int i = blockIdx.x * 256 + threadIdx.x;
    if (i < PREP_W1) {
        int j = i * 8;
        float4 a = *(const float4*)(in_proj_w + j);
        float4 b = *(const float4*)(in_proj_w + j + 4);
        ushort_t o[8] = { f2bf(a.x), f2bf(a.y), f2bf(a.z), f2bf(a.w),
                          f2bf(b.x), f2bf(b.y), f2bf(b.z), f2bf(b.w) };
        *(ushort4*)(w_in_bf + j)     = *(ushort4*)o;
        *(ushort4*)(w_in_bf + j + 4) = *(ushort4*)(o + 4);
        return;
    }
    i -= PREP_W1;
    if (i < PREP_W2) {
        int j = i * 8;
        float4 a = *(const float4*)(out_proj_w + j);
        float4 b = *(const float4*)(out_proj_w + j + 4);
        ushort_t o[8] = { f2bf(a.x), f2bf(a.y), f2bf(a.z), f2bf(a.w),
                          f2bf(b.x), f2bf(b.y), f2bf(b.z), f2bf(b.w) };
        *(ushort4*)(w_out_bf + j)     = *(ushort4*)o;
        *(ushort4*)(w_out_bf + j + 4) = *(ushort4*)(o + 4);
        return;
    }
    i -= PREP_W2;
    if (i < PREP_A) {
        int n = i / DI, d = i % DI;
        aT[i] = -__expf(A_log[d * DS + n]) * 1.44269504f;
        return;
    }
    i -= PREP_A;
    if (i < PREP_X) {
        int r = i / DI, c = i % DI;
        xpw_pad[i] = (r < DBCW) ? f2bf(x_proj_w[r * DI + c]) : (ushort_t)0;
        return;
    }
    i -= PREP_X;
    if (i < PREP_DT) {
        int r = i / 64, c = i % 64;
        dtw_bf[i] = (c < DTR) ? f2bf(dt_proj_w[r * DTR + c]) : (ushort_t)0;
    }
}

// ---------------- split-K partial reduce: out[i] = sum_z part[z][i] (float4) -------
__global__ __launch_bounds__(256) void reduce_sk4(const float4* __restrict__ part,
                                                  float4* __restrict__ out,
                                                  int count4, int nslices)
{
    int i = blockIdx.x * 256 + threadIdx.x;
    if (i >= count4) return;
    float4 s = part[i];
    for (int z = 1; z < nslices; ++z) {
        float4 p = part[(size_t)z * count4 + i];
        s.x += p.x; s.y += p.y; s.z += p.z; s.w += p.w;
    }
    out[i] = s;
}

// ---- x_proj split-K reduce: part 8x[2048][128] -> dbc[2048][80] fp32 + dtb[2048][64] bf16
__global__ __launch_bounds__(256) void reduce_dbc(const float* __restrict__ part,
                                                  float* __restrict__ dbc,
                                                  ushort_t* __restrict__ dtb)
{
    int i = blockIdx.x * 256 + threadIdx.x;    // over 2048*128
    if (i >= MROWS * XPN) return;
    int r = i / XPN, c = i % XPN;
    if (c >= DBCW) return;                     // cols 80..127 never written/used
    float s = 0.f;
    #pragma unroll
    for (int z = 0; z < XP_KS; ++z)
        s += part[(size_t)z * MROWS * XPN + i];
    dbc[(size_t)r * DBCW + c] = s;
    if (c < 64) dtb[(size_t)r * 64 + c] = (c < DTR) ? f2bf(s) : (ushort_t)0;
}

// ---- bf16 MFMA GEMM, BK=64, XOR-swizzled LDS, bf16 out: C = A(MxK) @ W(NxK)^T ----
// LDS rows are 128B; source col-group pre-swizzled (s = g ^ (row&7)) so the linear
// global_load_lds dest yields a swizzled layout; frag reads use the same XOR ->
// lanes spread over 8 distinct 16B slots (2-way, free).
__global__ __launch_bounds__(256) void gemm_bf16_obf(const ushort_t* __restrict__ A,
                                                     const ushort_t* __restrict__ W,
                                                     ushort_t* __restrict__ C,
                                                     int N, int K)
{
    __shared__ __align__(16) ushort_t As[128 * 64];
    __shared__ __align__(16) ushort_t Bs[128 * 64];

    int tid = threadIdx.x;
    int wave = tid >> 6, lane = tid & 63;
    int wr = wave >> 1, wc = wave & 1;
    int l15 = lane & 15, kb = lane >> 4;
    int m0 = blockIdx.y * 128, n0 = blockIdx.x * 128;

    f32x4 acc[4][4] = {};

    for (int k0 = 0; k0 < K; k0 += 64) {
        #pragma unroll
        for (int i = 0; i < 4; ++i) {
            int cbase = i * 256 + wave * 64;
            int c = cbase + lane;              // 0..1023 chunk id
            int row = c >> 3;                  // 8 x 16B chunks per 128B row
            int sg = (c & 7) ^ (row & 7);      // pre-swizzled source col-group
            gload16(A + (size_t)(m0 + row) * K + k0 + sg * 8, (char*)As + (size_t)cbase * 16);
            gload16(W + (size_t)(n0 + row) * K + k0 + sg * 8, (char*)Bs + (size_t)cbase * 16);
        }
        __syncthreads();

        #pragma unroll
        for (int kk = 0; kk < 2; ++kk) {
            short8 af[4], bfr[4];
            #pragma unroll
            for (int m = 0; m < 4; ++m) {
                int row = wr * 64 + m * 16 + l15;
                af[m] = *(const short8*)&As[row * 64 + (((kk * 4 + kb) ^ (row & 7)) * 8)];
            }
            #pragma unroll
            for (int n = 0; n < 4; ++n) {
                int row = wc * 64 + n * 16 + l15;
                bfr[n] = *(const short8*)&Bs[row * 64 + (((kk * 4 + kb) ^ (row & 7)) * 8)];
            }
            #pragma unroll
            for (int m = 0; m < 4; ++m)
                #pragma unroll
                for (int n = 0; n < 4; ++n)
                    acc[m][n] = __builtin_amdgcn_mfma_f32_16x16x32_bf16(af[m], bfr[n], acc[m][n], 0, 0, 0);
        }
        __syncthreads();
    }

    int r0 = m0 + wr * 64 + kb * 4;
    int c0 = n0 + wc * 64 + l15;
    #pragma unroll
    for (int m = 0; m < 4; ++m)
        #pragma unroll
        for (int n = 0; n < 4; ++n) {
            int rr = r0 + m * 16;
            int cc = c0 + n * 16;
            #pragma unroll
            for (int r = 0; r < 4; ++r)
                C[(size_t)(rr + r) * N + cc] = f2bf(acc[m][n][r]);
        }
}

// ---- split-K bf16 MFMA GEMM: Cpart[z] = A @ W^T over K-slice z; writes cols < Nw ----
__global__ __launch_bounds__(256) void gemm_bf16_sk(const ushort_t* __restrict__ A,
                                                    const ushort_t* __restrict__ W,
                                                    float* __restrict__ Cpart,
                                                    int N, int Ktot, int Kslice, int M, int Nw)
{
    __shared__ __align__(16) ushort_t As[128 * 32];
    __shared__ __align__(16) ushort_t Bs[128 * 32];

    int tid = threadIdx.x;
    int wave = tid >> 6, lane = tid & 63;
    int wr = wave >> 1, wc = wave & 1;
    int l15 = lane & 15, kb = lane >> 4;
    int m0 = blockIdx.y * 128, n0 = blockIdx.x * 128;
    int kbase = blockIdx.z * Kslice;
    float* C = Cpart + (size_t)blockIdx.z * M * N;

    f32x4 acc[4][4] = {};

    for (int k0 = kbase; k0 < kbase + Kslice; k0 += 32) {
        #pragma unroll
        for (int i = 0; i < 2; ++i) {
            int cbase = i * 256 + wave * 64;
            int c = cbase + lane;
            int row = c >> 2;
            int col = (c & 3) * 8;
            gload16(A + (size_t)(m0 + row) * Ktot + k0 + col, (char*)As + (size_t)cbase * 16);
            gload16(W + (size_t)(n0 + row) * Ktot + k0 + col, (char*)Bs + (size_t)cbase * 16);
        }
        __syncthreads();

        short8 af[4], bfr[4];
        #pragma unroll
        for (int m = 0; m < 4; ++m)
            af[m] = *(const short8*)&As[(wr * 64 + m * 16 + l15) * 32 + kb * 8];
        #pragma unroll
        for (int n = 0; n < 4; ++n)
            bfr[n] = *(const short8*)&Bs[(wc * 64 + n * 16 + l15) * 32 + kb * 8];

        #pragma unroll
        for (int m = 0; m < 4; ++m)
            #pragma unroll
            for (int n = 0; n < 4; ++n)
                acc[m][n] = __builtin_amdgcn_mfma_f32_16x16x32_bf16(af[m], bfr[n], acc[m][n], 0, 0, 0);

        __syncthreads();
    }

    int r0 = m0 + wr * 64 + kb * 4;
    int c0 = n0 + wc * 64 + l15;
    #pragma unroll
    for (int m = 0; m < 4; ++m)
        #pragma unroll
        for (int n = 0; n < 4; ++n) {
            int rr = r0 + m * 16;
            int cc = c0 + n * 16;
            if (cc < Nw) {
                #pragma unroll
                for (int r = 0; r < 4; ++r)
                    C[(size_t)(rr + r) * N + cc] = acc[m][n][r];
            }
        }
}

// ---- dt_proj bf16 MFMA, K=64, fused bias+softplus, bf16 out: delta = sp(A@W^T+b) ----
__global__ __launch_bounds__(256) void gemm_dt(const ushort_t* __restrict__ A,
                                               const ushort_t* __restrict__ W,
                                               const float* __restrict__ bias,
                                               ushort_t* __restrict__ C)
{
    __shared__ __align__(16) ushort_t As[128 * 32];
    __shared__ __align__(16) ushort_t Bs[128 * 32];

    int tid = threadIdx.x;
    int wave = tid >> 6, lane = tid & 63;
    int wr = wave >> 1, wc = wave & 1;
    int l15 = lane & 15, kb = lane >> 4;
    int m0 = blockIdx.y * 128, n0 = blockIdx.x * 128;

    f32x4 acc[4][4] = {};

    #pragma unroll
    for (int k0 = 0; k0 < 64; k0 += 32) {
        #pragma unroll
        for (int i = 0; i < 2; ++i) {
            int cbase = i * 256 + wave * 64;
            int c = cbase + lane;
            int row = c >> 2;
            int col = (c & 3) * 8;
            gload16(A + (size_t)(m0 + row) * 64 + k0 + col, (char*)As + (size_t)cbase * 16);
            gload16(W + (size_t)(n0 + row) * 64 + k0 + col, (char*)Bs + (size_t)cbase * 16);
        }
        __syncthreads();

        short8 af[4], bfr[4];
        #pragma unroll
        for (int m = 0; m < 4; ++m)
            af[m] = *(const short8*)&As[(wr * 64 + m * 16 + l15) * 32 + kb * 8];
        #pragma unroll
        for (int n = 0; n < 4; ++n)
            bfr[n] = *(const short8*)&Bs[(wc * 64 + n * 16 + l15) * 32 + kb * 8];

        #pragma unroll
        for (int m = 0; m < 4; ++m)
            #pragma unroll
            for (int n = 0; n < 4; ++n)
                acc[m][n] = __builtin_amdgcn_mfma_f32_16x16x32_bf16(af[m], bfr[n], acc[m][n], 0, 0, 0);

        __syncthreads();
    }

    int r0 = m0 + wr * 64 + kb * 4;
    int c0 = n0 + wc * 64 + l15;
    #pragma unroll
    for (int m = 0; m < 4; ++m)
        #pragma unroll
        for (int n = 0; n < 4; ++n) {
            int rr = r0 + m * 16;
            int cc = c0 + n * 16;
            float bv = bias[cc];
            #pragma unroll
            for (int r = 0; r < 4; ++r) {
                float v = acc[m][n][r] + bv;
                v = (v > 20.f) ? v : log1pf(__expf(v));
                C[(size_t)(rr + r) * DI + cc] = f2bf(v);
            }
        }
}

// ---------- causal depthwise conv + SiLU (bf16 in, bf16 out, fp32 math) ------------
__global__ __launch_bounds__(256) void conv_silu_kernel(const ushort_t* __restrict__ xzb,
                                                        const float* __restrict__ cw,
                                                        const float* __restrict__ cb,
                                                        ushort_t* __restrict__ u_bf)
{
    int idx = blockIdx.x * 256 + threadIdx.x;   // over MROWS * DI/4
    int d4 = idx % (DI / 4);
    int bt = idx / (DI / 4);
    int t = bt % SEQ;
    int b = bt / SEQ;
    int d = d4 * 4;

    float4 w0 = *(const float4*)(cw + (d + 0) * 4);
    float4 w1 = *(const float4*)(cw + (d + 1) * 4);
    float4 w2 = *(const float4*)(cw + (d + 2) * 4);
    float4 w3 = *(const float4*)(cw + (d + 3) * 4);
    const float* wp[4] = { (const float*)&w0, (const float*)&w1,
                           (const float*)&w2, (const float*)&w3 };

    float4 acc = *(const float4*)(cb + d);
    #pragma unroll
    for (int k = 0; k < DCONV; ++k) {
        int tt = t - (DCONV - 1) + k;
        if (tt >= 0) {
            ushort4 xv = *(const ushort4*)(xzb + (size_t)(b * SEQ + tt) * XZW + d);
            acc.x += bf2f(xv.x) * wp[0][k];
            acc.y += bf2f(xv.y) * wp[1][k];
            acc.z += bf2f(xv.z) * wp[2][k];
            acc.w += bf2f(xv.w) * wp[3][k];
        }
    }
    acc.x *= sigmoidf_(acc.x);
    acc.y *= sigmoidf_(acc.y);
    acc.z *= sigmoidf_(acc.z);
    acc.w *= sigmoidf_(acc.w);
    ushort4 ob = { f2bf(acc.x), f2bf(acc.y), f2bf(acc.z), f2bf(acc.w) };
    *(ushort4*)(u_bf + (size_t)(b * SEQ + t) * DI + d) = ob;
}

// ======================= 3-kernel chunked scan, lane = channel =====================
// K1: chunk-local (P,S) with h_in = 0
__global__ __launch_bounds__(256) void scan_p1(const ushort_t* __restrict__ delta,
                                               const ushort_t* __restrict__ u,
                                               const float* __restrict__ dbc,
                                               const float* __restrict__ aT,
                                               float* __restrict__ Pw,
                                               float* __restrict__ Sw)
{
    __shared__ float Bs[4][CLEN][DS];          // 8 KB
    int tid = threadIdx.x;
    int lane = tid & 63, w = tid >> 6;
    int d = blockIdx.x * 64 + lane;
    int chunk = blockIdx.y * 4 + w;
    int b = blockIdx.z;
    int t0 = chunk * CLEN;

    #pragma unroll
    for (int i = 0; i < 2; ++i) {
        int idx = i * 64 + lane;
        int tl = idx >> 2, c = idx & 3;
        *(float4*)&Bs[w][tl][c * 4] =
            *(const float4*)(dbc + (size_t)(b * SEQ + t0 + tl) * DBCW + DTR + c * 4);
    }

    float a[DS];
    #pragma unroll
    for (int n = 0; n < DS; ++n) a[n] = aT[n * DI + d];

    __syncthreads();

    float P[DS], S[DS];
    #pragma unroll
    for (int n = 0; n < DS; ++n) { P[n] = 1.f; S[n] = 0.f; }

    const ushort_t* dp = delta + ((size_t)b * SEQ + t0) * DI + d;
    const ushort_t* up = u     + ((size_t)b * SEQ + t0) * DI + d;
    #pragma unroll 4
    for (int j = 0; j < CLEN; ++j) {
        float dlt = bf2f(dp[(size_t)j * DI]);
        float uu  = bf2f(up[(size_t)j * DI]);
        float dltu = dlt * uu;
        #pragma unroll
        for (int n = 0; n < DS; ++n) {
            float dA = exp2f(dlt * a[n]);
            P[n] *= dA;
            S[n] = dA * S[n] + dltu * Bs[w][j][n];
        }
    }

    size_t base = (((size_t)b * NCHUNK + chunk) * DS) * DI + d;
    #pragma unroll
    for (int n = 0; n < DS; ++n) {
        Pw[base + (size_t)n * DI] = P[n];
        Sw[base + (size_t)n * DI] = S[n];
    }
}

// K2: serial combine across chunks -> Hin
__global__ __launch_bounds__(256) void scan_comb(const float* __restrict__ Pw,
                                                 const float* __restrict__ Sw,
                                                 float* __restrict__ Hin)
{
    int d = blockIdx.x * 256 + threadIdx.x;
    int n = blockIdx.y, b = blockIdx.z;
    float h = 0.f;
    for (int c = 0; c < NCHUNK; ++c) {
        size_t idx = (((size_t)b * NCHUNK + c) * DS + n) * DI + d;
        Hin[idx] = h;
        h = Pw[idx] * h + Sw[idx];
    }
}

// K3: replay with h_in, dot with C in-lane, gate with silu(z), write y bf16
__global__ __launch_bounds__(256) void scan_p3(const ushort_t* __restrict__ delta,
                                               const ushort_t* __restrict__ u,
                                               const float* __restrict__ dbc,
                                               const ushort_t* __restrict__ xzb,
                                               const float* __restrict__ aT,
                                               const float* __restrict__ Dp,
                                               const float* __restrict__ Hin,
                                               ushort_t* __restrict__ y)
{
    __shared__ float Bs[4][CLEN][2 * DS];      // 16 KB
    int tid = threadIdx.x;
    int lane = tid & 63, w = tid >> 6;
    int d = blockIdx.x * 64 + lane;
    int chunk = blockIdx.y * 4 + w;
    int b = blockIdx.z;
    int t0 = chunk * CLEN;

    #pragma unroll
    for (int i = 0; i < 4; ++i) {
        int idx = i * 64 + lane;
        int tl = idx >> 3, c = idx & 7;
        *(float4*)&Bs[w][tl][c * 4] =
            *(const float4*)(dbc + (size_t)(b * SEQ + t0 + tl) * DBCW + DTR + c * 4);
    }

    float a[DS], h[DS];
    #pragma unroll
    for (int n = 0; n < DS; ++n) a[n] = aT[n * DI + d];
    size_t hbase = (((size_t)b * NCHUNK + chunk) * DS) * DI + d;
    #pragma unroll
    for (int n = 0; n < DS; ++n) h[n] = Hin[hbase + (size_t)n * DI];

    float Dd = Dp[d];
    __syncthreads();

    const ushort_t* dp = delta + ((size_t)b * SEQ + t0) * DI + d;
    const ushort_t* up = u     + ((size_t)b * SEQ + t0) * DI + d;
    const ushort_t* zp = xzb   + ((size_t)b * SEQ + t0) * XZW + DI + d;
    ushort_t* yp       = y     + ((size_t)b * SEQ + t0) * DI + d;

    #pragma unroll 2
    for (int j = 0; j < CLEN; ++j) {
        float dlt = bf2f(dp[(size_t)j * DI]);
        float uu  = bf2f(up[(size_t)j * DI]);
        float dltu = dlt * uu;
        #pragma unroll
        for (int n = 0; n < DS; ++n) {
            float dA = exp2f(dlt * a[n]);
            h[n] = dA * h[n] + dltu * Bs[w][j][n];
        }
        float p0 = 0.f, p1 = 0.f, p2 = 0.f, p3 = 0.f;
        #pragma unroll
        for (int n = 0; n < DS; n += 4) {
            p0 += h[n]     * Bs[w][j][DS + n];
            p1 += h[n + 1] * Bs[w][j][DS + n + 1];
            p2 += h[n + 2] * Bs[w][j][DS + n + 2];
            p3 += h[n + 3] * Bs[w][j][DS + n + 3];
        }
        float p = (p0 + p1) + (p2 + p3);
        float z = bf2f(zp[(size_t)j * XZW]);
        float yv = (p + uu * Dd) * (z * sigmoidf_(z));
        yp[(size_t)j * DI] = f2bf(yv);
    }
}

extern "C" void kernel_launch(void* const* d_in, const int* in_sizes, int n_in,
                              void* d_out, int out_size, void* d_ws, size_t ws_size,
                              hipStream_t stream) {
    const float* x         = (const float*)d_in[0];
    const float* ln_w      = (const float*)d_in[1];
    const float* ln_b      = (const float*)d_in[2];
    const float* in_proj_w = (const float*)d_in[3];   // (3072, 768)
    const float* conv_w    = (const float*)d_in[4];   // (1536, 4)
    const float* conv_b    = (const float*)d_in[5];   // (1536)
    const float* x_proj_w  = (const float*)d_in[6];   // (80, 1536)
    const float* dt_proj_w = (const float*)d_in[7];   // (1536, 48)
    const float* dt_proj_b = (const float*)d_in[8];   // (1536)
    const float* A_log     = (const float*)d_in[9];   // (1536, 16)
    const float* D_param   = (const float*)d_in[10];  // (1536)
    const float* out_proj_w= (const float*)d_in[11];  // (768, 1536)
    float* out = (float*)d_out;

    char* ws = (char*)d_ws;
    size_t off = 0;
    auto alloc = [&](size_t bytes) { void* p = ws + off; off += (bytes + 255) & ~255ull; return p; };

    ushort_t* xn_bf   = (ushort_t*)alloc((size_t)MROWS * DIM * 2);
    ushort_t* w_in_bf = (ushort_t*)alloc((size_t)XZW * DIM * 2);
    ushort_t* w_out_bf= (ushort_t*)alloc((size_t)DIM * DI * 2);
    ushort_t* y_bf    = (ushort_t*)alloc((size_t)MROWS * DI * 2);
    ushort_t* u_bf    = (ushort_t*)alloc((size_t)MROWS * DI * 2);
    ushort_t* xpw_pad = (ushort_t*)alloc((size_t)XPN * DI * 2);
    ushort_t* dtw_bf  = (ushort_t*)alloc((size_t)DI * 64 * 2);
    ushort_t* dtb     = (ushort_t*)alloc((size_t)MROWS * 64 * 2);
    ushort_t* xzb     = (ushort_t*)alloc((size_t)MROWS * XZW * 2);
    ushort_t* delta_bf= (ushort_t*)alloc((size_t)MROWS * DI * 2);
    float* dbc   = (float*)alloc((size_t)MROWS * DBCW * 4);
    float* aT    = (float*)alloc((size_t)DS * DI * 4);
    float* xpart = (float*)alloc((size_t)XP_KS * MROWS * XPN * 4);
    float* opart = (float*)alloc((size_t)OP_KS * MROWS * DIM * 4);

    // scan scratch aliases opart (used only after scan): 3*B*NCHUNK*DS*DI = 18.9 MB <= 25.2 MB
    size_t cvol = (size_t)BATCH * NCHUNK * DS * DI;
    float* Pw  = opart;
    float* Sw  = opart + cvol;
    float* Hin = opart + 2 * cvol;

    // 0+1. fused prep (weight cvts, aT, padded weights) + LayerNorm
    hipLaunchKernelGGL(prep_ln, dim3(PREP_BLOCKS + MROWS), dim3(256), 0, stream,
                       in_proj_w, out_proj_w, A_log, x_proj_w, dt_proj_w,
                       x, ln_w, ln_b,
                       w_in_bf, w_out_bf, aT, xpw_pad, dtw_bf, xn_bf);

    // 2. in_proj (bf16 MFMA BK=64 swizzled, bf16 out): xzb = xn @ in_proj_w^T
    hipLaunchKernelGGL(gemm_bf16_obf, dim3(XZW / 128, MROWS / 128), dim3(256), 0, stream,
                       xn_bf, w_in_bf, xzb, XZW, DIM);

    // 3. conv + silu -> u_bf
    hipLaunchKernelGGL(conv_silu_kernel, dim3((MROWS * DI / 4) / 256), dim3(256), 0, stream,
                       xzb, conv_w, conv_b, u_bf);

    // 4. x_proj (bf16 MFMA split-K, N padded to 128, writes cols<80): xpart[z] = u_bf @ xpw_pad^T
    hipLaunchKernelGGL(gemm_bf16_sk, dim3(XPN / 128, MROWS / 128, XP_KS), dim3(256), 0, stream,
                       u_bf, xpw_pad, xpart, XPN, DI, DI / XP_KS, MROWS, DBCW);
    hipLaunchKernelGGL(reduce_dbc, dim3((MROWS * XPN + 255) / 256), dim3(256), 0, stream,
                       xpart, dbc, dtb);

    // 5. dt_proj (bf16 MFMA K=64) + bias + softplus -> delta (bf16)
    hipLaunchKernelGGL(gemm_dt, dim3(DI / 128, MROWS / 128), dim3(256), 0, stream,
                       dtb, dtw_bf, dt_proj_b, delta_bf);

    // 6. chunked scan: K1 (P,S) -> K2 combine -> K3 replay+gate
    hipLaunchKernelGGL(scan_p1, dim3(DI / 64, NCHUNK / 4, BATCH), dim3(256), 0, stream,
                       delta_bf, u_bf, dbc, aT, Pw, Sw);
    hipLaunchKernelGGL(scan_comb, dim3(DI / 256, DS, BATCH), dim3(256), 0, stream,
                       Pw, Sw, Hin);
    hipLaunchKernelGGL(scan_p3, dim3(DI / 64, NCHUNK / 4, BATCH), dim3(256), 0, stream,
                       delta_bf, u_bf, dbc, xzb, aT, D_param, Hin, y_bf);

    // 7. out_proj (bf16 MFMA split-K): out(2048x768) = y @ out_proj_w^T
    hipLaunchKernelGGL(gemm_bf16_sk, dim3(DIM / 128, MROWS / 128, OP_KS), dim3(256), 0, stream,
                       y_bf, w_out_bf, opart, DIM, DI, DI / OP_KS, MROWS, DIM);
    hipLaunchKernelGGL(reduce_sk4, dim3((MROWS * DIM / 4 + 255) / 256), dim3(256), 0, stream,
                       (const float4*)opart, (float4*)out, MROWS * DIM / 4, OP_KS);
}

// Round 13
// 168.999 us; speedup vs baseline: 1.7028x; 1.0099x over previous
//
#include <hip/hip_runtime.h>
#include <hip/hip_bf16.h>

// Mamba layer: prep+LN(fused) -> in_proj(bf16 MFMA BK=64 swizzled, bf16 out) -> conv+silu(bf16)
//              -> x_proj(bf16 MFMA split-K) -> dt_proj(bf16 MFMA K=64, softplus, bf16 out)
//              -> scan (lane=channel, 3-kernel chunked) -> out_proj(bf16 MFMA split-K)
// All MFMA GEMMs use XCD-chunked block swizzle (T1) for L2 panel locality.
#define BATCH 2
#define SEQ   1024
#define DIM   768
#define DI    1536
#define DS    16
#define DCONV 4
#define DTR   48
#define XZW   (2*DI)     // 3072
#define DBCW  (DTR+2*DS) // 80
#define MROWS (BATCH*SEQ) // 2048
#define NCHUNK 32
#define CLEN  (SEQ/NCHUNK) // 32
#define XP_KS 8          // x_proj split-K slices
#define OP_KS 4          // out_proj split-K slices
#define XPN   128        // padded x_proj output width

typedef unsigned short ushort_t;
typedef __attribute__((ext_vector_type(8))) short short8;
typedef __attribute__((ext_vector_type(4))) float f32x4;

__device__ __forceinline__ float sigmoidf_(float x) {
    return 1.f / (1.f + __expf(-x));
}

__device__ __forceinline__ ushort_t f2bf(float x) {
    union { float f; unsigned u; } c{x};
    unsigned r = c.u + 0x7FFF + ((c.u >> 16) & 1);   // RNE
    return (ushort_t)(r >> 16);
}

__device__ __forceinline__ float bf2f(ushort_t v) {
    union { unsigned u; float f; } c{(unsigned)v << 16};
    return c.f;
}

__device__ __forceinline__ void gload16(const void* g, void* lds) {
    __builtin_amdgcn_global_load_lds(
        (const __attribute__((address_space(1))) void*)g,
        (__attribute__((address_space(3))) void*)lds,
        16, 0, 0);
}

// XCD-chunked bijective block-id swizzle (nb must be divisible by 8):
// hardware round-robins flat dispatch id across 8 XCDs; this relabeling gives
// each XCD a contiguous range of logical tile ids -> L2 panel locality.
__device__ __forceinline__ int xcd_swz(int f, int nb) {
    return (f & 7) * (nb >> 3) + (f >> 3);
}

// ---- fused prep + LayerNorm (block-range dispatch) ----
#define PREP_W1 ((XZW*DIM)/8)            // 294912
#define PREP_W2 ((DIM*DI)/8)             // 147456
#define PREP_A  (DS*DI)                  // 24576
#define PREP_X  (XPN*DI)                 // 196608
#define PREP_DT (DI*64)                  // 98304
#define PREP_BLOCKS ((PREP_W1+PREP_W2+PREP_A+PREP_X+PREP_DT+255)/256)  // 2976
__global__ __launch_bounds__(256) void prep_ln(const float* __restrict__ in_proj_w,
                                               const float* __restrict__ out_proj_w,
                                               const float* __restrict__ A_log,
                                               const float* __restrict__ x_proj_w,
                                               const float* __restrict__ dt_proj_w,
                                               const float* __restrict__ x,
                                               const float* __restrict__ ln_w,
                                               const float* __restrict__ ln_b,
                                               ushort_t* __restrict__ w_in_bf,
                                               ushort_t* __restrict__ w_out_bf,
                                               float* __restrict__ aT,
                                               ushort_t* __restrict__ xpw_pad,
                                               ushort_t* __restrict__ dtw_bf,
                                               ushort_t* __restrict__ xn)
{
    __shared__ float part[8];
    if (blockIdx.x >= PREP_BLOCKS) {
        // --------- LayerNorm branch: one row per block ---------
        int row = blockIdx.x - PREP_BLOCKS;
        const float* xr = x + (size_t)row * DIM;
        ushort_t* o = xn + (size_t)row * DIM;
        int tid = threadIdx.x;
        int lane = tid & 63, wid = tid >> 6;

        float v0 = xr[tid], v1 = xr[tid + 256], v2 = xr[tid + 512];
        float s = v0 + v1 + v2;
        #pragma unroll
        for (int off = 32; off > 0; off >>= 1) s += __shfl_xor(s, off);
        if (lane == 0) part[wid] = s;
        __syncthreads();
        float mu = (part[0] + part[1] + part[2] + part[3]) * (1.f / DIM);

        float d0 = v0 - mu, d1 = v1 - mu, d2 = v2 - mu;
        float q = d0 * d0 + d1 * d1 + d2 * d2;
        #pragma unroll
        for (int off = 32; off > 0; off >>= 1) q += __shfl_xor(q, off);
        if (lane == 0) part[4 + wid] = q;
        __syncthreads();
        float rstd = rsqrtf((part[4] + part[5] + part[6] + part[7]) * (1.f / DIM) + 1e-5f);

        o[tid]       = f2bf(d0 * rstd * ln_w[tid]       + ln_b[tid]);
        o[tid + 256] = f2bf(d1 * rstd * ln_w[tid + 256] + ln_b[tid + 256]);
        o[tid + 512] = f2bf(d2 * rstd * ln_w[tid + 512] + ln_b[tid + 512]);
        return;
    }
    // --------- prep branch ---------
    int i = blockIdx.x * 256 + threadIdx.x;
    if (i < PREP_W1) {
        int j = i * 8;
        float4 a = *(const float4*)(in_proj_w + j);
        float4 b = *(const float4*)(in_proj_w + j + 4);
        ushort_t o[8] = { f2bf(a.x), f2bf(a.y), f2bf(a.z), f2bf(a.w),
                          f2bf(b.x), f2bf(b.y), f2bf(b.z), f2bf(b.w) };
        *(ushort4*)(w_in_bf + j)     = *(ushort4*)o;
        *(ushort4*)(w_in_bf + j + 4) = *(ushort4*)(o + 4);
        return;
    }
    i -= PREP_W1;
    if (i < PREP_W2) {
        int j = i * 8;
        float4 a = *(const float4*)(out_proj_w + j);
        float4 b = *(const float4*)(out_proj_w + j + 4);
        ushort_t o[8] = { f2bf(a.x), f2bf(a.y), f2bf(a.z), f2bf(a.w),
                          f2bf(b.x), f2bf(b.y), f2bf(b.z), f2bf(b.w) };
        *(ushort4*)(w_out_bf + j)     = *(ushort4*)o;
        *(ushort4*)(w_out_bf + j + 4) = *(ushort4*)(o + 4);
        return;
    }
    i -= PREP_W2;
    if (i < PREP_A) {
        int n = i / DI, d = i % DI;
        aT[i] = -__expf(A_log[d * DS + n]) * 1.44269504f;
        return;
    }
    i -= PREP_A;
    if (i < PREP_X) {
        int r = i / DI, c = i % DI;
        xpw_pad[i] = (r < DBCW) ? f2bf(x_proj_w[r * DI + c]) : (ushort_t)0;
        return;
    }
    i -= PREP_X;
    if (i < PREP_DT) {
        int r = i / 64, c = i % 64;
        dtw_bf[i] = (c < DTR) ? f2bf(dt_proj_w[r * DTR + c]) : (ushort_t)0;
    }
}

// ---------------- split-K partial reduce: out[i] = sum_z part[z][i] (float4) -------
__global__ __launch_bounds__(256) void reduce_sk4(const float4* __restrict__ part,
                                                  float4* __restrict__ out,
                                                  int count4, int nslices)
{
    int i = blockIdx.x * 256 + threadIdx.x;
    if (i >= count4) return;
    float4 s = part[i];
    for (int z = 1; z < nslices; ++z) {
        float4 p = part[(size_t)z * count4 + i];
        s.x += p.x; s.y += p.y; s.z += p.z; s.w += p.w;
    }
    out[i] = s;
}

// ---- x_proj split-K reduce: part 8x[2048][128] -> dbc[2048][80] fp32 + dtb[2048][64] bf16
__global__ __launch_bounds__(256) void reduce_dbc(const float* __restrict__ part,
                                                  float* __restrict__ dbc,
                                                  ushort_t* __restrict__ dtb)
{
    int i = blockIdx.x * 256 + threadIdx.x;    // over 2048*128
    if (i >= MROWS * XPN) return;
    int r = i / XPN, c = i % XPN;
    if (c >= DBCW) return;                     // cols 80..127 never written/used
    float s = 0.f;
    #pragma unroll
    for (int z = 0; z < XP_KS; ++z)
        s += part[(size_t)z * MROWS * XPN + i];
    dbc[(size_t)r * DBCW + c] = s;
    if (c < 64) dtb[(size_t)r * 64 + c] = (c < DTR) ? f2bf(s) : (ushort_t)0;
}

// ---- bf16 MFMA GEMM, BK=64, XOR-swizzled LDS, bf16 out, XCD-swizzled grid ----
__global__ __launch_bounds__(256) void gemm_bf16_obf(const ushort_t* __restrict__ A,
                                                     const ushort_t* __restrict__ W,
                                                     ushort_t* __restrict__ C,
                                                     int N, int K)
{
    __shared__ __align__(16) ushort_t As[128 * 64];
    __shared__ __align__(16) ushort_t Bs[128 * 64];

    int tid = threadIdx.x;
    int wave = tid >> 6, lane = tid & 63;
    int wr = wave >> 1, wc = wave & 1;
    int l15 = lane & 15, kb = lane >> 4;

    int gx = gridDim.x, nb = gx * gridDim.y;
    int l = xcd_swz(blockIdx.y * gx + blockIdx.x, nb);
    int m0 = (l / gx) * 128, n0 = (l % gx) * 128;

    f32x4 acc[4][4] = {};

    for (int k0 = 0; k0 < K; k0 += 64) {
        #pragma unroll
        for (int i = 0; i < 4; ++i) {
            int cbase = i * 256 + wave * 64;
            int c = cbase + lane;              // 0..1023 chunk id
            int row = c >> 3;                  // 8 x 16B chunks per 128B row
            int sg = (c & 7) ^ (row & 7);      // pre-swizzled source col-group
            gload16(A + (size_t)(m0 + row) * K + k0 + sg * 8, (char*)As + (size_t)cbase * 16);
            gload16(W + (size_t)(n0 + row) * K + k0 + sg * 8, (char*)Bs + (size_t)cbase * 16);
        }
        __syncthreads();

        #pragma unroll
        for (int kk = 0; kk < 2; ++kk) {
            short8 af[4], bfr[4];
            #pragma unroll
            for (int m = 0; m < 4; ++m) {
                int row = wr * 64 + m * 16 + l15;
                af[m] = *(const short8*)&As[row * 64 + (((kk * 4 + kb) ^ (row & 7)) * 8)];
            }
            #pragma unroll
            for (int n = 0; n < 4; ++n) {
                int row = wc * 64 + n * 16 + l15;
                bfr[n] = *(const short8*)&Bs[row * 64 + (((kk * 4 + kb) ^ (row & 7)) * 8)];
            }
            #pragma unroll
            for (int m = 0; m < 4; ++m)
                #pragma unroll
                for (int n = 0; n < 4; ++n)
                    acc[m][n] = __builtin_amdgcn_mfma_f32_16x16x32_bf16(af[m], bfr[n], acc[m][n], 0, 0, 0);
        }
        __syncthreads();
    }

    int r0 = m0 + wr * 64 + kb * 4;
    int c0 = n0 + wc * 64 + l15;
    #pragma unroll
    for (int m = 0; m < 4; ++m)
        #pragma unroll
        for (int n = 0; n < 4; ++n) {
            int rr = r0 + m * 16;
            int cc = c0 + n * 16;
            #pragma unroll
            for (int r = 0; r < 4; ++r)
                C[(size_t)(rr + r) * N + cc] = f2bf(acc[m][n][r]);
        }
}

// ---- split-K bf16 MFMA GEMM, XCD-swizzled grid; writes cols < Nw ----
__global__ __launch_bounds__(256) void gemm_bf16_sk(const ushort_t* __restrict__ A,
                                                    const ushort_t* __restrict__ W,
                                                    float* __restrict__ Cpart,
                                                    int N, int Ktot, int Kslice, int M, int Nw)
{
    __shared__ __align__(16) ushort_t As[128 * 32];
    __shared__ __align__(16) ushort_t Bs[128 * 32];

    int tid = threadIdx.x;
    int wave = tid >> 6, lane = tid & 63;
    int wr = wave >> 1, wc = wave & 1;
    int l15 = lane & 15, kb = lane >> 4;

    int gx = gridDim.x, gy = gridDim.y;
    int nb = gx * gy * gridDim.z;
    int f = (blockIdx.z * gy + blockIdx.y) * gx + blockIdx.x;
    int l = xcd_swz(f, nb);
    int bx = l % gx, by = (l / gx) % gy, bz = l / (gx * gy);
    int m0 = by * 128, n0 = bx * 128;
    int kbase = bz * Kslice;
    float* C = Cpart + (size_t)bz * M * N;

    f32x4 acc[4][4] = {};

    for (int k0 = kbase; k0 < kbase + Kslice; k0 += 32) {
        #pragma unroll
        for (int i = 0; i < 2; ++i) {
            int cbase = i * 256 + wave * 64;
            int c = cbase + lane;
            int row = c >> 2;
            int col = (c & 3) * 8;
            gload16(A + (size_t)(m0 + row) * Ktot + k0 + col, (char*)As + (size_t)cbase * 16);
            gload16(W + (size_t)(n0 + row) * Ktot + k0 + col, (char*)Bs + (size_t)cbase * 16);
        }
        __syncthreads();

        short8 af[4], bfr[4];
        #pragma unroll
        for (int m = 0; m < 4; ++m)
            af[m] = *(const short8*)&As[(wr * 64 + m * 16 + l15) * 32 + kb * 8];
        #pragma unroll
        for (int n = 0; n < 4; ++n)
            bfr[n] = *(const short8*)&Bs[(wc * 64 + n * 16 + l15) * 32 + kb * 8];

        #pragma unroll
        for (int m = 0; m < 4; ++m)
            #pragma unroll
            for (int n = 0; n < 4; ++n)
                acc[m][n] = __builtin_amdgcn_mfma_f32_16x16x32_bf16(af[m], bfr[n], acc[m][n], 0, 0, 0);

        __syncthreads();
    }

    int r0 = m0 + wr * 64 + kb * 4;
    int c0 = n0 + wc * 64 + l15;
    #pragma unroll
    for (int m = 0; m < 4; ++m)
        #pragma unroll
        for (int n = 0; n < 4; ++n) {
            int rr = r0 + m * 16;
            int cc = c0 + n * 16;
            if (cc < Nw) {
                #pragma unroll
                for (int r = 0; r < 4; ++r)
                    C[(size_t)(rr + r) * N + cc] = acc[m][n][r];
            }
        }
}

// ---- dt_proj bf16 MFMA, K=64, fused bias+softplus, bf16 out, XCD-swizzled grid ----
__global__ __launch_bounds__(256) void gemm_dt(const ushort_t* __restrict__ A,
                                               const ushort_t* __restrict__ W,
                                               const float* __restrict__ bias,
                                               ushort_t* __restrict__ C)
{
    __shared__ __align__(16) ushort_t As[128 * 32];
    __shared__ __align__(16) ushort_t Bs[128 * 32];

    int tid = threadIdx.x;
    int wave = tid >> 6, lane = tid & 63;
    int wr = wave >> 1, wc = wave & 1;
    int l15 = lane & 15, kb = lane >> 4;

    int gx = gridDim.x, nb = gx * gridDim.y;
    int l = xcd_swz(blockIdx.y * gx + blockIdx.x, nb);
    int m0 = (l / gx) * 128, n0 = (l % gx) * 128;

    f32x4 acc[4][4] = {};

    #pragma unroll
    for (int k0 = 0; k0 < 64; k0 += 32) {
        #pragma unroll
        for (int i = 0; i < 2; ++i) {
            int cbase = i * 256 + wave * 64;
            int c = cbase + lane;
            int row = c >> 2;
            int col = (c & 3) * 8;
            gload16(A + (size_t)(m0 + row) * 64 + k0 + col, (char*)As + (size_t)cbase * 16);
            gload16(W + (size_t)(n0 + row) * 64 + k0 + col, (char*)Bs + (size_t)cbase * 16);
        }
        __syncthreads();

        short8 af[4], bfr[4];
        #pragma unroll
        for (int m = 0; m < 4; ++m)
            af[m] = *(const short8*)&As[(wr * 64 + m * 16 + l15) * 32 + kb * 8];
        #pragma unroll
        for (int n = 0; n < 4; ++n)
            bfr[n] = *(const short8*)&Bs[(wc * 64 + n * 16 + l15) * 32 + kb * 8];

        #pragma unroll
        for (int m = 0; m < 4; ++m)
            #pragma unroll
            for (int n = 0; n < 4; ++n)
                acc[m][n] = __builtin_amdgcn_mfma_f32_16x16x32_bf16(af[m], bfr[n], acc[m][n], 0, 0, 0);

        __syncthreads();
    }

    int r0 = m0 + wr * 64 + kb * 4;
    int c0 = n0 + wc * 64 + l15;
    #pragma unroll
    for (int m = 0; m < 4; ++m)
        #pragma unroll
        for (int n = 0; n < 4; ++n) {
            int rr = r0 + m * 16;
            int cc = c0 + n * 16;
            float bv = bias[cc];
            #pragma unroll
            for (int r = 0; r < 4; ++r) {
                float v = acc[m][n][r] + bv;
                v = (v > 20.f) ? v : log1pf(__expf(v));
                C[(size_t)(rr + r) * DI + cc] = f2bf(v);
            }
        }
}

// ---------- causal depthwise conv + SiLU (bf16 in, bf16 out, fp32 math) ------------
__global__ __launch_bounds__(256) void conv_silu_kernel(const ushort_t* __restrict__ xzb,
                                                        const float* __restrict__ cw,
                                                        const float* __restrict__ cb,
                                                        ushort_t* __restrict__ u_bf)
{
    int idx = blockIdx.x * 256 + threadIdx.x;   // over MROWS * DI/4
    int d4 = idx % (DI / 4);
    int bt = idx / (DI / 4);
    int t = bt % SEQ;
    int b = bt / SEQ;
    int d = d4 * 4;

    float4 w0 = *(const float4*)(cw + (d + 0) * 4);
    float4 w1 = *(const float4*)(cw + (d + 1) * 4);
    float4 w2 = *(const float4*)(cw + (d + 2) * 4);
    float4 w3 = *(const float4*)(cw + (d + 3) * 4);
    const float* wp[4] = { (const float*)&w0, (const float*)&w1,
                           (const float*)&w2, (const float*)&w3 };

    float4 acc = *(const float4*)(cb + d);
    #pragma unroll
    for (int k = 0; k < DCONV; ++k) {
        int tt = t - (DCONV - 1) + k;
        if (tt >= 0) {
            ushort4 xv = *(const ushort4*)(xzb + (size_t)(b * SEQ + tt) * XZW + d);
            acc.x += bf2f(xv.x) * wp[0][k];
            acc.y += bf2f(xv.y) * wp[1][k];
            acc.z += bf2f(xv.z) * wp[2][k];
            acc.w += bf2f(xv.w) * wp[3][k];
        }
    }
    acc.x *= sigmoidf_(acc.x);
    acc.y *= sigmoidf_(acc.y);
    acc.z *= sigmoidf_(acc.z);
    acc.w *= sigmoidf_(acc.w);
    ushort4 ob = { f2bf(acc.x), f2bf(acc.y), f2bf(acc.z), f2bf(acc.w) };
    *(ushort4*)(u_bf + (size_t)(b * SEQ + t) * DI + d) = ob;
}

// ======================= 3-kernel chunked scan, lane = channel =====================
// K1: chunk-local (P,S) with h_in = 0
__global__ __launch_bounds__(256) void scan_p1(const ushort_t* __restrict__ delta,
                                               const ushort_t* __restrict__ u,
                                               const float* __restrict__ dbc,
                                               const float* __restrict__ aT,
                                               float* __restrict__ Pw,
                                               float* __restrict__ Sw)
{
    __shared__ float Bs[4][CLEN][DS];          // 8 KB
    int tid = threadIdx.x;
    int lane = tid & 63, w = tid >> 6;
    int d = blockIdx.x * 64 + lane;
    int chunk = blockIdx.y * 4 + w;
    int b = blockIdx.z;
    int t0 = chunk * CLEN;

    #pragma unroll
    for (int i = 0; i < 2; ++i) {
        int idx = i * 64 + lane;
        int tl = idx >> 2, c = idx & 3;
        *(float4*)&Bs[w][tl][c * 4] =
            *(const float4*)(dbc + (size_t)(b * SEQ + t0 + tl) * DBCW + DTR + c * 4);
    }

    float a[DS];
    #pragma unroll
    for (int n = 0; n < DS; ++n) a[n] = aT[n * DI + d];

    __syncthreads();

    float P[DS], S[DS];
    #pragma unroll
    for (int n = 0; n < DS; ++n) { P[n] = 1.f; S[n] = 0.f; }

    const ushort_t* dp = delta + ((size_t)b * SEQ + t0) * DI + d;
    const ushort_t* up = u     + ((size_t)b * SEQ + t0) * DI + d;
    #pragma unroll 4
    for (int j = 0; j < CLEN; ++j) {
        float dlt = bf2f(dp[(size_t)j * DI]);
        float uu  = bf2f(up[(size_t)j * DI]);
        float dltu = dlt * uu;
        #pragma unroll
        for (int n = 0; n < DS; ++n) {
            float dA = exp2f(dlt * a[n]);
            P[n] *= dA;
            S[n] = dA * S[n] + dltu * Bs[w][j][n];
        }
    }

    size_t base = (((size_t)b * NCHUNK + chunk) * DS) * DI + d;
    #pragma unroll
    for (int n = 0; n < DS; ++n) {
        Pw[base + (size_t)n * DI] = P[n];
        Sw[base + (size_t)n * DI] = S[n];
    }
}

// K2: serial combine across chunks -> Hin
__global__ __launch_bounds__(256) void scan_comb(const float* __restrict__ Pw,
                                                 const float* __restrict__ Sw,
                                                 float* __restrict__ Hin)
{
    int d = blockIdx.x * 256 + threadIdx.x;
    int n = blockIdx.y, b = blockIdx.z;
    float h = 0.f;
    for (int c = 0; c < NCHUNK; ++c) {
        size_t idx = (((size_t)b * NCHUNK + c) * DS + n) * DI + d;
        Hin[idx] = h;
        h = Pw[idx] * h + Sw[idx];
    }
}

// K3: replay with h_in, dot with C in-lane, gate with silu(z), write y bf16
__global__ __launch_bounds__(256) void scan_p3(const ushort_t* __restrict__ delta,
                                               const ushort_t* __restrict__ u,
                                               const float* __restrict__ dbc,
                                               const ushort_t* __restrict__ xzb,
                                               const float* __restrict__ aT,
                                               const float* __restrict__ Dp,
                                               const float* __restrict__ Hin,
                                               ushort_t* __restrict__ y)
{
    __shared__ float Bs[4][CLEN][2 * DS];      // 16 KB
    int tid = threadIdx.x;
    int lane = tid & 63, w = tid >> 6;
    int d = blockIdx.x * 64 + lane;
    int chunk = blockIdx.y * 4 + w;
    int b = blockIdx.z;
    int t0 = chunk * CLEN;

    #pragma unroll
    for (int i = 0; i < 4; ++i) {
        int idx = i * 64 + lane;
        int tl = idx >> 3, c = idx & 7;
        *(float4*)&Bs[w][tl][c * 4] =
            *(const float4*)(dbc + (size_t)(b * SEQ + t0 + tl) * DBCW + DTR + c * 4);
    }

    float a[DS], h[DS];
    #pragma unroll
    for (int n = 0; n < DS; ++n) a[n] = aT[n * DI + d];
    size_t hbase = (((size_t)b * NCHUNK + chunk) * DS) * DI + d;
    #pragma unroll
    for (int n = 0; n < DS; ++n) h[n] = Hin[hbase + (size_t)n * DI];

    float Dd = Dp[d];
    __syncthreads();

    const ushort_t* dp = delta + ((size_t)b * SEQ + t0) * DI + d;
    const ushort_t* up = u     + ((size_t)b * SEQ + t0) * DI + d;
    const ushort_t* zp = xzb   + ((size_t)b * SEQ + t0) * XZW + DI + d;
    ushort_t* yp       = y     + ((size_t)b * SEQ + t0) * DI + d;

    #pragma unroll 2
    for (int j = 0; j < CLEN; ++j) {
        float dlt = bf2f(dp[(size_t)j * DI]);
        float uu  = bf2f(up[(size_t)j * DI]);
        float dltu = dlt * uu;
        #pragma unroll
        for (int n = 0; n < DS; ++n) {
            float dA = exp2f(dlt * a[n]);
            h[n] = dA * h[n] + dltu * Bs[w][j][n];
        }
        float p0 = 0.f, p1 = 0.f, p2 = 0.f, p3 = 0.f;
        #pragma unroll
        for (int n = 0; n < DS; n += 4) {
            p0 += h[n]     * Bs[w][j][DS + n];
            p1 += h[n + 1] * Bs[w][j][DS + n + 1];
            p2 += h[n + 2] * Bs[w][j][DS + n + 2];
            p3 += h[n + 3] * Bs[w][j][DS + n + 3];
        }
        float p = (p0 + p1) + (p2 + p3);
        float z = bf2f(zp[(size_t)j * XZW]);
        float yv = (p + uu * Dd) * (z * sigmoidf_(z));
        yp[(size_t)j * DI] = f2bf(yv);
    }
}

extern "C" void kernel_launch(void* const* d_in, const int* in_sizes, int n_in,
                              void* d_out, int out_size, void* d_ws, size_t ws_size,
                              hipStream_t stream) {
    const float* x         = (const float*)d_in[0];
    const float* ln_w      = (const float*)d_in[1];
    const float* ln_b      = (const float*)d_in[2];
    const float* in_proj_w = (const float*)d_in[3];   // (3072, 768)
    const float* conv_w    = (const float*)d_in[4];   // (1536, 4)
    const float* conv_b    = (const float*)d_in[5];   // (1536)
    const float* x_proj_w  = (const float*)d_in[6];   // (80, 1536)
    const float* dt_proj_w = (const float*)d_in[7];   // (1536, 48)
    const float* dt_proj_b = (const float*)d_in[8];   // (1536)
    const float* A_log     = (const float*)d_in[9];   // (1536, 16)
    const float* D_param   = (const float*)d_in[10];  // (1536)
    const float* out_proj_w= (const float*)d_in[11];  // (768, 1536)
    float* out = (float*)d_out;

    char* ws = (char*)d_ws;
    size_t off = 0;
    auto alloc = [&](size_t bytes) { void* p = ws + off; off += (bytes + 255) & ~255ull; return p; };

    ushort_t* xn_bf   = (ushort_t*)alloc((size_t)MROWS * DIM * 2);
    ushort_t* w_in_bf = (ushort_t*)alloc((size_t)XZW * DIM * 2);
    ushort_t* w_out_bf= (ushort_t*)alloc((size_t)DIM * DI * 2);
    ushort_t* y_bf    = (ushort_t*)alloc((size_t)MROWS * DI * 2);
    ushort_t* u_bf    = (ushort_t*)alloc((size_t)MROWS * DI * 2);
    ushort_t* xpw_pad = (ushort_t*)alloc((size_t)XPN * DI * 2);
    ushort_t* dtw_bf  = (ushort_t*)alloc((size_t)DI * 64 * 2);
    ushort_t* dtb     = (ushort_t*)alloc((size_t)MROWS * 64 * 2);
    ushort_t* xzb     = (ushort_t*)alloc((size_t)MROWS * XZW * 2);
    ushort_t* delta_bf= (ushort_t*)alloc((size_t)MROWS * DI * 2);
    float* dbc   = (float*)alloc((size_t)MROWS * DBCW * 4);
    float* aT    = (float*)alloc((size_t)DS * DI * 4);
    float* xpart = (float*)alloc((size_t)XP_KS * MROWS * XPN * 4);
    float* opart = (float*)alloc((size_t)OP_KS * MROWS * DIM * 4);

    // scan scratch aliases opart (used only after scan): 3*B*NCHUNK*DS*DI = 18.9 MB <= 25.2 MB
    size_t cvol = (size_t)BATCH * NCHUNK * DS * DI;
    float* Pw  = opart;
    float* Sw  = opart + cvol;
    float* Hin = opart + 2 * cvol;

    // 0+1. fused prep (weight cvts, aT, padded weights) + LayerNorm
    hipLaunchKernelGGL(prep_ln, dim3(PREP_BLOCKS + MROWS), dim3(256), 0, stream,
                       in_proj_w, out_proj_w, A_log, x_proj_w, dt_proj_w,
                       x, ln_w, ln_b,
                       w_in_bf, w_out_bf, aT, xpw_pad, dtw_bf, xn_bf);

    // 2. in_proj (bf16 MFMA BK=64 swizzled, bf16 out): xzb = xn @ in_proj_w^T
    hipLaunchKernelGGL(gemm_bf16_obf, dim3(XZW / 128, MROWS / 128), dim3(256), 0, stream,
                       xn_bf, w_in_bf, xzb, XZW, DIM);

    // 3. conv + silu -> u_bf
    hipLaunchKernelGGL(conv_silu_kernel, dim3((MROWS * DI / 4) / 256), dim3(256), 0, stream,
                       xzb, conv_w, conv_b, u_bf);

    // 4. x_proj (bf16 MFMA split-K, N padded to 128, writes cols<80): xpart[z] = u_bf @ xpw_pad^T
    hipLaunchKernelGGL(gemm_bf16_sk, dim3(XPN / 128, MROWS / 128, XP_KS), dim3(256), 0, stream,
                       u_bf, xpw_pad, xpart, XPN, DI, DI / XP_KS, MROWS, DBCW);
    hipLaunchKernelGGL(reduce_dbc, dim3((MROWS * XPN + 255) / 256), dim3(256), 0, stream,
                       xpart, dbc, dtb);

    // 5. dt_proj (bf16 MFMA K=64) + bias + softplus -> delta (bf16)
    hipLaunchKernelGGL(gemm_dt, dim3(DI / 128, MROWS / 128), dim3(256), 0, stream,
                       dtb, dtw_bf, dt_proj_b, delta_bf);

    // 6. chunked scan: K1 (P,S) -> K2 combine -> K3 replay+gate
    hipLaunchKernelGGL(scan_p1, dim3(DI / 64, NCHUNK / 4, BATCH), dim3(256), 0, stream,
                       delta_bf, u_bf, dbc, aT, Pw, Sw);
    hipLaunchKernelGGL(scan_comb, dim3(DI / 256, DS, BATCH), dim3(256), 0, stream,
                       Pw, Sw, Hin);
    hipLaunchKernelGGL(scan_p3, dim3(DI / 64, NCHUNK / 4, BATCH), dim3(256), 0, stream,
                       delta_bf, u_bf, dbc, xzb, aT, D_param, Hin, y_bf);

    // 7. out_proj (bf16 MFMA split-K): out(2048x768) = y @ out_proj_w^T
    hipLaunchKernelGGL(gemm_bf16_sk, dim3(DIM / 128, MROWS / 128, OP_KS), dim3(256), 0, stream,
                       y_bf, w_out_bf, opart, DIM, DI, DI / OP_KS, MROWS, DIM);
    hipLaunchKernelGGL(reduce_sk4, dim3((MROWS * DIM / 4 + 255) / 256), dim3(256), 0, stream,
                       (const float4*)opart, (float4*)out, MROWS * DIM / 4, OP_KS);
}